// Round 1
// baseline (22852.180 us; speedup 1.0000x reference)
//
#include <hip/hip_runtime.h>
#include <hip/hip_bf16.h>

// Problem constants
#define NNODES   32768      // N = 512 groups * 64
#define NGROUPS  512
#define EPG      512        // edges per group
#define ND       (32768l*128)

// ---------------------------------------------------------------------------
// h0 = node_features(32768x32) @ W(32x128) + b
__global__ void k_node_enc(const float* __restrict__ nf, const float* __restrict__ w,
                           const float* __restrict__ b, float* __restrict__ h0) {
  int idx = blockIdx.x * 256 + threadIdx.x;   // N*128 threads
  int row = idx >> 7, col = idx & 127;
  const float* x = nf + row * 32;
  float acc = b[col];
#pragma unroll
  for (int k = 0; k < 32; ++k) acc = fmaf(x[k], w[k * 128 + col], acc);
  h0[idx] = acc;
}

// ---------------------------------------------------------------------------
// Fused 2-layer MLP: out = relu([x0|x1] @ W1 + b1) @ W2 + b2
// x0,x1: N x 128 (x1 may be null -> zeros), W1: 256x256, W2: 256x128.
// Block: 256 threads, 32 rows.  2 blocks/CU.
__global__ __launch_bounds__(256, 2)
void k_mlp2(const float* __restrict__ x0, const float* __restrict__ x1,
            const float* __restrict__ W1, const float* __restrict__ b1,
            const float* __restrict__ W2, const float* __restrict__ b2,
            float* __restrict__ out) {
  __shared__ __align__(16) float xt[256][36];   // transposed input  [k][row]
  __shared__ __align__(16) float yt[256][36];   // transposed hidden [k][row]
  const int tid = threadIdx.x;
  const int row0 = blockIdx.x * 32;

  { // stage transposed: xt[k][r] = x(row0+r)[k]
    const int r = tid >> 5;       // 0..7
    const int q = tid & 31;       // float4 index within a row
    for (int rr = r; rr < 32; rr += 8) {
      float4 v0 = ((const float4*)(x0 + (long)(row0 + rr) * 128))[q];
      xt[q*4+0][rr] = v0.x; xt[q*4+1][rr] = v0.y; xt[q*4+2][rr] = v0.z; xt[q*4+3][rr] = v0.w;
      float4 v1 = make_float4(0.f, 0.f, 0.f, 0.f);
      if (x1) v1 = ((const float4*)(x1 + (long)(row0 + rr) * 128))[q];
      xt[128+q*4+0][rr] = v1.x; xt[128+q*4+1][rr] = v1.y; xt[128+q*4+2][rr] = v1.z; xt[128+q*4+3][rr] = v1.w;
    }
  }
  __syncthreads();

  const int tc = tid & 63, rg = tid >> 6;
  const int c0 = tc * 4, r0 = rg * 8;

  // layer 1: 8 rows x 4 cols per thread
  float acc[8][4];
#pragma unroll
  for (int r = 0; r < 8; ++r)
#pragma unroll
    for (int j = 0; j < 4; ++j) acc[r][j] = b1[c0 + j];

#pragma unroll 4
  for (int k = 0; k < 256; ++k) {
    const float4 xa = *(const float4*)&xt[k][r0];
    const float4 xb = *(const float4*)&xt[k][r0 + 4];
    const float4 wv = *(const float4*)&W1[k * 256 + c0];
    const float xs_[8] = {xa.x, xa.y, xa.z, xa.w, xb.x, xb.y, xb.z, xb.w};
#pragma unroll
    for (int r = 0; r < 8; ++r) {
      acc[r][0] = fmaf(xs_[r], wv.x, acc[r][0]);
      acc[r][1] = fmaf(xs_[r], wv.y, acc[r][1]);
      acc[r][2] = fmaf(xs_[r], wv.z, acc[r][2]);
      acc[r][3] = fmaf(xs_[r], wv.w, acc[r][3]);
    }
  }
#pragma unroll
  for (int j = 0; j < 4; ++j) {
    float4 lo = make_float4(fmaxf(acc[0][j],0.f), fmaxf(acc[1][j],0.f),
                            fmaxf(acc[2][j],0.f), fmaxf(acc[3][j],0.f));
    float4 hi = make_float4(fmaxf(acc[4][j],0.f), fmaxf(acc[5][j],0.f),
                            fmaxf(acc[6][j],0.f), fmaxf(acc[7][j],0.f));
    *(float4*)&yt[c0 + j][r0]     = lo;
    *(float4*)&yt[c0 + j][r0 + 4] = hi;
  }
  __syncthreads();

  // layer 2: 8 rows x 2 cols per thread (128 output cols)
  const int c20 = tc * 2;
  float a2[8][2];
#pragma unroll
  for (int r = 0; r < 8; ++r) { a2[r][0] = b2[c20]; a2[r][1] = b2[c20 + 1]; }

#pragma unroll 4
  for (int k = 0; k < 256; ++k) {
    const float4 xa = *(const float4*)&yt[k][r0];
    const float4 xb = *(const float4*)&yt[k][r0 + 4];
    const float2 wv = *(const float2*)&W2[k * 128 + c20];
    const float xs_[8] = {xa.x, xa.y, xa.z, xa.w, xb.x, xb.y, xb.z, xb.w};
#pragma unroll
    for (int r = 0; r < 8; ++r) {
      a2[r][0] = fmaf(xs_[r], wv.x, a2[r][0]);
      a2[r][1] = fmaf(xs_[r], wv.y, a2[r][1]);
    }
  }
#pragma unroll
  for (int r = 0; r < 8; ++r) {
    float2 v = make_float2(a2[r][0], a2[r][1]);
    *(float2*)&out[(long)(row0 + r0 + r) * 128 + c20] = v;
  }
}

// ---------------------------------------------------------------------------
// Fused per-group: e0 recompute + messages MLP + segment_sum into LDS.
// One block per group (512 blocks), 512 edges each, agg written directly.
__global__ __launch_bounds__(256, 2)
void k_msgagg(const float* __restrict__ comb, const float* __restrict__ efeat,
              const float* __restrict__ ew, const float* __restrict__ ebias,
              const int* __restrict__ from_idx, const int* __restrict__ to_idx,
              const float* __restrict__ mw1, const float* __restrict__ mb1,
              const float* __restrict__ mw2, const float* __restrict__ mb2,
              float* __restrict__ agg) {
  __shared__ float agg_s[64 * 128];
  __shared__ __align__(16) float xt[320][20];   // [k][edge] chunk of 16 edges; reused for hidden
  __shared__ int fl[EPG], tl[EPG];
  const int tid = threadIdx.x;
  const int g = blockIdx.x;
  const int be = g * EPG;       // first edge of group
  const int bn = g * 64;        // first node of group

  for (int i = tid; i < 64 * 128; i += 256) agg_s[i] = 0.f;
  for (int i = tid; i < EPG; i += 256) {
    fl[i] = from_idx[be + i] - bn;
    tl[i] = to_idx[be + i] - bn;
  }
  __syncthreads();

  const int tc = tid & 63, eg = tid >> 6;
  const int c0 = tc * 4, e0r = eg * 4, c20 = tc * 2;

  for (int ch = 0; ch < 32; ++ch) {            // 32 chunks x 16 edges
    const int ebase = ch * 16;
    { // stage xt rows 0..255 from comb (gathered via L2)
      const int e = tid & 15, k0 = (tid >> 4) * 16;
      const int loc = (k0 < 128) ? fl[ebase + e] : tl[ebase + e];
      const int kk = k0 & 127;
      const float* src = comb + (long)(bn + loc) * 128 + kk;
#pragma unroll
      for (int i = 0; i < 4; ++i) {
        float4 v = ((const float4*)src)[i];
        xt[k0 + i*4 + 0][e] = v.x; xt[k0 + i*4 + 1][e] = v.y;
        xt[k0 + i*4 + 2][e] = v.z; xt[k0 + i*4 + 3][e] = v.w;
      }
    }
    { // e0 rows 256..319: e0 = edge_feat(16) @ ew(16x64) + eb
      const int e = tid & 15, j0 = (tid >> 4) * 4;
      const float* erow = efeat + (long)(be + ebase + e) * 16;
      float a0 = ebias[j0], a1 = ebias[j0+1], a2_ = ebias[j0+2], a3 = ebias[j0+3];
#pragma unroll
      for (int i = 0; i < 16; ++i) {
        const float xv = erow[i];
        const float4 wv = *(const float4*)&ew[i * 64 + j0];
        a0 = fmaf(xv, wv.x, a0); a1 = fmaf(xv, wv.y, a1);
        a2_ = fmaf(xv, wv.z, a2_); a3 = fmaf(xv, wv.w, a3);
      }
      xt[256 + j0 + 0][e] = a0; xt[256 + j0 + 1][e] = a1;
      xt[256 + j0 + 2][e] = a2_; xt[256 + j0 + 3][e] = a3;
    }
    __syncthreads();

    // layer 1: hidden[e][c] ; thread tile 4 edges x 4 cols
    float acc[4][4];
#pragma unroll
    for (int e = 0; e < 4; ++e)
#pragma unroll
      for (int j = 0; j < 4; ++j) acc[e][j] = mb1[c0 + j];

#pragma unroll 4
    for (int k = 0; k < 320; ++k) {
      const float4 xv = *(const float4*)&xt[k][e0r];
      const float4 wv = *(const float4*)&mw1[k * 256 + c0];
      const float xs_[4] = {xv.x, xv.y, xv.z, xv.w};
#pragma unroll
      for (int e = 0; e < 4; ++e) {
        acc[e][0] = fmaf(xs_[e], wv.x, acc[e][0]);
        acc[e][1] = fmaf(xs_[e], wv.y, acc[e][1]);
        acc[e][2] = fmaf(xs_[e], wv.z, acc[e][2]);
        acc[e][3] = fmaf(xs_[e], wv.w, acc[e][3]);
      }
    }
    __syncthreads();   // all xt reads done before overwrite with hidden
#pragma unroll
    for (int j = 0; j < 4; ++j) {
      float4 hv = make_float4(fmaxf(acc[0][j],0.f), fmaxf(acc[1][j],0.f),
                              fmaxf(acc[2][j],0.f), fmaxf(acc[3][j],0.f));
      *(float4*)&xt[c0 + j][e0r] = hv;   // hidden stored [c][e]
    }
    __syncthreads();

    // layer 2: msg[e][c] ; thread tile 4 edges x 2 cols, then LDS segment-sum
    float a2[4][2];
#pragma unroll
    for (int e = 0; e < 4; ++e) { a2[e][0] = mb2[c20]; a2[e][1] = mb2[c20 + 1]; }

#pragma unroll 4
    for (int k = 0; k < 256; ++k) {
      const float4 xv = *(const float4*)&xt[k][e0r];
      const float2 wv = *(const float2*)&mw2[k * 128 + c20];
      const float xs_[4] = {xv.x, xv.y, xv.z, xv.w};
#pragma unroll
      for (int e = 0; e < 4; ++e) {
        a2[e][0] = fmaf(xs_[e], wv.x, a2[e][0]);
        a2[e][1] = fmaf(xs_[e], wv.y, a2[e][1]);
      }
    }
#pragma unroll
    for (int e = 0; e < 4; ++e) {
      const int to = tl[ebase + e0r + e];
      atomicAdd(&agg_s[to * 128 + c20],     a2[e][0]);
      atomicAdd(&agg_s[to * 128 + c20 + 1], a2[e][1]);
    }
    __syncthreads();
  }
  for (int i = tid; i < 64 * 128; i += 256) agg[(long)bn * 128 + i] = agg_s[i];
}

// ---------------------------------------------------------------------------
// tf = relu(parts5 @ t1w + t1b) @ t2w + t2b   (N x 64); 4 rows per block
__global__ void k_tfeat(const float* __restrict__ x,
                        const float* __restrict__ t1w, const float* __restrict__ t1b,
                        const float* __restrict__ t2w, const float* __restrict__ t2b,
                        float* __restrict__ tf) {
  __shared__ float xs[4][128];
  __shared__ float ys[4][64];
  const int tid = threadIdx.x;
  const long row0 = (long)blockIdx.x * 4;
  for (int i = tid; i < 512; i += 256)
    xs[i >> 7][i & 127] = x[(row0 + (i >> 7)) * 128 + (i & 127)];
  __syncthreads();
  const int r = tid >> 6, c = tid & 63;
  float acc = t1b[c];
#pragma unroll 4
  for (int k = 0; k < 128; ++k) acc = fmaf(xs[r][k], t1w[k * 64 + c], acc);
  ys[r][c] = fmaxf(acc, 0.f);
  __syncthreads();
  float a2 = t2b[c];
#pragma unroll 4
  for (int k = 0; k < 64; ++k) a2 = fmaf(ys[r][k], t2w[k * 64 + c], a2);
  tf[(row0 + r) * 64 + c] = a2;
}

// ---------------------------------------------------------------------------
// sim[b] = tq_b (64x64) @ tc_b^T ; one block per pair
__global__ void k_sim(const float* __restrict__ tf, float* __restrict__ sim) {
  const int b = blockIdx.x, tid = threadIdx.x;
  __shared__ float tq[64][65];
  __shared__ float tcs[64][65];
  for (int i = tid; i < 4096; i += 256) {
    tq[i >> 6][i & 63]  = tf[(long)b * 8192 + i];          // even graph rows
    tcs[i >> 6][i & 63] = tf[(long)b * 8192 + 4096 + i];   // odd graph rows
  }
  __syncthreads();
  const int m = tid >> 2, j0 = (tid & 3) * 16;
#pragma unroll
  for (int j = 0; j < 16; ++j) {
    float a = 0.f;
#pragma unroll 4
    for (int k = 0; k < 64; ++k) a = fmaf(tq[m][k], tcs[j0 + j][k], a);
    sim[(long)b * 4096 + m * 64 + j0 + j] = a;
  }
}

// ---------------------------------------------------------------------------
// Sinkhorn: la = sim/TEMP; 20x (row-LSE, col-LSE); plan = exp(la)
__global__ void k_sink(float* __restrict__ sim, float* __restrict__ outp) {
  const int b = blockIdx.x, tid = threadIdx.x;
  __shared__ float la[64][65];
  __shared__ float red[64];
  for (int i = tid; i < 4096; i += 256)
    la[i >> 6][i & 63] = sim[(long)b * 4096 + i] * 10.0f;
  __syncthreads();
  for (int it = 0; it < 20; ++it) {
    if (tid < 64) {       // row LSE (over c)
      const int r = tid;
      float m = -3.4e38f;
      for (int c = 0; c < 64; ++c) m = fmaxf(m, la[r][c]);
      float s = 0.f;
      for (int c = 0; c < 64; ++c) s += expf(la[r][c] - m);
      red[r] = m + logf(s);
    }
    __syncthreads();
    for (int i = tid; i < 4096; i += 256) la[i >> 6][i & 63] -= red[i >> 6];
    __syncthreads();
    if (tid < 64) {       // col LSE (over q)
      const int c = tid;
      float m = -3.4e38f;
      for (int r = 0; r < 64; ++r) m = fmaxf(m, la[r][c]);
      float s = 0.f;
      for (int r = 0; r < 64; ++r) s += expf(la[r][c] - m);
      red[c] = m + logf(s);
    }
    __syncthreads();
    for (int i = tid; i < 4096; i += 256) la[i >> 6][i & 63] -= red[i & 63];
    __syncthreads();
  }
  for (int i = tid; i < 4096; i += 256) {
    const float v = expf(la[i >> 6][i & 63]);
    outp[(long)b * 4096 + i] = v;     // d_out
    sim[(long)b * 4096 + i] = v;      // plan kept in ws for mixing
  }
}

// ---------------------------------------------------------------------------
// mixed[p] rows: q-rows = plan @ parts[p](c-rows); c-rows = plan^T @ parts[p](q-rows)
// grid (256 pairs, 4 p-values)
__global__ void k_mix(const float* __restrict__ plan, const float* __restrict__ parts_base,
                      float* __restrict__ mixed_base) {
  const int b = blockIdx.x, pi = blockIdx.y, tid = threadIdx.x;
  const float* parts = parts_base + (long)pi * ND;
  float* mixed = mixed_base + (long)pi * ND;
  __shared__ float pl[64][65];
  __shared__ float qs[64][128];
  __shared__ float cs[64][128];
  const long qbase = (long)(2 * b) * 64, cbase = qbase + 64;
  for (int i = tid; i < 4096; i += 256) pl[i >> 6][i & 63] = plan[(long)b * 4096 + i];
  for (int i = tid; i < 8192; i += 256) {
    qs[i >> 7][i & 127] = parts[qbase * 128 + i];
    cs[i >> 7][i & 127] = parts[cbase * 128 + i];
  }
  __syncthreads();
  const int d = tid & 127, m0 = (tid >> 7) * 32;
  for (int m = m0; m < m0 + 32; ++m) {
    float a = 0.f;
#pragma unroll 4
    for (int j = 0; j < 64; ++j) a = fmaf(pl[m][j], cs[j][d], a);
    mixed[(qbase + m) * 128 + d] = a;
  }
  for (int j = m0; j < m0 + 32; ++j) {
    float a = 0.f;
#pragma unroll 4
    for (int m = 0; m < 64; ++m) a = fmaf(pl[m][j], qs[m][d], a);
    mixed[(cbase + j) * 128 + d] = a;
  }
}

// ---------------------------------------------------------------------------
extern "C" void kernel_launch(void* const* d_in, const int* in_sizes, int n_in,
                              void* d_out, int out_size, void* d_ws, size_t ws_size,
                              hipStream_t stream) {
  const float* nf  = (const float*)d_in[0];
  const float* ef  = (const float*)d_in[1];
  const int* from_idx = (const int*)d_in[2];
  const int* to_idx   = (const int*)d_in[3];
  const float* new_w = (const float*)d_in[4];
  const float* new_b = (const float*)d_in[5];
  const float* eew = (const float*)d_in[6];
  const float* eeb = (const float*)d_in[7];
  const float* mw1 = (const float*)d_in[8];
  const float* mb1 = (const float*)d_in[9];
  const float* mw2 = (const float*)d_in[10];
  const float* mb2 = (const float*)d_in[11];
  const float* nw1 = (const float*)d_in[12];
  const float* nb1 = (const float*)d_in[13];
  const float* nw2 = (const float*)d_in[14];
  const float* nb2 = (const float*)d_in[15];
  const float* cw1 = (const float*)d_in[16];
  const float* cb1 = (const float*)d_in[17];
  const float* cw2 = (const float*)d_in[18];
  const float* cb2 = (const float*)d_in[19];
  const float* t1w = (const float*)d_in[20];
  const float* t1b = (const float*)d_in[21];
  const float* t2w = (const float*)d_in[22];
  const float* t2b = (const float*)d_in[23];

  float* W = (float*)d_ws;
  float* h0    = W;                 // ND
  float* comb  = h0 + ND;           // ND
  float* agg   = comb + ND;         // ND
  float* parts = agg + ND;          // 5 * ND   (parts[p] at (p-1)*ND)
  float* mixed = parts + 5 * ND;    // 4 * ND   (mixed[p] at (p-1)*ND)
  float* tf    = mixed + 4 * ND;    // 32768*64
  float* sim   = tf + 32768l * 64;  // 256*64*64 (also holds plan after k_sink)
  float* outp  = (float*)d_out;

  k_node_enc<<<16384, 256, 0, stream>>>(nf, new_w, new_b, h0);

  for (int t = 0; t < 3; ++t) {
    const float* hprev = h0;
    for (int p = 1; p <= 5; ++p) {
      const float* inter = (t > 0 && p > 1) ? (mixed + (long)(p - 2) * ND) : nullptr;
      k_mlp2<<<1024, 256, 0, stream>>>(hprev, inter, cw1, cb1, cw2, cb2, comb);
      k_msgagg<<<512, 256, 0, stream>>>(comb, ef, eew, eeb, from_idx, to_idx,
                                        mw1, mb1, mw2, mb2, agg);
      float* hnew = parts + (long)(p - 1) * ND;
      k_mlp2<<<1024, 256, 0, stream>>>(comb, agg, nw1, nb1, nw2, nb2, hnew);
      hprev = hnew;
    }
    k_tfeat<<<8192, 256, 0, stream>>>(parts + 4 * ND, t1w, t1b, t2w, t2b, tf);
    k_sim<<<256, 256, 0, stream>>>(tf, sim);
    k_sink<<<256, 256, 0, stream>>>(sim, outp);
    if (t < 2) k_mix<<<dim3(256, 4), 256, 0, stream>>>(sim, parts, mixed);
  }
}

// Round 3
// 10472.645 us; speedup vs baseline: 2.1821x; 2.1821x over previous
//
#include <hip/hip_runtime.h>
#include <hip/hip_bf16.h>

#define NNODES   32768
#define NGROUPS  512
#define EPG      512
#define ND       (32768l*128)

// ---------------------------------------------------------------------------
// h0 = node_features(32768x32) @ W(32x128) + b
__global__ void k_node_enc(const float* __restrict__ nf, const float* __restrict__ w,
                           const float* __restrict__ b, float* __restrict__ h0) {
  int idx = blockIdx.x * 256 + threadIdx.x;
  int row = idx >> 7, col = idx & 127;
  const float* x = nf + row * 32;
  float acc = b[col];
#pragma unroll
  for (int k = 0; k < 32; ++k) acc = fmaf(x[k], w[k * 128 + col], acc);
  h0[idx] = acc;
}

// ---------------------------------------------------------------------------
// Precompute folded weights:
//  blocks 0..15 : Wfold[16][256] = eew(16x64) @ mw1[256:320,:]
//  block  16    : bfold[256]     = eeb @ mw1[256:320,:] + mb1
//  block  17    : vbias[256]     = mb2 @ nw1[128:256,:]
__global__ void k_prep(const float* __restrict__ eew, const float* __restrict__ eeb,
                       const float* __restrict__ mw1, const float* __restrict__ mb1,
                       const float* __restrict__ mb2, const float* __restrict__ nw1,
                       float* __restrict__ Wfold, float* __restrict__ bfold,
                       float* __restrict__ vbias) {
  const int c = threadIdx.x, b = blockIdx.x;
  if (b < 16) {
    float a = 0.f;
    for (int j = 0; j < 64; ++j) a = fmaf(eew[b * 64 + j], mw1[(256 + j) * 256 + c], a);
    Wfold[b * 256 + c] = a;
  } else if (b == 16) {
    float a = mb1[c];
    for (int j = 0; j < 64; ++j) a = fmaf(eeb[j], mw1[(256 + j) * 256 + c], a);
    bfold[c] = a;
  } else {
    float a = 0.f;
    for (int j = 0; j < 128; ++j) a = fmaf(mb2[j], nw1[(128 + j) * 256 + c], a);
    vbias[c] = a;
  }
}

__global__ void k_zero_deg(int* __restrict__ deg) {
  deg[blockIdx.x * 256 + threadIdx.x] = 0;
}
__global__ void k_degc(const int* __restrict__ to_idx, int* __restrict__ deg) {
  atomicAdd(&deg[to_idx[blockIdx.x * 256 + threadIdx.x]], 1);
}

// ---------------------------------------------------------------------------
// Unified 2-layer MLP with split K: out = relu(x0@W1a + x1@W1b + bias)@W2 + b2
// bias = b1 (+ deg*vbias if DEG). x0: Nx128; x1: NxK1.
template<int K1, bool DEG>
__global__ __launch_bounds__(256, 2)
void k_mlp2g(const float* __restrict__ x0, const float* __restrict__ x1,
             const float* __restrict__ W1a, const float* __restrict__ W1b,
             const float* __restrict__ b1, const int* __restrict__ deg,
             const float* __restrict__ vbias,
             const float* __restrict__ W2, const float* __restrict__ b2,
             float* __restrict__ out) {
  __shared__ __align__(16) float buf[256][36];
  const int tid = threadIdx.x;
  const int row0 = blockIdx.x * 32;

  for (int i = tid; i < 1024; i += 256) {
    int n = i >> 5, q = i & 31;
    float4 v = *(const float4*)&x0[(long)(row0 + n) * 128 + q * 4];
    buf[q*4+0][n] = v.x; buf[q*4+1][n] = v.y; buf[q*4+2][n] = v.z; buf[q*4+3][n] = v.w;
  }
  if constexpr (K1 == 128) {
    for (int i = tid; i < 1024; i += 256) {
      int n = i >> 5, q = i & 31;
      float4 v = *(const float4*)&x1[(long)(row0 + n) * 128 + q * 4];
      buf[128+q*4+0][n] = v.x; buf[128+q*4+1][n] = v.y; buf[128+q*4+2][n] = v.z; buf[128+q*4+3][n] = v.w;
    }
  }
  __syncthreads();

  const int tc = tid & 63, rg = tid >> 6;
  const int c0 = tc * 4, r0 = rg * 8;

  float acc[8][4];
  {
    const float4 bv = *(const float4*)&b1[c0];
    if constexpr (DEG) {
      const float4 vb = *(const float4*)&vbias[c0];
#pragma unroll
      for (int r = 0; r < 8; ++r) {
        const float dv = (float)deg[row0 + r0 + r];
        acc[r][0] = fmaf(dv, vb.x, bv.x); acc[r][1] = fmaf(dv, vb.y, bv.y);
        acc[r][2] = fmaf(dv, vb.z, bv.z); acc[r][3] = fmaf(dv, vb.w, bv.w);
      }
    } else {
#pragma unroll
      for (int r = 0; r < 8; ++r) {
        acc[r][0] = bv.x; acc[r][1] = bv.y; acc[r][2] = bv.z; acc[r][3] = bv.w;
      }
    }
  }

#pragma unroll 4
  for (int k = 0; k < 128; ++k) {
    const float4 xa = *(const float4*)&buf[k][r0];
    const float4 xb = *(const float4*)&buf[k][r0 + 4];
    const float4 wv = *(const float4*)&W1a[k * 256 + c0];
    const float xs_[8] = {xa.x, xa.y, xa.z, xa.w, xb.x, xb.y, xb.z, xb.w};
#pragma unroll
    for (int r = 0; r < 8; ++r) {
      acc[r][0] = fmaf(xs_[r], wv.x, acc[r][0]);
      acc[r][1] = fmaf(xs_[r], wv.y, acc[r][1]);
      acc[r][2] = fmaf(xs_[r], wv.z, acc[r][2]);
      acc[r][3] = fmaf(xs_[r], wv.w, acc[r][3]);
    }
  }
  if constexpr (K1 > 0) {
#pragma unroll 4
    for (int k = 0; k < K1; ++k) {
      const float4 xa = *(const float4*)&buf[128 + k][r0];
      const float4 xb = *(const float4*)&buf[128 + k][r0 + 4];
      const float4 wv = *(const float4*)&W1b[k * 256 + c0];
      const float xs_[8] = {xa.x, xa.y, xa.z, xa.w, xb.x, xb.y, xb.z, xb.w};
#pragma unroll
      for (int r = 0; r < 8; ++r) {
        acc[r][0] = fmaf(xs_[r], wv.x, acc[r][0]);
        acc[r][1] = fmaf(xs_[r], wv.y, acc[r][1]);
        acc[r][2] = fmaf(xs_[r], wv.z, acc[r][2]);
        acc[r][3] = fmaf(xs_[r], wv.w, acc[r][3]);
      }
    }
  }
  __syncthreads();   // all buf reads done before hidden overwrite
#pragma unroll
  for (int j = 0; j < 4; ++j) {
    float4 lo = make_float4(fmaxf(acc[0][j],0.f), fmaxf(acc[1][j],0.f),
                            fmaxf(acc[2][j],0.f), fmaxf(acc[3][j],0.f));
    float4 hi = make_float4(fmaxf(acc[4][j],0.f), fmaxf(acc[5][j],0.f),
                            fmaxf(acc[6][j],0.f), fmaxf(acc[7][j],0.f));
    *(float4*)&buf[c0 + j][r0]     = lo;
    *(float4*)&buf[c0 + j][r0 + 4] = hi;
  }
  __syncthreads();

  const int c20 = tc * 2;
  float a2[8][2];
#pragma unroll
  for (int r = 0; r < 8; ++r) { a2[r][0] = b2[c20]; a2[r][1] = b2[c20 + 1]; }
#pragma unroll 4
  for (int k = 0; k < 256; ++k) {
    const float4 xa = *(const float4*)&buf[k][r0];
    const float4 xb = *(const float4*)&buf[k][r0 + 4];
    const float2 wv = *(const float2*)&W2[k * 128 + c20];
    const float xs_[8] = {xa.x, xa.y, xa.z, xa.w, xb.x, xb.y, xb.z, xb.w};
#pragma unroll
    for (int r = 0; r < 8; ++r) {
      a2[r][0] = fmaf(xs_[r], wv.x, a2[r][0]);
      a2[r][1] = fmaf(xs_[r], wv.y, a2[r][1]);
    }
  }
#pragma unroll
  for (int r = 0; r < 8; ++r) {
    float2 v = make_float2(a2[r][0], a2[r][1]);
    *(float2*)&out[(long)(row0 + r0 + r) * 128 + c20] = v;
  }
}

// ---------------------------------------------------------------------------
// Fused per-group edge pipeline. One block per group (512 blocks):
//   for each 64-col block cb of the 256 hidden cols:
//     cA = comb_g @ mw1[0:128, cb]; cB = comb_g @ mw1[128:256, cb]   (LDS GEMM)
//     hidden[e] = relu(cA[from] + cB[to] + ef@Wfold + bfold); ag[to] += hidden
//     aM += ag @ mw2[cb,:]                                           (reg accum)
//   aggM[g] = aM   (N x 128)
// LDS: cA/cB 34.8KB + union(ct | ag+efc) 34.8KB + fl/tl 4KB = 73.7KB -> 2 blk/CU
__global__ __launch_bounds__(256, 2)
void k_edge(const float* __restrict__ comb, const float* __restrict__ ef,
            const float* __restrict__ mw1, const float* __restrict__ mw2,
            const float* __restrict__ Wfold, const float* __restrict__ bfold,
            const int* __restrict__ from_idx, const int* __restrict__ to_idx,
            float* __restrict__ aggM) {
  __shared__ __align__(16) float cA[64][68], cB[64][68];
  __shared__ __align__(16) float U[8704];   // ct[128][68]  |  ag[64][68] + efc[128][20]
  __shared__ int fl[EPG], tl[EPG];
  float* ct  = U;              // [128][68]
  float* ag  = U;              // [64][68]
  float* efc = U + 64 * 68;    // [128][20]

  const int tid = threadIdx.x;
  const int g = blockIdx.x, be = g * EPG, bn = g * 64;

  for (int i = tid; i < EPG; i += 256) {
    fl[i] = from_idx[be + i] - bn;
    tl[i] = to_idx[be + i] - bn;
  }

  const int ng = tid >> 4, cg = tid & 15;
  const int n0 = ng * 4;
  const int cq = cg * 4;

  float aM[4][8];
#pragma unroll
  for (int i = 0; i < 4; ++i)
#pragma unroll
    for (int j = 0; j < 8; ++j) aM[i][j] = 0.f;

  for (int cb = 0; cb < 4; ++cb) {
    const int col0 = cb * 64;
    __syncthreads();   // prev iter's ag reads (and fl/tl init) done before U overwrite
    // stage ct[k][n] = comb[bn+n][k]
    for (int i = tid; i < 2048; i += 256) {
      int n = i >> 5, q = i & 31;
      float4 v = *(const float4*)&comb[(long)(bn + n) * 128 + q * 4];
      ct[(q*4+0)*68 + n] = v.x; ct[(q*4+1)*68 + n] = v.y;
      ct[(q*4+2)*68 + n] = v.z; ct[(q*4+3)*68 + n] = v.w;
    }
    __syncthreads();
    // AB GEMM: 4n x 4c per thread, K=128
    {
      float accA[4][4], accB[4][4];
#pragma unroll
      for (int i = 0; i < 4; ++i)
#pragma unroll
        for (int j = 0; j < 4; ++j) { accA[i][j] = 0.f; accB[i][j] = 0.f; }
      const int c0 = col0 + cq;
#pragma unroll 2
      for (int k = 0; k < 128; ++k) {
        const float4 xv = *(const float4*)&ct[k * 68 + n0];
        const float4 wa = *(const float4*)&mw1[k * 256 + c0];
        const float4 wb = *(const float4*)&mw1[(128 + k) * 256 + c0];
        const float xs_[4] = {xv.x, xv.y, xv.z, xv.w};
#pragma unroll
        for (int i = 0; i < 4; ++i) {
          accA[i][0] = fmaf(xs_[i], wa.x, accA[i][0]);
          accA[i][1] = fmaf(xs_[i], wa.y, accA[i][1]);
          accA[i][2] = fmaf(xs_[i], wa.z, accA[i][2]);
          accA[i][3] = fmaf(xs_[i], wa.w, accA[i][3]);
          accB[i][0] = fmaf(xs_[i], wb.x, accB[i][0]);
          accB[i][1] = fmaf(xs_[i], wb.y, accB[i][1]);
          accB[i][2] = fmaf(xs_[i], wb.z, accB[i][2]);
          accB[i][3] = fmaf(xs_[i], wb.w, accB[i][3]);
        }
      }
#pragma unroll
      for (int i = 0; i < 4; ++i) {
        *(float4*)&cA[n0 + i][cq] = make_float4(accA[i][0], accA[i][1], accA[i][2], accA[i][3]);
        *(float4*)&cB[n0 + i][cq] = make_float4(accB[i][0], accB[i][1], accB[i][2], accB[i][3]);
      }
    }
    __syncthreads();   // all ct reads + cA/cB writes complete
    for (int i = tid; i < 64 * 68; i += 256) ag[i] = 0.f;
    float4 Wf[16];
#pragma unroll
    for (int k = 0; k < 16; ++k) Wf[k] = *(const float4*)&Wfold[k * 256 + col0 + cq];
    const float4 bf = *(const float4*)&bfold[col0 + cq];
    __syncthreads();   // ag zeroed, cA/cB visible

    // edge phase: 4 chunks of 128 edges
    for (int ch = 0; ch < 4; ++ch) {
      for (int i = tid; i < 512; i += 256) {
        int j = i >> 2, q = i & 3;
        *(float4*)&efc[j * 20 + q * 4] = *(const float4*)&ef[(long)(be + ch * 128 + j) * 16 + q * 4];
      }
      __syncthreads();
      const int eg = tid >> 4;
      for (int it = 0; it < 8; ++it) {
        const int j = it * 16 + eg;
        const int e = ch * 128 + j;
        const int f = fl[e], t = tl[e];
        float4 acc = bf;
#pragma unroll
        for (int kq = 0; kq < 4; ++kq) {
          const float4 e4 = *(const float4*)&efc[j * 20 + kq * 4];
          const float ev[4] = {e4.x, e4.y, e4.z, e4.w};
#pragma unroll
          for (int s = 0; s < 4; ++s) {
            const float4 w = Wf[kq * 4 + s];
            acc.x = fmaf(ev[s], w.x, acc.x); acc.y = fmaf(ev[s], w.y, acc.y);
            acc.z = fmaf(ev[s], w.z, acc.z); acc.w = fmaf(ev[s], w.w, acc.w);
          }
        }
        const float4 va = *(const float4*)&cA[f][cq];
        const float4 vb = *(const float4*)&cB[t][cq];
        acc.x = fmaxf(acc.x + va.x + vb.x, 0.f);
        acc.y = fmaxf(acc.y + va.y + vb.y, 0.f);
        acc.z = fmaxf(acc.z + va.z + vb.z, 0.f);
        acc.w = fmaxf(acc.w + va.w + vb.w, 0.f);
        atomicAdd(&ag[t * 68 + cq + 0], acc.x);
        atomicAdd(&ag[t * 68 + cq + 1], acc.y);
        atomicAdd(&ag[t * 68 + cq + 2], acc.z);
        atomicAdd(&ag[t * 68 + cq + 3], acc.w);
      }
      __syncthreads();
    }
    // partial mw2 GEMM: aM[n][c] += sum_kk ag[n][kk] * mw2[col0+kk][c]
    {
      const int c0 = cg * 8;
#pragma unroll 2
      for (int kk = 0; kk < 64; ++kk) {
        const float4 w0 = *(const float4*)&mw2[(col0 + kk) * 128 + c0];
        const float4 w1 = *(const float4*)&mw2[(col0 + kk) * 128 + c0 + 4];
#pragma unroll
        for (int i = 0; i < 4; ++i) {
          const float x = ag[(n0 + i) * 68 + kk];
          aM[i][0] = fmaf(x, w0.x, aM[i][0]); aM[i][1] = fmaf(x, w0.y, aM[i][1]);
          aM[i][2] = fmaf(x, w0.z, aM[i][2]); aM[i][3] = fmaf(x, w0.w, aM[i][3]);
          aM[i][4] = fmaf(x, w1.x, aM[i][4]); aM[i][5] = fmaf(x, w1.y, aM[i][5]);
          aM[i][6] = fmaf(x, w1.z, aM[i][6]); aM[i][7] = fmaf(x, w1.w, aM[i][7]);
        }
      }
    }
  }
#pragma unroll
  for (int i = 0; i < 4; ++i) {
    *(float4*)&aggM[(long)(bn + n0 + i) * 128 + cg * 8]     = *(float4*)&aM[i][0];
    *(float4*)&aggM[(long)(bn + n0 + i) * 128 + cg * 8 + 4] = *(float4*)&aM[i][4];
  }
}

// ---------------------------------------------------------------------------
// tf = relu(parts5 @ t1w + t1b) @ t2w + t2b
__global__ void k_tfeat(const float* __restrict__ x,
                        const float* __restrict__ t1w, const float* __restrict__ t1b,
                        const float* __restrict__ t2w, const float* __restrict__ t2b,
                        float* __restrict__ tf) {
  __shared__ float xs[4][128];
  __shared__ float ys[4][64];
  const int tid = threadIdx.x;
  const long row0 = (long)blockIdx.x * 4;
  for (int i = tid; i < 512; i += 256)
    xs[i >> 7][i & 127] = x[(row0 + (i >> 7)) * 128 + (i & 127)];
  __syncthreads();
  const int r = tid >> 6, c = tid & 63;
  float acc = t1b[c];
#pragma unroll 4
  for (int k = 0; k < 128; ++k) acc = fmaf(xs[r][k], t1w[k * 64 + c], acc);
  ys[r][c] = fmaxf(acc, 0.f);
  __syncthreads();
  float a2 = t2b[c];
#pragma unroll 4
  for (int k = 0; k < 64; ++k) a2 = fmaf(ys[r][k], t2w[k * 64 + c], a2);
  tf[(row0 + r) * 64 + c] = a2;
}

// ---------------------------------------------------------------------------
__global__ void k_sim(const float* __restrict__ tf, float* __restrict__ sim) {
  const int b = blockIdx.x, tid = threadIdx.x;
  __shared__ float tq[64][65];
  __shared__ float tcs[64][65];
  for (int i = tid; i < 4096; i += 256) {
    tq[i >> 6][i & 63]  = tf[(long)b * 8192 + i];
    tcs[i >> 6][i & 63] = tf[(long)b * 8192 + 4096 + i];
  }
  __syncthreads();
  const int m = tid >> 2, j0 = (tid & 3) * 16;
#pragma unroll
  for (int j = 0; j < 16; ++j) {
    float a = 0.f;
#pragma unroll 4
    for (int k = 0; k < 64; ++k) a = fmaf(tq[m][k], tcs[j0 + j][k], a);
    sim[(long)b * 4096 + m * 64 + j0 + j] = a;
  }
}

// ---------------------------------------------------------------------------
// Sinkhorn in base-2: u = sim * 10*log2(e); 20x (row-LSE2, col-LSE2); plan = 2^u
__global__ void k_sink(float* __restrict__ sim, float* __restrict__ outp) {
  const int b = blockIdx.x, tid = threadIdx.x;
  __shared__ float la[64][65];
  const float C = 14.426950408889634f;   // 10 / ln(2)
  for (int i = tid; i < 4096; i += 256)
    la[i >> 6][i & 63] = sim[(long)b * 4096 + i] * C;
  __syncthreads();
  const int r4 = tid >> 2, l4 = tid & 3;
  for (int it = 0; it < 20; ++it) {
    { // rows
      float m = -3.4e38f;
#pragma unroll
      for (int i = 0; i < 16; ++i) m = fmaxf(m, la[r4][l4 + 4 * i]);
      m = fmaxf(m, __shfl_xor(m, 1)); m = fmaxf(m, __shfl_xor(m, 2));
      float s = 0.f;
#pragma unroll
      for (int i = 0; i < 16; ++i) s += exp2f(la[r4][l4 + 4 * i] - m);
      s += __shfl_xor(s, 1); s += __shfl_xor(s, 2);
      const float lse = m + log2f(s);
#pragma unroll
      for (int i = 0; i < 16; ++i) la[r4][l4 + 4 * i] -= lse;
    }
    __syncthreads();
    { // cols
      float m = -3.4e38f;
#pragma unroll
      for (int i = 0; i < 16; ++i) m = fmaxf(m, la[l4 + 4 * i][r4]);
      m = fmaxf(m, __shfl_xor(m, 1)); m = fmaxf(m, __shfl_xor(m, 2));
      float s = 0.f;
#pragma unroll
      for (int i = 0; i < 16; ++i) s += exp2f(la[l4 + 4 * i][r4] - m);
      s += __shfl_xor(s, 1); s += __shfl_xor(s, 2);
      const float lse = m + log2f(s);
#pragma unroll
      for (int i = 0; i < 16; ++i) la[l4 + 4 * i][r4] -= lse;
    }
    __syncthreads();
  }
  for (int i = tid; i < 4096; i += 256) {
    const float v = exp2f(la[i >> 6][i & 63]);
    outp[(long)b * 4096 + i] = v;
    sim[(long)b * 4096 + i] = v;
  }
}

// ---------------------------------------------------------------------------
// One p-slice of mixing: dst(q rows) = plan @ src(c rows); dst(c rows) = plan^T @ src(q rows)
__global__ void k_mix(const float* __restrict__ plan, const float* __restrict__ src,
                      float* __restrict__ dst) {
  const int b = blockIdx.x, tid = threadIdx.x;
  __shared__ float pl[64][65];
  __shared__ float qs[64][128];
  __shared__ float cs[64][128];
  const long qbase = (long)(2 * b) * 64, cbase = qbase + 64;
  for (int i = tid; i < 4096; i += 256) pl[i >> 6][i & 63] = plan[(long)b * 4096 + i];
  for (int i = tid; i < 8192; i += 256) {
    qs[i >> 7][i & 127] = src[qbase * 128 + i];
    cs[i >> 7][i & 127] = src[cbase * 128 + i];
  }
  __syncthreads();
  const int d = tid & 127, m0 = (tid >> 7) * 32;
  for (int m = m0; m < m0 + 32; ++m) {
    float a = 0.f;
#pragma unroll 4
    for (int j = 0; j < 64; ++j) a = fmaf(pl[m][j], cs[j][d], a);
    dst[(qbase + m) * 128 + d] = a;
  }
  for (int j = m0; j < m0 + 32; ++j) {
    float a = 0.f;
#pragma unroll 4
    for (int m = 0; m < 64; ++m) a = fmaf(pl[m][j], qs[m][d], a);
    dst[(cbase + j) * 128 + d] = a;
  }
}

// ---------------------------------------------------------------------------
extern "C" void kernel_launch(void* const* d_in, const int* in_sizes, int n_in,
                              void* d_out, int out_size, void* d_ws, size_t ws_size,
                              hipStream_t stream) {
  const float* nf  = (const float*)d_in[0];
  const float* ef  = (const float*)d_in[1];
  const int* from_idx = (const int*)d_in[2];
  const int* to_idx   = (const int*)d_in[3];
  const float* new_w = (const float*)d_in[4];
  const float* new_b = (const float*)d_in[5];
  const float* eew = (const float*)d_in[6];
  const float* eeb = (const float*)d_in[7];
  const float* mw1 = (const float*)d_in[8];
  const float* mb1 = (const float*)d_in[9];
  const float* mw2 = (const float*)d_in[10];
  const float* mb2 = (const float*)d_in[11];
  const float* nw1 = (const float*)d_in[12];
  const float* nb1 = (const float*)d_in[13];
  const float* nw2 = (const float*)d_in[14];
  const float* nb2 = (const float*)d_in[15];
  const float* cw1 = (const float*)d_in[16];
  const float* cb1 = (const float*)d_in[17];
  const float* cw2 = (const float*)d_in[18];
  const float* cb2 = (const float*)d_in[19];
  const float* t1w = (const float*)d_in[20];
  const float* t1b = (const float*)d_in[21];
  const float* t2w = (const float*)d_in[22];
  const float* t2b = (const float*)d_in[23];

  float* W = (float*)d_ws;
  float* h0     = W;                       // ND
  float* comb   = h0 + ND;                 // ND
  float* aggM   = comb + ND;               // ND (also tf @ +0, sim @ +2,097,152)
  float* parts  = aggM + ND;               // 5*ND (mixed[pi] aliased at slot pi+1)
  float* Wfold  = parts + 5 * ND;          // 4096
  float* bfold  = Wfold + 4096;            // 256
  float* vbias  = bfold + 256;             // 256
  int*   deg    = (int*)(vbias + 256);     // 32768
  float* tf     = aggM;                    // 32768*64 = 2,097,152
  float* sim    = aggM + 2097152;          // 256*4096 = 1,048,576
  float* outp   = (float*)d_out;

  k_prep<<<18, 256, 0, stream>>>(eew, eeb, mw1, mb1, mb2, nw1, Wfold, bfold, vbias);
  k_zero_deg<<<128, 256, 0, stream>>>(deg);
  k_degc<<<1024, 256, 0, stream>>>(to_idx, deg);
  k_node_enc<<<16384, 256, 0, stream>>>(nf, new_w, new_b, h0);

  for (int t = 0; t < 3; ++t) {
    const float* hprev = h0;
    for (int p = 1; p <= 5; ++p) {
      // inter = mixed[p-2], aliased at parts slot p-1 (read before node-MLP overwrites it)
      if (t > 0 && p > 1)
        k_mlp2g<128, false><<<1024, 256, 0, stream>>>(hprev, parts + (long)(p - 1) * ND,
                                                      cw1, cw1 + 128 * 256,
                                                      cb1, nullptr, nullptr, cw2, cb2, comb);
      else
        k_mlp2g<0, false><<<1024, 256, 0, stream>>>(hprev, nullptr, cw1, nullptr,
                                                    cb1, nullptr, nullptr, cw2, cb2, comb);
      k_edge<<<512, 256, 0, stream>>>(comb, ef, mw1, mw2, Wfold, bfold,
                                      from_idx, to_idx, aggM);
      float* hnew = parts + (long)(p - 1) * ND;
      k_mlp2g<128, true><<<1024, 256, 0, stream>>>(comb, aggM, nw1, nw1 + 128 * 256,
                                                   nb1, deg, vbias, nw2, nb2, hnew);
      hprev = hnew;
    }
    k_tfeat<<<8192, 256, 0, stream>>>(parts + 4 * ND, t1w, t1b, t2w, t2b, tf);
    k_sim<<<256, 256, 0, stream>>>(tf, sim);
    k_sink<<<256, 256, 0, stream>>>(sim, outp);
    if (t < 2) {
      // mixed[pi] -> parts slot pi+1; run pi=3..0 so each slot is read before overwrite
      for (int pi = 3; pi >= 0; --pi)
        k_mix<<<256, 256, 0, stream>>>(sim, parts + (long)pi * ND, parts + (long)(pi + 1) * ND);
    }
  }
}

// Round 4
// 6775.768 us; speedup vs baseline: 3.3726x; 1.5456x over previous
//
#include <hip/hip_runtime.h>
#include <hip/hip_bf16.h>

#define NNODES   32768
#define NGROUPS  512
#define EPG      512
#define ND       (32768l*128)

// ---------------------------------------------------------------------------
// h0 = node_features(32768x32) @ W(32x128) + b
__global__ void k_node_enc(const float* __restrict__ nf, const float* __restrict__ w,
                           const float* __restrict__ b, float* __restrict__ h0) {
  int idx = blockIdx.x * 256 + threadIdx.x;
  int row = idx >> 7, col = idx & 127;
  const float* x = nf + row * 32;
  float acc = b[col];
#pragma unroll
  for (int k = 0; k < 32; ++k) acc = fmaf(x[k], w[k * 128 + col], acc);
  h0[idx] = acc;
}

// ---------------------------------------------------------------------------
// Folded weights:
//  blocks 0..15 : Wfold[16][256] = eew(16x64) @ mw1[256:320,:]
//  block  16    : bfold[256]     = eeb @ mw1[256:320,:] + mb1
//  block  17    : vbias[256]     = mb2 @ nw1[128:256,:]
__global__ void k_prep(const float* __restrict__ eew, const float* __restrict__ eeb,
                       const float* __restrict__ mw1, const float* __restrict__ mb1,
                       const float* __restrict__ mb2, const float* __restrict__ nw1,
                       float* __restrict__ Wfold, float* __restrict__ bfold,
                       float* __restrict__ vbias) {
  const int c = threadIdx.x, b = blockIdx.x;
  if (b < 16) {
    float a = 0.f;
    for (int j = 0; j < 64; ++j) a = fmaf(eew[b * 64 + j], mw1[(256 + j) * 256 + c], a);
    Wfold[b * 256 + c] = a;
  } else if (b == 16) {
    float a = mb1[c];
    for (int j = 0; j < 64; ++j) a = fmaf(eeb[j], mw1[(256 + j) * 256 + c], a);
    bfold[c] = a;
  } else {
    float a = 0.f;
    for (int j = 0; j < 128; ++j) a = fmaf(mb2[j], nw1[(128 + j) * 256 + c], a);
    vbias[c] = a;
  }
}

// ---------------------------------------------------------------------------
// Deterministic CSR per group: edges stably sorted by to-node.
__global__ void k_csr(const int* __restrict__ from_idx, const int* __restrict__ to_idx,
                      const float* __restrict__ ef,
                      int* __restrict__ csr_f, int* __restrict__ rp_g,
                      float* __restrict__ efp, int* __restrict__ deg) {
  __shared__ int cnt[64], rps[65];
  __shared__ int tls[EPG], fls[EPG];
  __shared__ short ord[EPG];
  const int g = blockIdx.x, tid = threadIdx.x;
  const int be = g * EPG, bn = g * 64;
  if (tid < 64) cnt[tid] = 0;
  __syncthreads();
  for (int e = tid; e < EPG; e += 256) {
    int t = to_idx[be + e] - bn;
    tls[e] = t;
    fls[e] = from_idx[be + e] - bn;
    atomicAdd(&cnt[t], 1);
  }
  __syncthreads();
  if (tid == 0) {
    int s = 0;
    for (int i = 0; i < 64; ++i) { rps[i] = s; s += cnt[i]; }
    rps[64] = s;
  }
  __syncthreads();
  if (tid < 64) {   // stable scatter: node tid picks its edges in original order
    int pos = rps[tid];
    for (int e = 0; e < EPG; ++e)
      if (tls[e] == tid) ord[pos++] = (short)e;
  }
  __syncthreads();
  for (int ec = tid; ec < EPG; ec += 256) {
    const int eo = ord[ec];
    csr_f[be + ec] = fls[eo];
    const float4* src = (const float4*)&ef[(long)(be + eo) * 16];
    float4* dst = (float4*)&efp[(long)(be + ec) * 16];
    dst[0] = src[0]; dst[1] = src[1]; dst[2] = src[2]; dst[3] = src[3];
  }
  if (tid < 65) rp_g[g * 65 + tid] = rps[tid];
  if (tid < 64) deg[bn + tid] = cnt[tid];
}

// ---------------------------------------------------------------------------
// Unified 2-layer MLP: out = relu(x0@W1a + x1@W1b + bias)@W2 + b2
// x1 may be a sum of two buffers (x1b). bias = b1 (+ deg*vbias if DEG).
template<int K1, bool DEG>
__global__ __launch_bounds__(256, 4)
void k_mlp2g(const float* __restrict__ x0, const float* __restrict__ x1,
             const float* __restrict__ x1b,
             const float* __restrict__ W1a, const float* __restrict__ W1b,
             const float* __restrict__ b1, const int* __restrict__ deg,
             const float* __restrict__ vbias,
             const float* __restrict__ W2, const float* __restrict__ b2,
             float* __restrict__ out) {
  __shared__ __align__(16) float buf[256][36];
  const int tid = threadIdx.x;
  const int row0 = blockIdx.x * 32;

  for (int i = tid; i < 1024; i += 256) {
    const int n = i & 31, q = i >> 5;
    float4 v = *(const float4*)&x0[(long)(row0 + n) * 128 + q * 4];
    buf[q*4+0][n] = v.x; buf[q*4+1][n] = v.y; buf[q*4+2][n] = v.z; buf[q*4+3][n] = v.w;
  }
  if constexpr (K1 == 128) {
    for (int i = tid; i < 1024; i += 256) {
      const int n = i & 31, q = i >> 5;
      float4 v = *(const float4*)&x1[(long)(row0 + n) * 128 + q * 4];
      if (x1b) {
        float4 w = *(const float4*)&x1b[(long)(row0 + n) * 128 + q * 4];
        v.x += w.x; v.y += w.y; v.z += w.z; v.w += w.w;
      }
      buf[128+q*4+0][n] = v.x; buf[128+q*4+1][n] = v.y;
      buf[128+q*4+2][n] = v.z; buf[128+q*4+3][n] = v.w;
    }
  }
  __syncthreads();

  const int tc = tid & 63, rg = tid >> 6;
  const int c0 = tc * 4, r0 = rg * 8;

  float acc[8][4];
  {
    const float4 bv = *(const float4*)&b1[c0];
    if constexpr (DEG) {
      const float4 vb = *(const float4*)&vbias[c0];
#pragma unroll
      for (int r = 0; r < 8; ++r) {
        const float dv = (float)deg[row0 + r0 + r];
        acc[r][0] = fmaf(dv, vb.x, bv.x); acc[r][1] = fmaf(dv, vb.y, bv.y);
        acc[r][2] = fmaf(dv, vb.z, bv.z); acc[r][3] = fmaf(dv, vb.w, bv.w);
      }
    } else {
#pragma unroll
      for (int r = 0; r < 8; ++r) {
        acc[r][0] = bv.x; acc[r][1] = bv.y; acc[r][2] = bv.z; acc[r][3] = bv.w;
      }
    }
  }

#pragma unroll 4
  for (int k = 0; k < 128; ++k) {
    const float4 xa = *(const float4*)&buf[k][r0];
    const float4 xb = *(const float4*)&buf[k][r0 + 4];
    const float4 wv = *(const float4*)&W1a[k * 256 + c0];
    const float xs_[8] = {xa.x, xa.y, xa.z, xa.w, xb.x, xb.y, xb.z, xb.w};
#pragma unroll
    for (int r = 0; r < 8; ++r) {
      acc[r][0] = fmaf(xs_[r], wv.x, acc[r][0]);
      acc[r][1] = fmaf(xs_[r], wv.y, acc[r][1]);
      acc[r][2] = fmaf(xs_[r], wv.z, acc[r][2]);
      acc[r][3] = fmaf(xs_[r], wv.w, acc[r][3]);
    }
  }
  if constexpr (K1 > 0) {
#pragma unroll 4
    for (int k = 0; k < K1; ++k) {
      const float4 xa = *(const float4*)&buf[128 + k][r0];
      const float4 xb = *(const float4*)&buf[128 + k][r0 + 4];
      const float4 wv = *(const float4*)&W1b[k * 256 + c0];
      const float xs_[8] = {xa.x, xa.y, xa.z, xa.w, xb.x, xb.y, xb.z, xb.w};
#pragma unroll
      for (int r = 0; r < 8; ++r) {
        acc[r][0] = fmaf(xs_[r], wv.x, acc[r][0]);
        acc[r][1] = fmaf(xs_[r], wv.y, acc[r][1]);
        acc[r][2] = fmaf(xs_[r], wv.z, acc[r][2]);
        acc[r][3] = fmaf(xs_[r], wv.w, acc[r][3]);
      }
    }
  }
  __syncthreads();
#pragma unroll
  for (int j = 0; j < 4; ++j) {
    float4 lo = make_float4(fmaxf(acc[0][j],0.f), fmaxf(acc[1][j],0.f),
                            fmaxf(acc[2][j],0.f), fmaxf(acc[3][j],0.f));
    float4 hi = make_float4(fmaxf(acc[4][j],0.f), fmaxf(acc[5][j],0.f),
                            fmaxf(acc[6][j],0.f), fmaxf(acc[7][j],0.f));
    *(float4*)&buf[c0 + j][r0]     = lo;
    *(float4*)&buf[c0 + j][r0 + 4] = hi;
  }
  __syncthreads();

  const int c20 = tc * 2;
  float a2[8][2];
#pragma unroll
  for (int r = 0; r < 8; ++r) { a2[r][0] = b2[c20]; a2[r][1] = b2[c20 + 1]; }
#pragma unroll 4
  for (int k = 0; k < 256; ++k) {
    const float4 xa = *(const float4*)&buf[k][r0];
    const float4 xb = *(const float4*)&buf[k][r0 + 4];
    const float2 wv = *(const float2*)&W2[k * 128 + c20];
    const float xs_[8] = {xa.x, xa.y, xa.z, xa.w, xb.x, xb.y, xb.z, xb.w};
#pragma unroll
    for (int r = 0; r < 8; ++r) {
      a2[r][0] = fmaf(xs_[r], wv.x, a2[r][0]);
      a2[r][1] = fmaf(xs_[r], wv.y, a2[r][1]);
    }
  }
#pragma unroll
  for (int r = 0; r < 8; ++r) {
    float2 v = make_float2(a2[r][0], a2[r][1]);
    *(float2*)&out[(long)(row0 + r0 + r) * 128 + c20] = v;
  }
}

// ---------------------------------------------------------------------------
// Fused per-group edge pipeline, CSR-based, atomic-free. grid (512, 2).
__global__ __launch_bounds__(256, 3)
void k_edge(const float* __restrict__ comb, const float* __restrict__ efp,
            const float* __restrict__ mw1, const float* __restrict__ mw2,
            const float* __restrict__ Wfold, const float* __restrict__ bfold,
            const int* __restrict__ csr_f, const int* __restrict__ rp_g,
            float* __restrict__ aggM) {
  __shared__ __align__(16) float cA[64 * 64];
  __shared__ __align__(16) float U[128 * 64];   // ct[128][64] | ag[64][64]
  __shared__ int fl[EPG];
  __shared__ int rp[65];
  float* ct = U;
  float* ag = U;

  const int tid = threadIdx.x;
  const int g = blockIdx.x, half = blockIdx.y;
  const int be = g * EPG, bn = g * 64;

  for (int i = tid; i < EPG; i += 256) fl[i] = csr_f[be + i];
  if (tid < 65) rp[tid] = rp_g[g * 65 + tid];

  const int ng = tid >> 4, cg = tid & 15;
  const int n0 = ng * 4, cq = cg * 4;

  float aM[4][8];
#pragma unroll
  for (int i = 0; i < 4; ++i)
#pragma unroll
    for (int j = 0; j < 8; ++j) aM[i][j] = 0.f;

  for (int cbi = 0; cbi < 2; ++cbi) {
    const int col0 = (half * 2 + cbi) * 64;
    __syncthreads();   // prev mw2 ag-reads done (and fl/rp ready) before U overwrite
    for (int i = tid; i < 2048; i += 256) {
      const int n = i & 63, q = i >> 6;
      float4 v = *(const float4*)&comb[(long)(bn + n) * 128 + q * 4];
      ct[(q*4+0)*64 + n] = v.x; ct[(q*4+1)*64 + n] = v.y;
      ct[(q*4+2)*64 + n] = v.z; ct[(q*4+3)*64 + n] = v.w;
    }
    __syncthreads();
    float accA[4][4], accB[4][4];
#pragma unroll
    for (int i = 0; i < 4; ++i)
#pragma unroll
      for (int j = 0; j < 4; ++j) { accA[i][j] = 0.f; accB[i][j] = 0.f; }
    {
      const int c0 = col0 + cq;
#pragma unroll 2
      for (int k = 0; k < 128; ++k) {
        const float4 xv = *(const float4*)&ct[k * 64 + n0];
        const float4 wa = *(const float4*)&mw1[k * 256 + c0];
        const float4 wb = *(const float4*)&mw1[(128 + k) * 256 + c0];
        const float xs_[4] = {xv.x, xv.y, xv.z, xv.w};
#pragma unroll
        for (int i = 0; i < 4; ++i) {
          accA[i][0] = fmaf(xs_[i], wa.x, accA[i][0]);
          accA[i][1] = fmaf(xs_[i], wa.y, accA[i][1]);
          accA[i][2] = fmaf(xs_[i], wa.z, accA[i][2]);
          accA[i][3] = fmaf(xs_[i], wa.w, accA[i][3]);
          accB[i][0] = fmaf(xs_[i], wb.x, accB[i][0]);
          accB[i][1] = fmaf(xs_[i], wb.y, accB[i][1]);
          accB[i][2] = fmaf(xs_[i], wb.z, accB[i][2]);
          accB[i][3] = fmaf(xs_[i], wb.w, accB[i][3]);
        }
      }
    }
    __syncthreads();   // ct reads done before ag writes (aliased)
#pragma unroll
    for (int i = 0; i < 4; ++i)
      *(float4*)&cA[(n0 + i) * 64 + cq] =
        make_float4(accA[i][0], accA[i][1], accA[i][2], accA[i][3]);
    float4 Wf[16];
#pragma unroll
    for (int k = 0; k < 16; ++k) Wf[k] = *(const float4*)&Wfold[k * 256 + col0 + cq];
    const float4 bf = *(const float4*)&bfold[col0 + cq];
    __syncthreads();   // cA visible

#pragma unroll
    for (int i = 0; i < 4; ++i) {
      const int n = n0 + i;
      float4 acc = make_float4(0.f, 0.f, 0.f, 0.f);
      const float4 cB = make_float4(accB[i][0], accB[i][1], accB[i][2], accB[i][3]);
      const int e1 = rp[n + 1];
      for (int e = rp[n]; e < e1; ++e) {
        const int f = fl[e];
        const float* er = efp + (long)(be + e) * 16;
        float4 h = bf;
#pragma unroll
        for (int kq = 0; kq < 4; ++kq) {
          const float4 e4 = *(const float4*)(er + kq * 4);
          const float ev[4] = {e4.x, e4.y, e4.z, e4.w};
#pragma unroll
          for (int s = 0; s < 4; ++s) {
            const float4 w = Wf[kq * 4 + s];
            h.x = fmaf(ev[s], w.x, h.x); h.y = fmaf(ev[s], w.y, h.y);
            h.z = fmaf(ev[s], w.z, h.z); h.w = fmaf(ev[s], w.w, h.w);
          }
        }
        const float4 va = *(const float4*)&cA[f * 64 + cq];
        acc.x += fmaxf(h.x + va.x + cB.x, 0.f);
        acc.y += fmaxf(h.y + va.y + cB.y, 0.f);
        acc.z += fmaxf(h.z + va.z + cB.z, 0.f);
        acc.w += fmaxf(h.w + va.w + cB.w, 0.f);
      }
      *(float4*)&ag[n * 64 + cq] = acc;
    }
    __syncthreads();   // ag complete

    {
      const int c2 = cg * 8;
#pragma unroll 2
      for (int kk = 0; kk < 64; ++kk) {
        const float4 w0 = *(const float4*)&mw2[(col0 + kk) * 128 + c2];
        const float4 w1 = *(const float4*)&mw2[(col0 + kk) * 128 + c2 + 4];
#pragma unroll
        for (int i = 0; i < 4; ++i) {
          const float x = ag[(n0 + i) * 64 + kk];
          aM[i][0] = fmaf(x, w0.x, aM[i][0]); aM[i][1] = fmaf(x, w0.y, aM[i][1]);
          aM[i][2] = fmaf(x, w0.z, aM[i][2]); aM[i][3] = fmaf(x, w0.w, aM[i][3]);
          aM[i][4] = fmaf(x, w1.x, aM[i][4]); aM[i][5] = fmaf(x, w1.y, aM[i][5]);
          aM[i][6] = fmaf(x, w1.z, aM[i][6]); aM[i][7] = fmaf(x, w1.w, aM[i][7]);
        }
      }
    }
  }
  float* aggMh = aggM + (long)half * ND;
#pragma unroll
  for (int i = 0; i < 4; ++i) {
    *(float4*)&aggMh[(long)(bn + n0 + i) * 128 + cg * 8]     = *(float4*)&aM[i][0];
    *(float4*)&aggMh[(long)(bn + n0 + i) * 128 + cg * 8 + 4] = *(float4*)&aM[i][4];
  }
}

// ---------------------------------------------------------------------------
__global__ void k_tfeat(const float* __restrict__ x,
                        const float* __restrict__ t1w, const float* __restrict__ t1b,
                        const float* __restrict__ t2w, const float* __restrict__ t2b,
                        float* __restrict__ tf) {
  __shared__ float xs[4][128];
  __shared__ float ys[4][64];
  const int tid = threadIdx.x;
  const long row0 = (long)blockIdx.x * 4;
  for (int i = tid; i < 512; i += 256)
    xs[i >> 7][i & 127] = x[(row0 + (i >> 7)) * 128 + (i & 127)];
  __syncthreads();
  const int r = tid >> 6, c = tid & 63;
  float acc = t1b[c];
#pragma unroll 4
  for (int k = 0; k < 128; ++k) acc = fmaf(xs[r][k], t1w[k * 64 + c], acc);
  ys[r][c] = fmaxf(acc, 0.f);
  __syncthreads();
  float a2 = t2b[c];
#pragma unroll 4
  for (int k = 0; k < 64; ++k) a2 = fmaf(ys[r][k], t2w[k * 64 + c], a2);
  tf[(row0 + r) * 64 + c] = a2;
}

// ---------------------------------------------------------------------------
__global__ void k_sim(const float* __restrict__ tf, float* __restrict__ sim) {
  const int b = blockIdx.x, tid = threadIdx.x;
  __shared__ float tq[64][65];
  __shared__ float tcs[64][65];
  for (int i = tid; i < 4096; i += 256) {
    tq[i >> 6][i & 63]  = tf[(long)b * 8192 + i];
    tcs[i >> 6][i & 63] = tf[(long)b * 8192 + 4096 + i];
  }
  __syncthreads();
  const int m = tid >> 2, j0 = (tid & 3) * 16;
#pragma unroll
  for (int j = 0; j < 16; ++j) {
    float a = 0.f;
#pragma unroll 4
    for (int k = 0; k < 64; ++k) a = fmaf(tq[m][k], tcs[j0 + j][k], a);
    sim[(long)b * 4096 + m * 64 + j0 + j] = a;
  }
}

// ---------------------------------------------------------------------------
__global__ void k_sink(float* __restrict__ sim, float* __restrict__ outp) {
  const int b = blockIdx.x, tid = threadIdx.x;
  __shared__ float la[64][65];
  const float C = 14.426950408889634f;   // 10 / ln(2)
  for (int i = tid; i < 4096; i += 256)
    la[i >> 6][i & 63] = sim[(long)b * 4096 + i] * C;
  __syncthreads();
  const int r4 = tid >> 2, l4 = tid & 3;
  for (int it = 0; it < 20; ++it) {
    {
      float m = -3.4e38f;
#pragma unroll
      for (int i = 0; i < 16; ++i) m = fmaxf(m, la[r4][l4 + 4 * i]);
      m = fmaxf(m, __shfl_xor(m, 1)); m = fmaxf(m, __shfl_xor(m, 2));
      float s = 0.f;
#pragma unroll
      for (int i = 0; i < 16; ++i) s += exp2f(la[r4][l4 + 4 * i] - m);
      s += __shfl_xor(s, 1); s += __shfl_xor(s, 2);
      const float lse = m + log2f(s);
#pragma unroll
      for (int i = 0; i < 16; ++i) la[r4][l4 + 4 * i] -= lse;
    }
    __syncthreads();
    {
      float m = -3.4e38f;
#pragma unroll
      for (int i = 0; i < 16; ++i) m = fmaxf(m, la[l4 + 4 * i][r4]);
      m = fmaxf(m, __shfl_xor(m, 1)); m = fmaxf(m, __shfl_xor(m, 2));
      float s = 0.f;
#pragma unroll
      for (int i = 0; i < 16; ++i) s += exp2f(la[l4 + 4 * i][r4] - m);
      s += __shfl_xor(s, 1); s += __shfl_xor(s, 2);
      const float lse = m + log2f(s);
#pragma unroll
      for (int i = 0; i < 16; ++i) la[l4 + 4 * i][r4] -= lse;
    }
    __syncthreads();
  }
  for (int i = tid; i < 4096; i += 256) {
    const float v = exp2f(la[i >> 6][i & 63]);
    outp[(long)b * 4096 + i] = v;
    sim[(long)b * 4096 + i] = v;
  }
}

// ---------------------------------------------------------------------------
__global__ void k_mix(const float* __restrict__ plan, const float* __restrict__ src,
                      float* __restrict__ dst) {
  const int b = blockIdx.x, tid = threadIdx.x;
  __shared__ float pl[64][65];
  __shared__ float qs[64][128];
  __shared__ float cs[64][128];
  const long qbase = (long)(2 * b) * 64, cbase = qbase + 64;
  for (int i = tid; i < 4096; i += 256) pl[i >> 6][i & 63] = plan[(long)b * 4096 + i];
  for (int i = tid; i < 8192; i += 256) {
    qs[i >> 7][i & 127] = src[qbase * 128 + i];
    cs[i >> 7][i & 127] = src[cbase * 128 + i];
  }
  __syncthreads();
  const int d = tid & 127, m0 = (tid >> 7) * 32;
  for (int m = m0; m < m0 + 32; ++m) {
    float a = 0.f;
#pragma unroll 4
    for (int j = 0; j < 64; ++j) a = fmaf(pl[m][j], cs[j][d], a);
    dst[(qbase + m) * 128 + d] = a;
  }
  for (int j = m0; j < m0 + 32; ++j) {
    float a = 0.f;
#pragma unroll 4
    for (int m = 0; m < 64; ++m) a = fmaf(pl[m][j], qs[m][d], a);
    dst[(cbase + j) * 128 + d] = a;
  }
}

// ---------------------------------------------------------------------------
extern "C" void kernel_launch(void* const* d_in, const int* in_sizes, int n_in,
                              void* d_out, int out_size, void* d_ws, size_t ws_size,
                              hipStream_t stream) {
  const float* nf  = (const float*)d_in[0];
  const float* ef  = (const float*)d_in[1];
  const int* from_idx = (const int*)d_in[2];
  const int* to_idx   = (const int*)d_in[3];
  const float* new_w = (const float*)d_in[4];
  const float* new_b = (const float*)d_in[5];
  const float* eew = (const float*)d_in[6];
  const float* eeb = (const float*)d_in[7];
  const float* mw1 = (const float*)d_in[8];
  const float* mb1 = (const float*)d_in[9];
  const float* mw2 = (const float*)d_in[10];
  const float* mb2 = (const float*)d_in[11];
  const float* nw1 = (const float*)d_in[12];
  const float* nb1 = (const float*)d_in[13];
  const float* nw2 = (const float*)d_in[14];
  const float* nb2 = (const float*)d_in[15];
  const float* cw1 = (const float*)d_in[16];
  const float* cb1 = (const float*)d_in[17];
  const float* cw2 = (const float*)d_in[18];
  const float* cb2 = (const float*)d_in[19];
  const float* t1w = (const float*)d_in[20];
  const float* t1b = (const float*)d_in[21];
  const float* t2w = (const float*)d_in[22];
  const float* t2b = (const float*)d_in[23];

  float* W = (float*)d_ws;
  float* h0     = W;                       // ND
  float* comb   = h0 + ND;                 // ND
  float* aggM0  = comb + ND;               // ND (tf/sim alias here)
  float* aggM1  = aggM0 + ND;              // ND
  float* parts  = aggM1 + ND;              // 5*ND
  float* efp    = parts + 5 * ND;          // 262144*16
  float* Wfold  = efp + 262144l * 16;      // 4096
  float* bfold  = Wfold + 4096;            // 256
  float* vbias  = bfold + 256;             // 256
  int*   deg    = (int*)(vbias + 256);     // 32768
  int*   csr_f  = deg + 32768;             // 262144
  int*   rp_g   = csr_f + 262144;          // 512*65
  float* tf     = aggM0;                   // 32768*64
  float* sim    = aggM0 + 2097152;         // 256*4096
  float* outp   = (float*)d_out;

  k_prep<<<18, 256, 0, stream>>>(eew, eeb, mw1, mb1, mb2, nw1, Wfold, bfold, vbias);
  k_csr<<<512, 256, 0, stream>>>(from_idx, to_idx, ef, csr_f, rp_g, efp, deg);
  k_node_enc<<<16384, 256, 0, stream>>>(nf, new_w, new_b, h0);

  for (int t = 0; t < 3; ++t) {
    const float* hprev = h0;
    for (int p = 1; p <= 5; ++p) {
      if (t > 0 && p > 1)
        k_mlp2g<128, false><<<1024, 256, 0, stream>>>(hprev, parts + (long)(p - 1) * ND,
                                                      nullptr, cw1, cw1 + 128 * 256,
                                                      cb1, nullptr, nullptr, cw2, cb2, comb);
      else
        k_mlp2g<0, false><<<1024, 256, 0, stream>>>(hprev, nullptr, nullptr, cw1, nullptr,
                                                    cb1, nullptr, nullptr, cw2, cb2, comb);
      k_edge<<<dim3(512, 2), 256, 0, stream>>>(comb, efp, mw1, mw2, Wfold, bfold,
                                               csr_f, rp_g, aggM0);
      float* hnew = parts + (long)(p - 1) * ND;
      k_mlp2g<128, true><<<1024, 256, 0, stream>>>(comb, aggM0, aggM1,
                                                   nw1, nw1 + 128 * 256,
                                                   nb1, deg, vbias, nw2, nb2, hnew);
      hprev = hnew;
    }
    k_tfeat<<<8192, 256, 0, stream>>>(parts + 4 * ND, t1w, t1b, t2w, t2b, tf);
    k_sim<<<256, 256, 0, stream>>>(tf, sim);
    k_sink<<<256, 256, 0, stream>>>(sim, outp);
    if (t < 2) {
      for (int pi = 3; pi >= 0; --pi)
        k_mix<<<256, 256, 0, stream>>>(sim, parts + (long)pi * ND, parts + (long)(pi + 1) * ND);
    }
  }
}

// Round 6
// 6684.990 us; speedup vs baseline: 3.4184x; 1.0136x over previous
//
#include <hip/hip_runtime.h>
#include <hip/hip_bf16.h>

#define NNODES   32768
#define NGROUPS  512
#define EPG      512
#define ND       (32768l*128)

typedef __attribute__((ext_vector_type(4))) float f32x4;
typedef __attribute__((ext_vector_type(8))) short bf16x8;

__device__ __forceinline__ short f2bf(float x) {
  unsigned u = __float_as_uint(x);
  unsigned r = (u + 0x7FFF + ((u >> 16) & 1)) >> 16;   // RNE
  return (short)r;
}
__device__ __forceinline__ float bf2f(short h) {
  return __uint_as_float(((unsigned)(unsigned short)h) << 16);
}
// 3-term bf16 split: x ~= h + m + l  (covers ~24 mantissa bits)
__device__ __forceinline__ void split3(float x, short* ph, short* pm, short* pl, int idx) {
  short h = f2bf(x); float r1 = x - bf2f(h);
  short m = f2bf(r1); float r2 = r1 - bf2f(m);
  ph[idx] = h; pm[idx] = m; pl[idx] = f2bf(r2);
}

// ---------------------------------------------------------------------------
// h0 = node_features(32768x32) @ W(32x128) + b
__global__ void k_node_enc(const float* __restrict__ nf, const float* __restrict__ w,
                           const float* __restrict__ b, float* __restrict__ h0) {
  int idx = blockIdx.x * 256 + threadIdx.x;
  int row = idx >> 7, col = idx & 127;
  const float* x = nf + row * 32;
  float acc = b[col];
#pragma unroll
  for (int k = 0; k < 32; ++k) acc = fmaf(x[k], w[k * 128 + col], acc);
  h0[idx] = acc;
}

// ---------------------------------------------------------------------------
// Folded weights (fp32):
//  blocks 0..15 : Wfold[16][256] = eew(16x64) @ mw1[256:320,:]
//  block  16    : bfold[256]     = eeb @ mw1[256:320,:] + mb1
//  block  17    : vbias[256]     = mb2 @ nw1[128:256,:]
__global__ void k_prep(const float* __restrict__ eew, const float* __restrict__ eeb,
                       const float* __restrict__ mw1, const float* __restrict__ mb1,
                       const float* __restrict__ mb2, const float* __restrict__ nw1,
                       float* __restrict__ Wfold, float* __restrict__ bfold,
                       float* __restrict__ vbias) {
  const int c = threadIdx.x, b = blockIdx.x;
  if (b < 16) {
    float a = 0.f;
    for (int j = 0; j < 64; ++j) a = fmaf(eew[b * 64 + j], mw1[(256 + j) * 256 + c], a);
    Wfold[b * 256 + c] = a;
  } else if (b == 16) {
    float a = mb1[c];
    for (int j = 0; j < 64; ++j) a = fmaf(eeb[j], mw1[(256 + j) * 256 + c], a);
    bfold[c] = a;
  } else {
    float a = 0.f;
    for (int j = 0; j < 128; ++j) a = fmaf(mb2[j], nw1[(128 + j) * 256 + c], a);
    vbias[c] = a;
  }
}

// ---------------------------------------------------------------------------
// Weight transpose + bf16x3 split: W (Kd x C row-major) -> Wt[c][k] stride 256, 3 planes
__global__ void k_wsplit3(const float* __restrict__ W, int C, int Kd,
                          short* __restrict__ th, short* __restrict__ tm,
                          short* __restrict__ tl) {
  const int c = blockIdx.x;
  for (int k = threadIdx.x; k < Kd; k += 256) {
    float w = W[(long)k * C + c];
    split3(w, th, tm, tl, c * 256 + k);
  }
}

// ---------------------------------------------------------------------------
// Deterministic CSR per group: edges stably sorted by to-node.
__global__ void k_csr(const int* __restrict__ from_idx, const int* __restrict__ to_idx,
                      const float* __restrict__ ef,
                      int* __restrict__ csr_f, int* __restrict__ rp_g,
                      float* __restrict__ efp, int* __restrict__ deg) {
  __shared__ int cnt[64], rps[65];
  __shared__ int tls[EPG], fls[EPG];
  __shared__ short ord[EPG];
  const int g = blockIdx.x, tid = threadIdx.x;
  const int be = g * EPG, bn = g * 64;
  if (tid < 64) cnt[tid] = 0;
  __syncthreads();
  for (int e = tid; e < EPG; e += 256) {
    int t = to_idx[be + e] - bn;
    tls[e] = t;
    fls[e] = from_idx[be + e] - bn;
    atomicAdd(&cnt[t], 1);
  }
  __syncthreads();
  if (tid == 0) {
    int s = 0;
    for (int i = 0; i < 64; ++i) { rps[i] = s; s += cnt[i]; }
    rps[64] = s;
  }
  __syncthreads();
  if (tid < 64) {
    int pos = rps[tid];
    for (int e = 0; e < EPG; ++e)
      if (tls[e] == tid) ord[pos++] = (short)e;
  }
  __syncthreads();
  for (int ec = tid; ec < EPG; ec += 256) {
    const int eo = ord[ec];
    csr_f[be + ec] = fls[eo];
    const float4* src = (const float4*)&ef[(long)(be + eo) * 16];
    float4* dst = (float4*)&efp[(long)(be + ec) * 16];
    dst[0] = src[0]; dst[1] = src[1]; dst[2] = src[2]; dst[3] = src[3];
  }
  if (tid < 65) rp_g[g * 65 + tid] = rps[tid];
  if (tid < 64) deg[bn + tid] = cnt[tid];
}

// ---------------------------------------------------------------------------
// MFMA bf16x3 2-layer MLP: out = relu(X@W1 + bias)@W2 + b2  (fp32-equivalent)
// X = [x0 | x1(+x1b)] (KTOT cols). W planes: [col][k] bf16, k-stride 256.
// Block: 32 rows, 4 waves; wave w: L1 cols [64w,64w+64), L2 cols [32w,32w+32).
// 6 MFMA products per fragment pair: hh, hm, mh, hl, mm, lh  (error ~2^-24).
template<int KTOT, bool DEG, bool SUM2>
__global__ __launch_bounds__(256, 2)
void k_mlp2m(const float* __restrict__ x0, const float* __restrict__ x1,
             const float* __restrict__ x1b,
             const short* __restrict__ W1h, const short* __restrict__ W1m,
             const short* __restrict__ W1l,
             const float* __restrict__ b1, const int* __restrict__ deg,
             const float* __restrict__ vbias,
             const short* __restrict__ W2h, const short* __restrict__ W2m,
             const short* __restrict__ W2l,
             const float* __restrict__ b2, float* __restrict__ out) {
  __shared__ short xh[32 * 264];
  __shared__ short xm[32 * 264];
  __shared__ short xl[32 * 264];
  __shared__ int degs[32];
  const int tid = threadIdx.x;
  const long row0 = (long)blockIdx.x * 32;

  // stage x0 (cols 0..127), split to 3 planes
  for (int i = tid; i < 32 * 32; i += 256) {
    const int r = i >> 5, q = i & 31;
    float4 v = *(const float4*)&x0[(row0 + r) * 128 + q * 4];
    const int base = r * 264 + q * 4;
    split3(v.x, xh, xm, xl, base + 0);
    split3(v.y, xh, xm, xl, base + 1);
    split3(v.z, xh, xm, xl, base + 2);
    split3(v.w, xh, xm, xl, base + 3);
  }
  if constexpr (KTOT == 256) {
    for (int i = tid; i < 32 * 32; i += 256) {
      const int r = i >> 5, q = i & 31;
      float4 v = *(const float4*)&x1[(row0 + r) * 128 + q * 4];
      if constexpr (SUM2) {
        float4 w = *(const float4*)&x1b[(row0 + r) * 128 + q * 4];
        v.x += w.x; v.y += w.y; v.z += w.z; v.w += w.w;
      }
      const int base = r * 264 + 128 + q * 4;
      split3(v.x, xh, xm, xl, base + 0);
      split3(v.y, xh, xm, xl, base + 1);
      split3(v.z, xh, xm, xl, base + 2);
      split3(v.w, xh, xm, xl, base + 3);
    }
  }
  if constexpr (DEG) { if (tid < 32) degs[tid] = deg[row0 + tid]; }
  __syncthreads();

  const int lane = tid & 63, wid = tid >> 6;
  const int lr = lane & 15;              // M/N index within fragment
  const int lk = (lane >> 4) * 8;        // K offset within fragment
  const int rsub = (lane >> 4) * 4;      // D-row sub-offset

  // ---- layer 1: 32 x 256, wave cols [wid*64, wid*64+64) ----
  f32x4 acc[2][4];
#pragma unroll
  for (int fc = 0; fc < 4; ++fc) {
    const int col = wid * 64 + fc * 16 + lr;
    const float bv = b1[col];
#pragma unroll
    for (int fr = 0; fr < 2; ++fr) acc[fr][fc] = {bv, bv, bv, bv};
    if constexpr (DEG) {
      const float vb = vbias[col];
#pragma unroll
      for (int fr = 0; fr < 2; ++fr)
#pragma unroll
        for (int r = 0; r < 4; ++r)
          acc[fr][fc][r] += (float)degs[fr * 16 + rsub + r] * vb;
    }
  }

  for (int ks = 0; ks < KTOT / 32; ++ks) {
    const int k0 = ks * 32 + lk;
    bf16x8 ah[2], am[2], al[2];
#pragma unroll
    for (int fr = 0; fr < 2; ++fr) {
      const int ab = (fr * 16 + lr) * 264 + k0;
      ah[fr] = *(const bf16x8*)&xh[ab];
      am[fr] = *(const bf16x8*)&xm[ab];
      al[fr] = *(const bf16x8*)&xl[ab];
    }
#pragma unroll
    for (int fc = 0; fc < 4; ++fc) {
      const long wrow = (long)(wid * 64 + fc * 16 + lr) * 256 + k0;
      const bf16x8 bh = *(const bf16x8*)&W1h[wrow];
      const bf16x8 bm = *(const bf16x8*)&W1m[wrow];
      const bf16x8 bl = *(const bf16x8*)&W1l[wrow];
#pragma unroll
      for (int fr = 0; fr < 2; ++fr) {
        acc[fr][fc] = __builtin_amdgcn_mfma_f32_16x16x32_bf16(ah[fr], bh, acc[fr][fc], 0, 0, 0);
        acc[fr][fc] = __builtin_amdgcn_mfma_f32_16x16x32_bf16(ah[fr], bm, acc[fr][fc], 0, 0, 0);
        acc[fr][fc] = __builtin_amdgcn_mfma_f32_16x16x32_bf16(am[fr], bh, acc[fr][fc], 0, 0, 0);
        acc[fr][fc] = __builtin_amdgcn_mfma_f32_16x16x32_bf16(ah[fr], bl, acc[fr][fc], 0, 0, 0);
        acc[fr][fc] = __builtin_amdgcn_mfma_f32_16x16x32_bf16(am[fr], bm, acc[fr][fc], 0, 0, 0);
        acc[fr][fc] = __builtin_amdgcn_mfma_f32_16x16x32_bf16(al[fr], bh, acc[fr][fc], 0, 0, 0);
      }
    }
  }
  __syncthreads();   // all A-reads done before hidden overwrite

  // relu + split3 + store hidden to LDS [row][hcol]
#pragma unroll
  for (int fr = 0; fr < 2; ++fr)
#pragma unroll
    for (int fc = 0; fc < 4; ++fc) {
      const int col = wid * 64 + fc * 16 + lr;
#pragma unroll
      for (int r = 0; r < 4; ++r) {
        const int row = fr * 16 + rsub + r;
        float v = fmaxf(acc[fr][fc][r], 0.f);
        split3(v, xh, xm, xl, row * 264 + col);
      }
    }
  __syncthreads();

  // ---- layer 2: 32 x 128, wave cols [wid*32, wid*32+32) ----
  f32x4 acc2[2][2];
#pragma unroll
  for (int fc = 0; fc < 2; ++fc) {
    const float bv = b2[wid * 32 + fc * 16 + lr];
#pragma unroll
    for (int fr = 0; fr < 2; ++fr) acc2[fr][fc] = {bv, bv, bv, bv};
  }
  for (int ks = 0; ks < 8; ++ks) {
    const int k0 = ks * 32 + lk;
    bf16x8 ah[2], am[2], al[2];
#pragma unroll
    for (int fr = 0; fr < 2; ++fr) {
      const int ab = (fr * 16 + lr) * 264 + k0;
      ah[fr] = *(const bf16x8*)&xh[ab];
      am[fr] = *(const bf16x8*)&xm[ab];
      al[fr] = *(const bf16x8*)&xl[ab];
    }
#pragma unroll
    for (int fc = 0; fc < 2; ++fc) {
      const long wrow = (long)(wid * 32 + fc * 16 + lr) * 256 + k0;
      const bf16x8 bh = *(const bf16x8*)&W2h[wrow];
      const bf16x8 bm = *(const bf16x8*)&W2m[wrow];
      const bf16x8 bl = *(const bf16x8*)&W2l[wrow];
#pragma unroll
      for (int fr = 0; fr < 2; ++fr) {
        acc2[fr][fc] = __builtin_amdgcn_mfma_f32_16x16x32_bf16(ah[fr], bh, acc2[fr][fc], 0, 0, 0);
        acc2[fr][fc] = __builtin_amdgcn_mfma_f32_16x16x32_bf16(ah[fr], bm, acc2[fr][fc], 0, 0, 0);
        acc2[fr][fc] = __builtin_amdgcn_mfma_f32_16x16x32_bf16(am[fr], bh, acc2[fr][fc], 0, 0, 0);
        acc2[fr][fc] = __builtin_amdgcn_mfma_f32_16x16x32_bf16(ah[fr], bl, acc2[fr][fc], 0, 0, 0);
        acc2[fr][fc] = __builtin_amdgcn_mfma_f32_16x16x32_bf16(am[fr], bm, acc2[fr][fc], 0, 0, 0);
        acc2[fr][fc] = __builtin_amdgcn_mfma_f32_16x16x32_bf16(al[fr], bh, acc2[fr][fc], 0, 0, 0);
      }
    }
  }
#pragma unroll
  for (int fr = 0; fr < 2; ++fr)
#pragma unroll
    for (int fc = 0; fc < 2; ++fc) {
      const int col = wid * 32 + fc * 16 + lr;
#pragma unroll
      for (int r = 0; r < 4; ++r)
        out[(row0 + fr * 16 + rsub + r) * 128 + col] = acc2[fr][fc][r];
    }
}

// ---------------------------------------------------------------------------
// Fused per-group edge pipeline, CSR-based, atomic-free. grid (512, 2).
__global__ __launch_bounds__(256, 3)
void k_edge(const float* __restrict__ comb, const float* __restrict__ efp,
            const float* __restrict__ mw1, const float* __restrict__ mw2,
            const float* __restrict__ Wfold, const float* __restrict__ bfold,
            const int* __restrict__ csr_f, const int* __restrict__ rp_g,
            float* __restrict__ aggM) {
  __shared__ __align__(16) float cA[64 * 64];
  __shared__ __align__(16) float U[128 * 64];   // ct[128][64] | ag[64][64]
  __shared__ int fl[EPG];
  __shared__ int rp[65];
  float* ct = U;
  float* ag = U;

  const int tid = threadIdx.x;
  const int g = blockIdx.x, half = blockIdx.y;
  const int be = g * EPG, bn = g * 64;

  for (int i = tid; i < EPG; i += 256) fl[i] = csr_f[be + i];
  if (tid < 65) rp[tid] = rp_g[g * 65 + tid];

  const int ng = tid >> 4, cg = tid & 15;
  const int n0 = ng * 4, cq = cg * 4;

  float aM[4][8];
#pragma unroll
  for (int i = 0; i < 4; ++i)
#pragma unroll
    for (int j = 0; j < 8; ++j) aM[i][j] = 0.f;

  for (int cbi = 0; cbi < 2; ++cbi) {
    const int col0 = (half * 2 + cbi) * 64;
    __syncthreads();
    for (int i = tid; i < 2048; i += 256) {
      const int n = i & 63, q = i >> 6;
      float4 v = *(const float4*)&comb[(long)(bn + n) * 128 + q * 4];
      ct[(q*4+0)*64 + n] = v.x; ct[(q*4+1)*64 + n] = v.y;
      ct[(q*4+2)*64 + n] = v.z; ct[(q*4+3)*64 + n] = v.w;
    }
    __syncthreads();
    float accA[4][4], accB[4][4];
#pragma unroll
    for (int i = 0; i < 4; ++i)
#pragma unroll
      for (int j = 0; j < 4; ++j) { accA[i][j] = 0.f; accB[i][j] = 0.f; }
    {
      const int c0 = col0 + cq;
#pragma unroll 2
      for (int k = 0; k < 128; ++k) {
        const float4 xv = *(const float4*)&ct[k * 64 + n0];
        const float4 wa = *(const float4*)&mw1[k * 256 + c0];
        const float4 wb = *(const float4*)&mw1[(128 + k) * 256 + c0];
        const float xs_[4] = {xv.x, xv.y, xv.z, xv.w};
#pragma unroll
        for (int i = 0; i < 4; ++i) {
          accA[i][0] = fmaf(xs_[i], wa.x, accA[i][0]);
          accA[i][1] = fmaf(xs_[i], wa.y, accA[i][1]);
          accA[i][2] = fmaf(xs_[i], wa.z, accA[i][2]);
          accA[i][3] = fmaf(xs_[i], wa.w, accA[i][3]);
          accB[i][0] = fmaf(xs_[i], wb.x, accB[i][0]);
          accB[i][1] = fmaf(xs_[i], wb.y, accB[i][1]);
          accB[i][2] = fmaf(xs_[i], wb.z, accB[i][2]);
          accB[i][3] = fmaf(xs_[i], wb.w, accB[i][3]);
        }
      }
    }
    __syncthreads();
#pragma unroll
    for (int i = 0; i < 4; ++i)
      *(float4*)&cA[(n0 + i) * 64 + cq] =
        make_float4(accA[i][0], accA[i][1], accA[i][2], accA[i][3]);
    float4 Wf[16];
#pragma unroll
    for (int k = 0; k < 16; ++k) Wf[k] = *(const float4*)&Wfold[k * 256 + col0 + cq];
    const float4 bf = *(const float4*)&bfold[col0 + cq];
    __syncthreads();

#pragma unroll
    for (int i = 0; i < 4; ++i) {
      const int n = n0 + i;
      float4 acc = make_float4(0.f, 0.f, 0.f, 0.f);
      const float4 cB = make_float4(accB[i][0], accB[i][1], accB[i][2], accB[i][3]);
      const int e1 = rp[n + 1];
      for (int e = rp[n]; e < e1; ++e) {
        const int f = fl[e];
        const float* er = efp + (long)(be + e) * 16;
        float4 h = bf;
#pragma unroll
        for (int kq = 0; kq < 4; ++kq) {
          const float4 e4 = *(const float4*)(er + kq * 4);
          const float ev[4] = {e4.x, e4.y, e4.z, e4.w};
#pragma unroll
          for (int s = 0; s < 4; ++s) {
            const float4 w = Wf[kq * 4 + s];
            h.x = fmaf(ev[s], w.x, h.x); h.y = fmaf(ev[s], w.y, h.y);
            h.z = fmaf(ev[s], w.z, h.z); h.w = fmaf(ev[s], w.w, h.w);
          }
        }
        const float4 va = *(const float4*)&cA[f * 64 + cq];
        acc.x += fmaxf(h.x + va.x + cB.x, 0.f);
        acc.y += fmaxf(h.y + va.y + cB.y, 0.f);
        acc.z += fmaxf(h.z + va.z + cB.z, 0.f);
        acc.w += fmaxf(h.w + va.w + cB.w, 0.f);
      }
      *(float4*)&ag[n * 64 + cq] = acc;
    }
    __syncthreads();

    {
      const int c2 = cg * 8;
#pragma unroll 2
      for (int kk = 0; kk < 64; ++kk) {
        const float4 w0 = *(const float4*)&mw2[(col0 + kk) * 128 + c2];
        const float4 w1 = *(const float4*)&mw2[(col0 + kk) * 128 + c2 + 4];
#pragma unroll
        for (int i = 0; i < 4; ++i) {
          const float x = ag[(n0 + i) * 64 + kk];
          aM[i][0] = fmaf(x, w0.x, aM[i][0]); aM[i][1] = fmaf(x, w0.y, aM[i][1]);
          aM[i][2] = fmaf(x, w0.z, aM[i][2]); aM[i][3] = fmaf(x, w0.w, aM[i][3]);
          aM[i][4] = fmaf(x, w1.x, aM[i][4]); aM[i][5] = fmaf(x, w1.y, aM[i][5]);
          aM[i][6] = fmaf(x, w1.z, aM[i][6]); aM[i][7] = fmaf(x, w1.w, aM[i][7]);
        }
      }
    }
  }
  float* aggMh = aggM + (long)half * ND;
#pragma unroll
  for (int i = 0; i < 4; ++i) {
    *(float4*)&aggMh[(long)(bn + n0 + i) * 128 + cg * 8]     = *(float4*)&aM[i][0];
    *(float4*)&aggMh[(long)(bn + n0 + i) * 128 + cg * 8 + 4] = *(float4*)&aM[i][4];
  }
}

// ---------------------------------------------------------------------------
__global__ void k_tfeat(const float* __restrict__ x,
                        const float* __restrict__ t1w, const float* __restrict__ t1b,
                        const float* __restrict__ t2w, const float* __restrict__ t2b,
                        float* __restrict__ tf) {
  __shared__ float xs[4][128];
  __shared__ float ys[4][64];
  const int tid = threadIdx.x;
  const long row0 = (long)blockIdx.x * 4;
  for (int i = tid; i < 512; i += 256)
    xs[i >> 7][i & 127] = x[(row0 + (i >> 7)) * 128 + (i & 127)];
  __syncthreads();
  const int r = tid >> 6, c = tid & 63;
  float acc = t1b[c];
#pragma unroll 4
  for (int k = 0; k < 128; ++k) acc = fmaf(xs[r][k], t1w[k * 64 + c], acc);
  ys[r][c] = fmaxf(acc, 0.f);
  __syncthreads();
  float a2 = t2b[c];
#pragma unroll 4
  for (int k = 0; k < 64; ++k) a2 = fmaf(ys[r][k], t2w[k * 64 + c], a2);
  tf[(row0 + r) * 64 + c] = a2;
}

// ---------------------------------------------------------------------------
__global__ void k_sim(const float* __restrict__ tf, float* __restrict__ sim) {
  const int b = blockIdx.x, tid = threadIdx.x;
  __shared__ float tq[64][65];
  __shared__ float tcs[64][65];
  for (int i = tid; i < 4096; i += 256) {
    tq[i >> 6][i & 63]  = tf[(long)b * 8192 + i];
    tcs[i >> 6][i & 63] = tf[(long)b * 8192 + 4096 + i];
  }
  __syncthreads();
  const int m = tid >> 2, j0 = (tid & 3) * 16;
#pragma unroll
  for (int j = 0; j < 16; ++j) {
    float a = 0.f;
#pragma unroll 4
    for (int k = 0; k < 64; ++k) a = fmaf(tq[m][k], tcs[j0 + j][k], a);
    sim[(long)b * 4096 + m * 64 + j0 + j] = a;
  }
}

// ---------------------------------------------------------------------------
__global__ void k_sink(float* __restrict__ sim, float* __restrict__ outp) {
  const int b = blockIdx.x, tid = threadIdx.x;
  __shared__ float la[64][65];
  const float C = 14.426950408889634f;   // 10 / ln(2)
  for (int i = tid; i < 4096; i += 256)
    la[i >> 6][i & 63] = sim[(long)b * 4096 + i] * C;
  __syncthreads();
  const int r4 = tid >> 2, l4 = tid & 3;
  for (int it = 0; it < 20; ++it) {
    {
      float m = -3.4e38f;
#pragma unroll
      for (int i = 0; i < 16; ++i) m = fmaxf(m, la[r4][l4 + 4 * i]);
      m = fmaxf(m, __shfl_xor(m, 1)); m = fmaxf(m, __shfl_xor(m, 2));
      float s = 0.f;
#pragma unroll
      for (int i = 0; i < 16; ++i) s += exp2f(la[r4][l4 + 4 * i] - m);
      s += __shfl_xor(s, 1); s += __shfl_xor(s, 2);
      const float lse = m + log2f(s);
#pragma unroll
      for (int i = 0; i < 16; ++i) la[r4][l4 + 4 * i] -= lse;
    }
    __syncthreads();
    {
      float m = -3.4e38f;
#pragma unroll
      for (int i = 0; i < 16; ++i) m = fmaxf(m, la[l4 + 4 * i][r4]);
      m = fmaxf(m, __shfl_xor(m, 1)); m = fmaxf(m, __shfl_xor(m, 2));
      float s = 0.f;
#pragma unroll
      for (int i = 0; i < 16; ++i) s += exp2f(la[l4 + 4 * i][r4] - m);
      s += __shfl_xor(s, 1); s += __shfl_xor(s, 2);
      const float lse = m + log2f(s);
#pragma unroll
      for (int i = 0; i < 16; ++i) la[l4 + 4 * i][r4] -= lse;
    }
    __syncthreads();
  }
  for (int i = tid; i < 4096; i += 256) {
    const float v = exp2f(la[i >> 6][i & 63]);
    outp[(long)b * 4096 + i] = v;
    sim[(long)b * 4096 + i] = v;
  }
}

// ---------------------------------------------------------------------------
__global__ void k_mix(const float* __restrict__ plan, const float* __restrict__ src,
                      float* __restrict__ dst) {
  const int b = blockIdx.x, tid = threadIdx.x;
  __shared__ float pl[64][65];
  __shared__ float qs[64][128];
  __shared__ float cs[64][128];
  const long qbase = (long)(2 * b) * 64, cbase = qbase + 64;
  for (int i = tid; i < 4096; i += 256) pl[i >> 6][i & 63] = plan[(long)b * 4096 + i];
  for (int i = tid; i < 8192; i += 256) {
    qs[i >> 7][i & 127] = src[qbase * 128 + i];
    cs[i >> 7][i & 127] = src[cbase * 128 + i];
  }
  __syncthreads();
  const int d = tid & 127, m0 = (tid >> 7) * 32;
  for (int m = m0; m < m0 + 32; ++m) {
    float a = 0.f;
#pragma unroll 4
    for (int j = 0; j < 64; ++j) a = fmaf(pl[m][j], cs[j][d], a);
    dst[(qbase + m) * 128 + d] = a;
  }
  for (int j = m0; j < m0 + 32; ++j) {
    float a = 0.f;
#pragma unroll 4
    for (int m = 0; m < 64; ++m) a = fmaf(pl[m][j], qs[m][d], a);
    dst[(cbase + j) * 128 + d] = a;
  }
}

// ---------------------------------------------------------------------------
extern "C" void kernel_launch(void* const* d_in, const int* in_sizes, int n_in,
                              void* d_out, int out_size, void* d_ws, size_t ws_size,
                              hipStream_t stream) {
  const float* nf  = (const float*)d_in[0];
  const float* ef  = (const float*)d_in[1];
  const int* from_idx = (const int*)d_in[2];
  const int* to_idx   = (const int*)d_in[3];
  const float* new_w = (const float*)d_in[4];
  const float* new_b = (const float*)d_in[5];
  const float* eew = (const float*)d_in[6];
  const float* eeb = (const float*)d_in[7];
  const float* mw1 = (const float*)d_in[8];
  const float* mb1 = (const float*)d_in[9];
  const float* mw2 = (const float*)d_in[10];
  const float* mb2 = (const float*)d_in[11];
  const float* nw1 = (const float*)d_in[12];
  const float* nb1 = (const float*)d_in[13];
  const float* nw2 = (const float*)d_in[14];
  const float* nb2 = (const float*)d_in[15];
  const float* cw1 = (const float*)d_in[16];
  const float* cb1 = (const float*)d_in[17];
  const float* cw2 = (const float*)d_in[18];
  const float* cb2 = (const float*)d_in[19];
  const float* t1w = (const float*)d_in[20];
  const float* t1b = (const float*)d_in[21];
  const float* t2w = (const float*)d_in[22];
  const float* t2b = (const float*)d_in[23];

  float* W = (float*)d_ws;
  float* h0     = W;                       // ND
  float* comb   = h0 + ND;                 // ND
  float* aggM0  = comb + ND;               // ND (tf/sim alias here)
  float* aggM1  = aggM0 + ND;              // ND
  float* parts  = aggM1 + ND;              // 5*ND
  float* efp    = parts + 5 * ND;          // 262144*16
  float* Wfold  = efp + 262144l * 16;      // 4096
  float* bfold  = Wfold + 4096;            // 256
  float* vbias  = bfold + 256;             // 256
  int*   deg    = (int*)(vbias + 256);     // 32768
  int*   csr_f  = deg + 32768;             // 262144
  int*   rp_g   = csr_f + 262144;          // 512*65 = 33280
  short* cw1t_h = (short*)(rp_g + 33280);  // 65536 shorts per plane below
  short* cw1t_m = cw1t_h + 65536;
  short* cw1t_l = cw1t_m + 65536;
  short* nw1t_h = cw1t_l + 65536;
  short* nw1t_m = nw1t_h + 65536;
  short* nw1t_l = nw1t_m + 65536;
  short* cw2t_h = nw1t_l + 65536;          // 32768 each
  short* cw2t_m = cw2t_h + 32768;
  short* cw2t_l = cw2t_m + 32768;
  short* nw2t_h = cw2t_l + 32768;
  short* nw2t_m = nw2t_h + 32768;
  short* nw2t_l = nw2t_m + 32768;
  float* tf     = aggM0;                   // 32768*64
  float* sim    = aggM0 + 2097152;         // 256*4096
  float* outp   = (float*)d_out;

  k_prep<<<18, 256, 0, stream>>>(eew, eeb, mw1, mb1, mb2, nw1, Wfold, bfold, vbias);
  k_csr<<<512, 256, 0, stream>>>(from_idx, to_idx, ef, csr_f, rp_g, efp, deg);
  k_wsplit3<<<256, 256, 0, stream>>>(cw1, 256, 256, cw1t_h, cw1t_m, cw1t_l);
  k_wsplit3<<<256, 256, 0, stream>>>(nw1, 256, 256, nw1t_h, nw1t_m, nw1t_l);
  k_wsplit3<<<128, 256, 0, stream>>>(cw2, 128, 256, cw2t_h, cw2t_m, cw2t_l);
  k_wsplit3<<<128, 256, 0, stream>>>(nw2, 128, 256, nw2t_h, nw2t_m, nw2t_l);
  k_node_enc<<<16384, 256, 0, stream>>>(nf, new_w, new_b, h0);

  for (int t = 0; t < 3; ++t) {
    const float* hprev = h0;
    for (int p = 1; p <= 5; ++p) {
      if (t > 0 && p > 1)
        k_mlp2m<256, false, false><<<1024, 256, 0, stream>>>(
            hprev, parts + (long)(p - 1) * ND, nullptr,
            cw1t_h, cw1t_m, cw1t_l, cb1, nullptr, nullptr,
            cw2t_h, cw2t_m, cw2t_l, cb2, comb);
      else
        k_mlp2m<128, false, false><<<1024, 256, 0, stream>>>(
            hprev, nullptr, nullptr,
            cw1t_h, cw1t_m, cw1t_l, cb1, nullptr, nullptr,
            cw2t_h, cw2t_m, cw2t_l, cb2, comb);
      k_edge<<<dim3(512, 2), 256, 0, stream>>>(comb, efp, mw1, mw2, Wfold, bfold,
                                               csr_f, rp_g, aggM0);
      float* hnew = parts + (long)(p - 1) * ND;
      k_mlp2m<256, true, true><<<1024, 256, 0, stream>>>(
          comb, aggM0, aggM1,
          nw1t_h, nw1t_m, nw1t_l, nb1, deg, vbias,
          nw2t_h, nw2t_m, nw2t_l, nb2, hnew);
      hprev = hnew;
    }
    k_tfeat<<<8192, 256, 0, stream>>>(parts + 4 * ND, t1w, t1b, t2w, t2b, tf);
    k_sim<<<256, 256, 0, stream>>>(tf, sim);
    k_sink<<<256, 256, 0, stream>>>(sim, outp);
    if (t < 2) {
      for (int pi = 3; pi >= 0; --pi)
        k_mix<<<256, 256, 0, stream>>>(sim, parts + (long)pi * ND, parts + (long)(pi + 1) * ND);
    }
  }
}

// Round 7
// 6440.823 us; speedup vs baseline: 3.5480x; 1.0379x over previous
//
#include <hip/hip_runtime.h>
#include <hip/hip_bf16.h>

#define NNODES   32768
#define NGROUPS  512
#define EPG      512
#define ND       (32768l*128)

typedef __attribute__((ext_vector_type(4))) float f32x4;
typedef __attribute__((ext_vector_type(8))) short bf16x8;

__device__ __forceinline__ short f2bf(float x) {
  unsigned u = __float_as_uint(x);
  unsigned r = (u + 0x7FFF + ((u >> 16) & 1)) >> 16;   // RNE
  return (short)r;
}
__device__ __forceinline__ float bf2f(short h) {
  return __uint_as_float(((unsigned)(unsigned short)h) << 16);
}
// 3-term bf16 split: x ~= h + m + l  (covers ~24 mantissa bits)
__device__ __forceinline__ void split3(float x, short* ph, short* pm, short* pl, long idx) {
  short h = f2bf(x); float r1 = x - bf2f(h);
  short m = f2bf(r1); float r2 = r1 - bf2f(m);
  ph[idx] = h; pm[idx] = m; pl[idx] = f2bf(r2);
}

// ---------------------------------------------------------------------------
// h0 = node_features(32768x32) @ W(32x128) + b
__global__ void k_node_enc(const float* __restrict__ nf, const float* __restrict__ w,
                           const float* __restrict__ b, float* __restrict__ h0) {
  int idx = blockIdx.x * 256 + threadIdx.x;
  int row = idx >> 7, col = idx & 127;
  const float* x = nf + row * 32;
  float acc = b[col];
#pragma unroll
  for (int k = 0; k < 32; ++k) acc = fmaf(x[k], w[k * 128 + col], acc);
  h0[idx] = acc;
}

// ---------------------------------------------------------------------------
// Folded weights (fp32):
//  blocks 0..15 : Wfold[16][256] = eew(16x64) @ mw1[256:320,:]
//  block  16    : bfold[256]     = eeb @ mw1[256:320,:] + mb1
//  block  17    : vbias[256]     = mb2 @ nw1[128:256,:]
__global__ void k_prep(const float* __restrict__ eew, const float* __restrict__ eeb,
                       const float* __restrict__ mw1, const float* __restrict__ mb1,
                       const float* __restrict__ mb2, const float* __restrict__ nw1,
                       float* __restrict__ Wfold, float* __restrict__ bfold,
                       float* __restrict__ vbias) {
  const int c = threadIdx.x, b = blockIdx.x;
  if (b < 16) {
    float a = 0.f;
    for (int j = 0; j < 64; ++j) a = fmaf(eew[b * 64 + j], mw1[(256 + j) * 256 + c], a);
    Wfold[b * 256 + c] = a;
  } else if (b == 16) {
    float a = mb1[c];
    for (int j = 0; j < 64; ++j) a = fmaf(eeb[j], mw1[(256 + j) * 256 + c], a);
    bfold[c] = a;
  } else {
    float a = 0.f;
    for (int j = 0; j < 128; ++j) a = fmaf(mb2[j], nw1[(128 + j) * 256 + c], a);
    vbias[c] = a;
  }
}

// ---------------------------------------------------------------------------
// Weight transpose + bf16x3 split: W (>=Kd x C row-major) -> Wt[c][k], k-stride 256
__global__ void k_wsplit3(const float* __restrict__ W, int C, int Kd,
                          short* __restrict__ th, short* __restrict__ tm,
                          short* __restrict__ tl) {
  const int c = blockIdx.x;
  for (int k = threadIdx.x; k < Kd; k += 256) {
    float w = W[(long)k * C + c];
    split3(w, th, tm, tl, c * 256 + k);
  }
}

// ---------------------------------------------------------------------------
// Deterministic CSR per group: edges stably sorted by to-node.
__global__ void k_csr(const int* __restrict__ from_idx, const int* __restrict__ to_idx,
                      const float* __restrict__ ef,
                      int* __restrict__ csr_f, int* __restrict__ rp_g,
                      float* __restrict__ efp, int* __restrict__ deg) {
  __shared__ int cnt[64], rps[65];
  __shared__ int tls[EPG], fls[EPG];
  __shared__ short ord[EPG];
  const int g = blockIdx.x, tid = threadIdx.x;
  const int be = g * EPG, bn = g * 64;
  if (tid < 64) cnt[tid] = 0;
  __syncthreads();
  for (int e = tid; e < EPG; e += 256) {
    int t = to_idx[be + e] - bn;
    tls[e] = t;
    fls[e] = from_idx[be + e] - bn;
    atomicAdd(&cnt[t], 1);
  }
  __syncthreads();
  if (tid == 0) {
    int s = 0;
    for (int i = 0; i < 64; ++i) { rps[i] = s; s += cnt[i]; }
    rps[64] = s;
  }
  __syncthreads();
  if (tid < 64) {
    int pos = rps[tid];
    for (int e = 0; e < EPG; ++e)
      if (tls[e] == tid) ord[pos++] = (short)e;
  }
  __syncthreads();
  for (int ec = tid; ec < EPG; ec += 256) {
    const int eo = ord[ec];
    csr_f[be + ec] = fls[eo];
    const float4* src = (const float4*)&ef[(long)(be + eo) * 16];
    float4* dst = (float4*)&efp[(long)(be + ec) * 16];
    dst[0] = src[0]; dst[1] = src[1]; dst[2] = src[2]; dst[3] = src[3];
  }
  if (tid < 65) rp_g[g * 65 + tid] = rps[tid];
  if (tid < 64) deg[bn + tid] = cnt[tid];
}

// ---------------------------------------------------------------------------
// MFMA bf16x3 2-layer MLP. X = [x0 | x1(+x1b)].
// RPX0: x0 read from pre-split planes. WPOUT: output written as bf16x3 planes.
template<int KTOT, bool DEG, bool SUM2, bool RPX0, bool WPOUT>
__global__ __launch_bounds__(256, 2)
void k_mlp2m(const float* __restrict__ x0,
             const short* __restrict__ x0h, const short* __restrict__ x0m,
             const short* __restrict__ x0l,
             const float* __restrict__ x1, const float* __restrict__ x1b,
             const short* __restrict__ W1h, const short* __restrict__ W1m,
             const short* __restrict__ W1l,
             const float* __restrict__ b1, const int* __restrict__ deg,
             const float* __restrict__ vbias,
             const short* __restrict__ W2h, const short* __restrict__ W2m,
             const short* __restrict__ W2l,
             const float* __restrict__ b2,
             float* __restrict__ out,
             short* __restrict__ outh, short* __restrict__ outm,
             short* __restrict__ outl) {
  __shared__ short xh[32 * 264];
  __shared__ short xm[32 * 264];
  __shared__ short xl[32 * 264];
  __shared__ int degs[32];
  const int tid = threadIdx.x;
  const long row0 = (long)blockIdx.x * 32;

  if constexpr (RPX0) {
    for (int i = tid; i < 32 * 16; i += 256) {
      const int r = i >> 4, q = i & 15;
      const long gb = (row0 + r) * 128 + q * 8;
      const int lb = r * 264 + q * 8;
      *(bf16x8*)&xh[lb] = *(const bf16x8*)&x0h[gb];
      *(bf16x8*)&xm[lb] = *(const bf16x8*)&x0m[gb];
      *(bf16x8*)&xl[lb] = *(const bf16x8*)&x0l[gb];
    }
  } else {
    for (int i = tid; i < 32 * 32; i += 256) {
      const int r = i >> 5, q = i & 31;
      float4 v = *(const float4*)&x0[(row0 + r) * 128 + q * 4];
      const int base = r * 264 + q * 4;
      split3(v.x, xh, xm, xl, base + 0);
      split3(v.y, xh, xm, xl, base + 1);
      split3(v.z, xh, xm, xl, base + 2);
      split3(v.w, xh, xm, xl, base + 3);
    }
  }
  if constexpr (KTOT == 256) {
    for (int i = tid; i < 32 * 32; i += 256) {
      const int r = i >> 5, q = i & 31;
      float4 v = *(const float4*)&x1[(row0 + r) * 128 + q * 4];
      if constexpr (SUM2) {
        float4 w = *(const float4*)&x1b[(row0 + r) * 128 + q * 4];
        v.x += w.x; v.y += w.y; v.z += w.z; v.w += w.w;
      }
      const int base = r * 264 + 128 + q * 4;
      split3(v.x, xh, xm, xl, base + 0);
      split3(v.y, xh, xm, xl, base + 1);
      split3(v.z, xh, xm, xl, base + 2);
      split3(v.w, xh, xm, xl, base + 3);
    }
  }
  if constexpr (DEG) { if (tid < 32) degs[tid] = deg[row0 + tid]; }
  __syncthreads();

  const int lane = tid & 63, wid = tid >> 6;
  const int lr = lane & 15;
  const int lk = (lane >> 4) * 8;
  const int rsub = (lane >> 4) * 4;

  // ---- layer 1: 32 x 256, wave cols [wid*64, wid*64+64) ----
  f32x4 acc[2][4];
#pragma unroll
  for (int fc = 0; fc < 4; ++fc) {
    const int col = wid * 64 + fc * 16 + lr;
    const float bv = b1[col];
#pragma unroll
    for (int fr = 0; fr < 2; ++fr) acc[fr][fc] = {bv, bv, bv, bv};
    if constexpr (DEG) {
      const float vb = vbias[col];
#pragma unroll
      for (int fr = 0; fr < 2; ++fr)
#pragma unroll
        for (int r = 0; r < 4; ++r)
          acc[fr][fc][r] += (float)degs[fr * 16 + rsub + r] * vb;
    }
  }

  for (int ks = 0; ks < KTOT / 32; ++ks) {
    const int k0 = ks * 32 + lk;
    bf16x8 ah[2], am[2], al[2];
#pragma unroll
    for (int fr = 0; fr < 2; ++fr) {
      const int ab = (fr * 16 + lr) * 264 + k0;
      ah[fr] = *(const bf16x8*)&xh[ab];
      am[fr] = *(const bf16x8*)&xm[ab];
      al[fr] = *(const bf16x8*)&xl[ab];
    }
#pragma unroll
    for (int fc = 0; fc < 4; ++fc) {
      const long wrow = (long)(wid * 64 + fc * 16 + lr) * 256 + k0;
      const bf16x8 bh = *(const bf16x8*)&W1h[wrow];
      const bf16x8 bm = *(const bf16x8*)&W1m[wrow];
      const bf16x8 bl = *(const bf16x8*)&W1l[wrow];
#pragma unroll
      for (int fr = 0; fr < 2; ++fr) {
        acc[fr][fc] = __builtin_amdgcn_mfma_f32_16x16x32_bf16(ah[fr], bh, acc[fr][fc], 0, 0, 0);
        acc[fr][fc] = __builtin_amdgcn_mfma_f32_16x16x32_bf16(ah[fr], bm, acc[fr][fc], 0, 0, 0);
        acc[fr][fc] = __builtin_amdgcn_mfma_f32_16x16x32_bf16(am[fr], bh, acc[fr][fc], 0, 0, 0);
        acc[fr][fc] = __builtin_amdgcn_mfma_f32_16x16x32_bf16(ah[fr], bl, acc[fr][fc], 0, 0, 0);
        acc[fr][fc] = __builtin_amdgcn_mfma_f32_16x16x32_bf16(am[fr], bm, acc[fr][fc], 0, 0, 0);
        acc[fr][fc] = __builtin_amdgcn_mfma_f32_16x16x32_bf16(al[fr], bh, acc[fr][fc], 0, 0, 0);
      }
    }
  }
  __syncthreads();

  // relu + split3 + store hidden to LDS [row][hcol]
#pragma unroll
  for (int fr = 0; fr < 2; ++fr)
#pragma unroll
    for (int fc = 0; fc < 4; ++fc) {
      const int col = wid * 64 + fc * 16 + lr;
#pragma unroll
      for (int r = 0; r < 4; ++r) {
        const int row = fr * 16 + rsub + r;
        float v = fmaxf(acc[fr][fc][r], 0.f);
        split3(v, xh, xm, xl, row * 264 + col);
      }
    }
  __syncthreads();

  // ---- layer 2: 32 x 128, wave cols [wid*32, wid*32+32) ----
  f32x4 acc2[2][2];
#pragma unroll
  for (int fc = 0; fc < 2; ++fc) {
    const float bv = b2[wid * 32 + fc * 16 + lr];
#pragma unroll
    for (int fr = 0; fr < 2; ++fr) acc2[fr][fc] = {bv, bv, bv, bv};
  }
  for (int ks = 0; ks < 8; ++ks) {
    const int k0 = ks * 32 + lk;
    bf16x8 ah[2], am[2], al[2];
#pragma unroll
    for (int fr = 0; fr < 2; ++fr) {
      const int ab = (fr * 16 + lr) * 264 + k0;
      ah[fr] = *(const bf16x8*)&xh[ab];
      am[fr] = *(const bf16x8*)&xm[ab];
      al[fr] = *(const bf16x8*)&xl[ab];
    }
#pragma unroll
    for (int fc = 0; fc < 2; ++fc) {
      const long wrow = (long)(wid * 32 + fc * 16 + lr) * 256 + k0;
      const bf16x8 bh = *(const bf16x8*)&W2h[wrow];
      const bf16x8 bm = *(const bf16x8*)&W2m[wrow];
      const bf16x8 bl = *(const bf16x8*)&W2l[wrow];
#pragma unroll
      for (int fr = 0; fr < 2; ++fr) {
        acc2[fr][fc] = __builtin_amdgcn_mfma_f32_16x16x32_bf16(ah[fr], bh, acc2[fr][fc], 0, 0, 0);
        acc2[fr][fc] = __builtin_amdgcn_mfma_f32_16x16x32_bf16(ah[fr], bm, acc2[fr][fc], 0, 0, 0);
        acc2[fr][fc] = __builtin_amdgcn_mfma_f32_16x16x32_bf16(am[fr], bh, acc2[fr][fc], 0, 0, 0);
        acc2[fr][fc] = __builtin_amdgcn_mfma_f32_16x16x32_bf16(ah[fr], bl, acc2[fr][fc], 0, 0, 0);
        acc2[fr][fc] = __builtin_amdgcn_mfma_f32_16x16x32_bf16(am[fr], bm, acc2[fr][fc], 0, 0, 0);
        acc2[fr][fc] = __builtin_amdgcn_mfma_f32_16x16x32_bf16(al[fr], bh, acc2[fr][fc], 0, 0, 0);
      }
    }
  }
#pragma unroll
  for (int fr = 0; fr < 2; ++fr)
#pragma unroll
    for (int fc = 0; fc < 2; ++fc) {
      const int col = wid * 32 + fc * 16 + lr;
#pragma unroll
      for (int r = 0; r < 4; ++r) {
        const long gi = (row0 + fr * 16 + rsub + r) * 128 + col;
        if constexpr (WPOUT) {
          split3(acc2[fr][fc][r], outh, outm, outl, gi);
        } else {
          out[gi] = acc2[fr][fc][r];
        }
      }
    }
}

// ---------------------------------------------------------------------------
// Fused per-group edge pipeline, MFMA GEMMs + fp32 CSR edge phase. grid (512,2).
// Per cb: cA/cB = comb_planes @ mw1t (MFMA) -> LDS; edge gather/relu/segsum -> ag;
// ag split3 -> planes (aliased over cA/cB); aM += agp @ mw2t (MFMA, C persists).
__global__ __launch_bounds__(256, 2)
void k_edgem(const short* __restrict__ chp, const short* __restrict__ cmp,
             const short* __restrict__ clp,
             const float* __restrict__ efp,
             const short* __restrict__ m1h, const short* __restrict__ m1m,
             const short* __restrict__ m1l,
             const short* __restrict__ m2h, const short* __restrict__ m2m,
             const short* __restrict__ m2l,
             const float* __restrict__ Wfold, const float* __restrict__ bfold,
             const int* __restrict__ csr_f, const int* __restrict__ rp_g,
             float* __restrict__ aggM) {
  __shared__ __align__(16) float cAB[2 * 64 * 68];   // cA | cB ; aliased agp planes
  __shared__ __align__(16) float ag[64 * 68];
  __shared__ int fl[EPG];
  __shared__ int rp[65];
  float* cA = cAB;
  float* cB = cAB + 64 * 68;
  short* agp = (short*)cAB;                 // 3 planes of [64][72] shorts

  const int tid = threadIdx.x;
  const int g = blockIdx.x, half = blockIdx.y;
  const int be = g * EPG, bn = g * 64;

  for (int i = tid; i < EPG; i += 256) fl[i] = csr_f[be + i];
  if (tid < 65) rp[tid] = rp_g[g * 65 + tid];

  const int lane = tid & 63, wid = tid >> 6;
  const int lr = lane & 15;
  const int lk = (lane >> 4) * 8;
  const int rsub = (lane >> 4) * 4;
  const int ng = tid >> 4, cg = tid & 15;
  const int n0 = ng * 4, cq = cg * 4;

  f32x4 aM[4][2];                           // 64 x (wave's 32 cols) of aggM
#pragma unroll
  for (int fr = 0; fr < 4; ++fr)
#pragma unroll
    for (int fc = 0; fc < 2; ++fc) aM[fr][fc] = {0.f, 0.f, 0.f, 0.f};

  for (int cbi = 0; cbi < 2; ++cbi) {
    const int col0 = (half * 2 + cbi) * 64;
    __syncthreads();   // previous iter's agp reads done before cA/cB rewrite

    // phase a: MFMA cA/cB. waves 0,1 -> cA (mw1 k 0..127); waves 2,3 -> cB (k 128..255)
    {
      const int isB = wid >> 1;
      const int cw = (wid & 1) * 32;
      const int wkof = isB * 128;
      f32x4 c[4][2];
#pragma unroll
      for (int fr = 0; fr < 4; ++fr)
#pragma unroll
        for (int fc = 0; fc < 2; ++fc) c[fr][fc] = {0.f, 0.f, 0.f, 0.f};
      for (int ks = 0; ks < 4; ++ks) {
        const int k0 = ks * 32 + lk;
        bf16x8 ah[4], am[4], al[4];
#pragma unroll
        for (int fr = 0; fr < 4; ++fr) {
          const long ga = (long)(bn + fr * 16 + lr) * 128 + k0;
          ah[fr] = *(const bf16x8*)&chp[ga];
          am[fr] = *(const bf16x8*)&cmp[ga];
          al[fr] = *(const bf16x8*)&clp[ga];
        }
#pragma unroll
        for (int fc = 0; fc < 2; ++fc) {
          const long wrow = (long)(col0 + cw + fc * 16 + lr) * 256 + wkof + k0;
          const bf16x8 bh = *(const bf16x8*)&m1h[wrow];
          const bf16x8 bm = *(const bf16x8*)&m1m[wrow];
          const bf16x8 bl = *(const bf16x8*)&m1l[wrow];
#pragma unroll
          for (int fr = 0; fr < 4; ++fr) {
            c[fr][fc] = __builtin_amdgcn_mfma_f32_16x16x32_bf16(ah[fr], bh, c[fr][fc], 0, 0, 0);
            c[fr][fc] = __builtin_amdgcn_mfma_f32_16x16x32_bf16(ah[fr], bm, c[fr][fc], 0, 0, 0);
            c[fr][fc] = __builtin_amdgcn_mfma_f32_16x16x32_bf16(am[fr], bh, c[fr][fc], 0, 0, 0);
            c[fr][fc] = __builtin_amdgcn_mfma_f32_16x16x32_bf16(ah[fr], bl, c[fr][fc], 0, 0, 0);
            c[fr][fc] = __builtin_amdgcn_mfma_f32_16x16x32_bf16(am[fr], bm, c[fr][fc], 0, 0, 0);
            c[fr][fc] = __builtin_amdgcn_mfma_f32_16x16x32_bf16(al[fr], bh, c[fr][fc], 0, 0, 0);
          }
        }
      }
      float* dstC = isB ? cB : cA;
#pragma unroll
      for (int fr = 0; fr < 4; ++fr)
#pragma unroll
        for (int fc = 0; fc < 2; ++fc) {
          const int col = cw + fc * 16 + lr;
#pragma unroll
          for (int r = 0; r < 4; ++r)
            dstC[(fr * 16 + rsub + r) * 68 + col] = c[fr][fc][r];
        }
    }
    float4 Wf[16];
#pragma unroll
    for (int k = 0; k < 16; ++k) Wf[k] = *(const float4*)&Wfold[k * 256 + col0 + cq];
    const float4 bf = *(const float4*)&bfold[col0 + cq];
    __syncthreads();   // cA/cB visible

    // phase b: edge phase (fp32 CSR, atomic-free)
#pragma unroll
    for (int i = 0; i < 4; ++i) {
      const int n = n0 + i;
      float4 acc = make_float4(0.f, 0.f, 0.f, 0.f);
      const float4 cBn = *(const float4*)&cB[n * 68 + cq];
      const int e1 = rp[n + 1];
      for (int e = rp[n]; e < e1; ++e) {
        const int f = fl[e];
        const float* er = efp + (long)(be + e) * 16;
        float4 h = bf;
#pragma unroll
        for (int kq = 0; kq < 4; ++kq) {
          const float4 e4 = *(const float4*)(er + kq * 4);
          const float ev[4] = {e4.x, e4.y, e4.z, e4.w};
#pragma unroll
          for (int s = 0; s < 4; ++s) {
            const float4 w = Wf[kq * 4 + s];
            h.x = fmaf(ev[s], w.x, h.x); h.y = fmaf(ev[s], w.y, h.y);
            h.z = fmaf(ev[s], w.z, h.z); h.w = fmaf(ev[s], w.w, h.w);
          }
        }
        const float4 va = *(const float4*)&cA[f * 68 + cq];
        acc.x += fmaxf(h.x + va.x + cBn.x, 0.f);
        acc.y += fmaxf(h.y + va.y + cBn.y, 0.f);
        acc.z += fmaxf(h.z + va.z + cBn.z, 0.f);
        acc.w += fmaxf(h.w + va.w + cBn.w, 0.f);
      }
      *(float4*)&ag[n * 68 + cq] = acc;
    }
    __syncthreads();   // ag complete; cA/cB dead

    // phase c: split3 ag -> agp planes [64][72] (aliased over cA/cB)
    for (int i = tid; i < 1024; i += 256) {
      const int n = i >> 4, kq = (i & 15) * 4;
      const float4 v = *(const float4*)&ag[n * 68 + kq];
      const int b0 = n * 72 + kq;
      split3(v.x, agp, agp + 4608, agp + 9216, b0 + 0);
      split3(v.y, agp, agp + 4608, agp + 9216, b0 + 1);
      split3(v.z, agp, agp + 4608, agp + 9216, b0 + 2);
      split3(v.w, agp, agp + 4608, agp + 9216, b0 + 3);
    }
    __syncthreads();

    // phase d: aM += agp @ mw2t[col0 slice]  (K=64)
    for (int ks = 0; ks < 2; ++ks) {
      const int k0 = ks * 32 + lk;
      bf16x8 ah[4], am[4], al[4];
#pragma unroll
      for (int fr = 0; fr < 4; ++fr) {
        const int ab = (fr * 16 + lr) * 72 + k0;
        ah[fr] = *(const bf16x8*)&agp[ab];
        am[fr] = *(const bf16x8*)&agp[4608 + ab];
        al[fr] = *(const bf16x8*)&agp[9216 + ab];
      }
#pragma unroll
      for (int fc = 0; fc < 2; ++fc) {
        const long wrow = (long)(wid * 32 + fc * 16 + lr) * 256 + col0 + k0;
        const bf16x8 bh = *(const bf16x8*)&m2h[wrow];
        const bf16x8 bm = *(const bf16x8*)&m2m[wrow];
        const bf16x8 bl = *(const bf16x8*)&m2l[wrow];
#pragma unroll
        for (int fr = 0; fr < 4; ++fr) {
          aM[fr][fc] = __builtin_amdgcn_mfma_f32_16x16x32_bf16(ah[fr], bh, aM[fr][fc], 0, 0, 0);
          aM[fr][fc] = __builtin_amdgcn_mfma_f32_16x16x32_bf16(ah[fr], bm, aM[fr][fc], 0, 0, 0);
          aM[fr][fc] = __builtin_amdgcn_mfma_f32_16x16x32_bf16(am[fr], bh, aM[fr][fc], 0, 0, 0);
          aM[fr][fc] = __builtin_amdgcn_mfma_f32_16x16x32_bf16(ah[fr], bl, aM[fr][fc], 0, 0, 0);
          aM[fr][fc] = __builtin_amdgcn_mfma_f32_16x16x32_bf16(am[fr], bm, aM[fr][fc], 0, 0, 0);
          aM[fr][fc] = __builtin_amdgcn_mfma_f32_16x16x32_bf16(al[fr], bh, aM[fr][fc], 0, 0, 0);
        }
      }
    }
  }

  float* aggMh = aggM + (long)half * ND;
#pragma unroll
  for (int fr = 0; fr < 4; ++fr)
#pragma unroll
    for (int fc = 0; fc < 2; ++fc) {
      const int col = wid * 32 + fc * 16 + lr;
#pragma unroll
      for (int r = 0; r < 4; ++r)
        aggMh[(long)(bn + fr * 16 + rsub + r) * 128 + col] = aM[fr][fc][r];
    }
}

// ---------------------------------------------------------------------------
__global__ void k_tfeat(const float* __restrict__ x,
                        const float* __restrict__ t1w, const float* __restrict__ t1b,
                        const float* __restrict__ t2w, const float* __restrict__ t2b,
                        float* __restrict__ tf) {
  __shared__ float xs[4][128];
  __shared__ float ys[4][64];
  const int tid = threadIdx.x;
  const long row0 = (long)blockIdx.x * 4;
  for (int i = tid; i < 512; i += 256)
    xs[i >> 7][i & 127] = x[(row0 + (i >> 7)) * 128 + (i & 127)];
  __syncthreads();
  const int r = tid >> 6, c = tid & 63;
  float acc = t1b[c];
#pragma unroll 4
  for (int k = 0; k < 128; ++k) acc = fmaf(xs[r][k], t1w[k * 64 + c], acc);
  ys[r][c] = fmaxf(acc, 0.f);
  __syncthreads();
  float a2 = t2b[c];
#pragma unroll 4
  for (int k = 0; k < 64; ++k) a2 = fmaf(ys[r][k], t2w[k * 64 + c], a2);
  tf[(row0 + r) * 64 + c] = a2;
}

// ---------------------------------------------------------------------------
__global__ void k_sim(const float* __restrict__ tf, float* __restrict__ sim) {
  const int b = blockIdx.x, tid = threadIdx.x;
  __shared__ float tq[64][65];
  __shared__ float tcs[64][65];
  for (int i = tid; i < 4096; i += 256) {
    tq[i >> 6][i & 63]  = tf[(long)b * 8192 + i];
    tcs[i >> 6][i & 63] = tf[(long)b * 8192 + 4096 + i];
  }
  __syncthreads();
  const int m = tid >> 2, j0 = (tid & 3) * 16;
#pragma unroll
  for (int j = 0; j < 16; ++j) {
    float a = 0.f;
#pragma unroll 4
    for (int k = 0; k < 64; ++k) a = fmaf(tq[m][k], tcs[j0 + j][k], a);
    sim[(long)b * 4096 + m * 64 + j0 + j] = a;
  }
}

// ---------------------------------------------------------------------------
__global__ void k_sink(float* __restrict__ sim, float* __restrict__ outp) {
  const int b = blockIdx.x, tid = threadIdx.x;
  __shared__ float la[64][65];
  const float C = 14.426950408889634f;   // 10 / ln(2)
  for (int i = tid; i < 4096; i += 256)
    la[i >> 6][i & 63] = sim[(long)b * 4096 + i] * C;
  __syncthreads();
  const int r4 = tid >> 2, l4 = tid & 3;
  for (int it = 0; it < 20; ++it) {
    {
      float m = -3.4e38f;
#pragma unroll
      for (int i = 0; i < 16; ++i) m = fmaxf(m, la[r4][l4 + 4 * i]);
      m = fmaxf(m, __shfl_xor(m, 1)); m = fmaxf(m, __shfl_xor(m, 2));
      float s = 0.f;
#pragma unroll
      for (int i = 0; i < 16; ++i) s += exp2f(la[r4][l4 + 4 * i] - m);
      s += __shfl_xor(s, 1); s += __shfl_xor(s, 2);
      const float lse = m + log2f(s);
#pragma unroll
      for (int i = 0; i < 16; ++i) la[r4][l4 + 4 * i] -= lse;
    }
    __syncthreads();
    {
      float m = -3.4e38f;
#pragma unroll
      for (int i = 0; i < 16; ++i) m = fmaxf(m, la[l4 + 4 * i][r4]);
      m = fmaxf(m, __shfl_xor(m, 1)); m = fmaxf(m, __shfl_xor(m, 2));
      float s = 0.f;
#pragma unroll
      for (int i = 0; i < 16; ++i) s += exp2f(la[l4 + 4 * i][r4] - m);
      s += __shfl_xor(s, 1); s += __shfl_xor(s, 2);
      const float lse = m + log2f(s);
#pragma unroll
      for (int i = 0; i < 16; ++i) la[l4 + 4 * i][r4] -= lse;
    }
    __syncthreads();
  }
  for (int i = tid; i < 4096; i += 256) {
    const float v = exp2f(la[i >> 6][i & 63]);
    outp[(long)b * 4096 + i] = v;
    sim[(long)b * 4096 + i] = v;
  }
}

// ---------------------------------------------------------------------------
__global__ void k_mix(const float* __restrict__ plan, const float* __restrict__ src,
                      float* __restrict__ dst) {
  const int b = blockIdx.x, tid = threadIdx.x;
  __shared__ float pl[64][65];
  __shared__ float qs[64][128];
  __shared__ float cs[64][128];
  const long qbase = (long)(2 * b) * 64, cbase = qbase + 64;
  for (int i = tid; i < 4096; i += 256) pl[i >> 6][i & 63] = plan[(long)b * 4096 + i];
  for (int i = tid; i < 8192; i += 256) {
    qs[i >> 7][i & 127] = src[qbase * 128 + i];
    cs[i >> 7][i & 127] = src[cbase * 128 + i];
  }
  __syncthreads();
  const int d = tid & 127, m0 = (tid >> 7) * 32;
  for (int m = m0; m < m0 + 32; ++m) {
    float a = 0.f;
#pragma unroll 4
    for (int j = 0; j < 64; ++j) a = fmaf(pl[m][j], cs[j][d], a);
    dst[(qbase + m) * 128 + d] = a;
  }
  for (int j = m0; j < m0 + 32; ++j) {
    float a = 0.f;
#pragma unroll 4
    for (int m = 0; m < 64; ++m) a = fmaf(pl[m][j], qs[m][d], a);
    dst[(cbase + j) * 128 + d] = a;
  }
}

// ---------------------------------------------------------------------------
extern "C" void kernel_launch(void* const* d_in, const int* in_sizes, int n_in,
                              void* d_out, int out_size, void* d_ws, size_t ws_size,
                              hipStream_t stream) {
  const float* nf  = (const float*)d_in[0];
  const float* ef  = (const float*)d_in[1];
  const int* from_idx = (const int*)d_in[2];
  const int* to_idx   = (const int*)d_in[3];
  const float* new_w = (const float*)d_in[4];
  const float* new_b = (const float*)d_in[5];
  const float* eew = (const float*)d_in[6];
  const float* eeb = (const float*)d_in[7];
  const float* mw1 = (const float*)d_in[8];
  const float* mb1 = (const float*)d_in[9];
  const float* mw2 = (const float*)d_in[10];
  const float* mb2 = (const float*)d_in[11];
  const float* nw1 = (const float*)d_in[12];
  const float* nb1 = (const float*)d_in[13];
  const float* nw2 = (const float*)d_in[14];
  const float* nb2 = (const float*)d_in[15];
  const float* cw1 = (const float*)d_in[16];
  const float* cb1 = (const float*)d_in[17];
  const float* cw2 = (const float*)d_in[18];
  const float* cb2 = (const float*)d_in[19];
  const float* t1w = (const float*)d_in[20];
  const float* t1b = (const float*)d_in[21];
  const float* t2w = (const float*)d_in[22];
  const float* t2b = (const float*)d_in[23];

  float* W = (float*)d_ws;
  float* h0     = W;                       // ND
  float* aggM0  = h0 + ND;                 // ND (tf/sim alias here)
  float* aggM1  = aggM0 + ND;              // ND
  float* parts  = aggM1 + ND;              // 5*ND
  float* efp    = parts + 5 * ND;          // 262144*16
  float* Wfold  = efp + 262144l * 16;      // 4096
  float* bfold  = Wfold + 4096;            // 256
  float* vbias  = bfold + 256;             // 256
  int*   deg    = (int*)(vbias + 256);     // 32768
  int*   csr_f  = deg + 32768;             // 262144
  int*   rp_g   = csr_f + 262144;          // 512*65 = 33280
  short* cw1t_h = (short*)(rp_g + 33280);  // 65536 shorts per plane
  short* cw1t_m = cw1t_h + 65536;
  short* cw1t_l = cw1t_m + 65536;
  short* nw1t_h = cw1t_l + 65536;
  short* nw1t_m = nw1t_h + 65536;
  short* nw1t_l = nw1t_m + 65536;
  short* cw2t_h = nw1t_l + 65536;          // 32768 each
  short* cw2t_m = cw2t_h + 32768;
  short* cw2t_l = cw2t_m + 32768;
  short* nw2t_h = cw2t_l + 32768;
  short* nw2t_m = nw2t_h + 32768;
  short* nw2t_l = nw2t_m + 32768;
  short* m1t_h  = nw2t_l + 32768;          // mw1[0:256] -> 65536 each
  short* m1t_m  = m1t_h + 65536;
  short* m1t_l  = m1t_m + 65536;
  short* m2t_h  = m1t_l + 65536;           // mw2 -> 32768 each
  short* m2t_m  = m2t_h + 32768;
  short* m2t_l  = m2t_m + 32768;
  short* chp    = m2t_l + 32768;           // comb planes: 32768*128 shorts each
  short* cmp    = chp + 32768l * 128;
  short* clp    = cmp + 32768l * 128;
  float* tf     = aggM0;                   // 32768*64
  float* sim    = aggM0 + 2097152;         // 256*4096
  float* outp   = (float*)d_out;

  k_prep<<<18, 256, 0, stream>>>(eew, eeb, mw1, mb1, mb2, nw1, Wfold, bfold, vbias);
  k_csr<<<512, 256, 0, stream>>>(from_idx, to_idx, ef, csr_f, rp_g, efp, deg);
  k_wsplit3<<<256, 256, 0, stream>>>(cw1, 256, 256, cw1t_h, cw1t_m, cw1t_l);
  k_wsplit3<<<256, 256, 0, stream>>>(nw1, 256, 256, nw1t_h, nw1t_m, nw1t_l);
  k_wsplit3<<<128, 256, 0, stream>>>(cw2, 128, 256, cw2t_h, cw2t_m, cw2t_l);
  k_wsplit3<<<128, 256, 0, stream>>>(nw2, 128, 256, nw2t_h, nw2t_m, nw2t_l);
  k_wsplit3<<<256, 256, 0, stream>>>(mw1, 256, 256, m1t_h, m1t_m, m1t_l);
  k_wsplit3<<<128, 256, 0, stream>>>(mw2, 128, 256, m2t_h, m2t_m, m2t_l);
  k_node_enc<<<16384, 256, 0, stream>>>(nf, new_w, new_b, h0);

  for (int t = 0; t < 3; ++t) {
    const float* hprev = h0;
    for (int p = 1; p <= 5; ++p) {
      if (t > 0 && p > 1)
        k_mlp2m<256, false, false, false, true><<<1024, 256, 0, stream>>>(
            hprev, nullptr, nullptr, nullptr,
            parts + (long)(p - 1) * ND, nullptr,
            cw1t_h, cw1t_m, cw1t_l, cb1, nullptr, nullptr,
            cw2t_h, cw2t_m, cw2t_l, cb2, nullptr, chp, cmp, clp);
      else
        k_mlp2m<128, false, false, false, true><<<1024, 256, 0, stream>>>(
            hprev, nullptr, nullptr, nullptr, nullptr, nullptr,
            cw1t_h, cw1t_m, cw1t_l, cb1, nullptr, nullptr,
            cw2t_h, cw2t_m, cw2t_l, cb2, nullptr, chp, cmp, clp);
      k_edgem<<<dim3(512, 2), 256, 0, stream>>>(chp, cmp, clp, efp,
                                                m1t_h, m1t_m, m1t_l,
                                                m2t_h, m2t_m, m2t_l,
                                                Wfold, bfold, csr_f, rp_g, aggM0);
      float* hnew = parts + (long)(p - 1) * ND;
      k_mlp2m<256, true, true, true, false><<<1024, 256, 0, stream>>>(
          nullptr, chp, cmp, clp, aggM0, aggM1,
          nw1t_h, nw1t_m, nw1t_l, nb1, deg, vbias,
          nw2t_h, nw2t_m, nw2t_l, nb2, hnew, nullptr, nullptr, nullptr);
      hprev = hnew;
    }
    k_tfeat<<<8192, 256, 0, stream>>>(parts + 4 * ND, t1w, t1b, t2w, t2b, tf);
    k_sim<<<256, 256, 0, stream>>>(tf, sim);
    k_sink<<<256, 256, 0, stream>>>(sim, outp);
    if (t < 2) {
      for (int pi = 3; pi >= 0; --pi)
        k_mix<<<256, 256, 0, stream>>>(sim, parts + (long)pi * ND, parts + (long)(pi + 1) * ND);
    }
  }
}

// Round 8
// 6071.545 us; speedup vs baseline: 3.7638x; 1.0608x over previous
//
#include <hip/hip_runtime.h>
#include <hip/hip_bf16.h>

#define NNODES   32768
#define NGROUPS  512
#define EPG      512
#define ND       (32768l*128)

typedef __attribute__((ext_vector_type(4))) float f32x4;
typedef __attribute__((ext_vector_type(8))) short bf16x8;

__device__ __forceinline__ short f2bf(float x) {
  unsigned u = __float_as_uint(x);
  unsigned r = (u + 0x7FFF + ((u >> 16) & 1)) >> 16;   // RNE
  return (short)r;
}
__device__ __forceinline__ float bf2f(short h) {
  return __uint_as_float(((unsigned)(unsigned short)h) << 16);
}
// 3-term bf16 split: x ~= h + m + l  (covers ~24 mantissa bits)
__device__ __forceinline__ void split3(float x, short* ph, short* pm, short* pl, long idx) {
  short h = f2bf(x); float r1 = x - bf2f(h);
  short m = f2bf(r1); float r2 = r1 - bf2f(m);
  ph[idx] = h; pm[idx] = m; pl[idx] = f2bf(r2);
}

// ---------------------------------------------------------------------------
// h0 = node_features(32768x32) @ W(32x128) + b
__global__ void k_node_enc(const float* __restrict__ nf, const float* __restrict__ w,
                           const float* __restrict__ b, float* __restrict__ h0) {
  int idx = blockIdx.x * 256 + threadIdx.x;
  int row = idx >> 7, col = idx & 127;
  const float* x = nf + row * 32;
  float acc = b[col];
#pragma unroll
  for (int k = 0; k < 32; ++k) acc = fmaf(x[k], w[k * 128 + col], acc);
  h0[idx] = acc;
}

// ---------------------------------------------------------------------------
// Folded weights (fp32):
//  blocks 0..15 : Wfold[16][256] = eew(16x64) @ mw1[256:320,:]
//  block  16    : bfold[256]     = eeb @ mw1[256:320,:] + mb1
//  block  17    : vbias[256]     = mb2 @ nw1[128:256,:]
__global__ void k_prep(const float* __restrict__ eew, const float* __restrict__ eeb,
                       const float* __restrict__ mw1, const float* __restrict__ mb1,
                       const float* __restrict__ mb2, const float* __restrict__ nw1,
                       float* __restrict__ Wfold, float* __restrict__ bfold,
                       float* __restrict__ vbias) {
  const int c = threadIdx.x, b = blockIdx.x;
  if (b < 16) {
    float a = 0.f;
    for (int j = 0; j < 64; ++j) a = fmaf(eew[b * 64 + j], mw1[(256 + j) * 256 + c], a);
    Wfold[b * 256 + c] = a;
  } else if (b == 16) {
    float a = mb1[c];
    for (int j = 0; j < 64; ++j) a = fmaf(eeb[j], mw1[(256 + j) * 256 + c], a);
    bfold[c] = a;
  } else {
    float a = 0.f;
    for (int j = 0; j < 128; ++j) a = fmaf(mb2[j], nw1[(128 + j) * 256 + c], a);
    vbias[c] = a;
  }
}

// ---------------------------------------------------------------------------
// Weight transpose + bf16x3 split: W (>=Kd x C row-major) -> Wt[c][k], k-stride 256
__global__ void k_wsplit3(const float* __restrict__ W, int C, int Kd,
                          short* __restrict__ th, short* __restrict__ tm,
                          short* __restrict__ tl) {
  const int c = blockIdx.x;
  for (int k = threadIdx.x; k < Kd; k += 256) {
    float w = W[(long)k * C + c];
    split3(w, th, tm, tl, c * 256 + k);
  }
}

// ---------------------------------------------------------------------------
// Deterministic CSR per group: edges stably sorted by to-node.
__global__ void k_csr(const int* __restrict__ from_idx, const int* __restrict__ to_idx,
                      const float* __restrict__ ef,
                      int* __restrict__ csr_f, int* __restrict__ rp_g,
                      float* __restrict__ efp, int* __restrict__ deg) {
  __shared__ int cnt[64], rps[65];
  __shared__ int tls[EPG], fls[EPG];
  __shared__ short ord[EPG];
  const int g = blockIdx.x, tid = threadIdx.x;
  const int be = g * EPG, bn = g * 64;
  if (tid < 64) cnt[tid] = 0;
  __syncthreads();
  for (int e = tid; e < EPG; e += 256) {
    int t = to_idx[be + e] - bn;
    tls[e] = t;
    fls[e] = from_idx[be + e] - bn;
    atomicAdd(&cnt[t], 1);
  }
  __syncthreads();
  if (tid == 0) {
    int s = 0;
    for (int i = 0; i < 64; ++i) { rps[i] = s; s += cnt[i]; }
    rps[64] = s;
  }
  __syncthreads();
  if (tid < 64) {
    int pos = rps[tid];
    for (int e = 0; e < EPG; ++e)
      if (tls[e] == tid) ord[pos++] = (short)e;
  }
  __syncthreads();
  for (int ec = tid; ec < EPG; ec += 256) {
    const int eo = ord[ec];
    csr_f[be + ec] = fls[eo];
    const float4* src = (const float4*)&ef[(long)(be + eo) * 16];
    float4* dst = (float4*)&efp[(long)(be + ec) * 16];
    dst[0] = src[0]; dst[1] = src[1]; dst[2] = src[2]; dst[3] = src[3];
  }
  if (tid < 65) rp_g[g * 65 + tid] = rps[tid];
  if (tid < 64) deg[bn + tid] = cnt[tid];
}

// ---------------------------------------------------------------------------
// MFMA bf16x3 2-layer MLP. X = [x0 | x1(+x1b)].
// RPX0: x0 read from pre-split planes. WPOUT: output written as bf16x3 planes.
template<int KTOT, bool DEG, bool SUM2, bool RPX0, bool WPOUT>
__global__ __launch_bounds__(256, 3)
void k_mlp2m(const float* __restrict__ x0,
             const short* __restrict__ x0h, const short* __restrict__ x0m,
             const short* __restrict__ x0l,
             const float* __restrict__ x1, const float* __restrict__ x1b,
             const short* __restrict__ W1h, const short* __restrict__ W1m,
             const short* __restrict__ W1l,
             const float* __restrict__ b1, const int* __restrict__ deg,
             const float* __restrict__ vbias,
             const short* __restrict__ W2h, const short* __restrict__ W2m,
             const short* __restrict__ W2l,
             const float* __restrict__ b2,
             float* __restrict__ out,
             short* __restrict__ outh, short* __restrict__ outm,
             short* __restrict__ outl) {
  __shared__ short xh[32 * 264];
  __shared__ short xm[32 * 264];
  __shared__ short xl[32 * 264];
  __shared__ int degs[32];
  const int tid = threadIdx.x;
  const long row0 = (long)blockIdx.x * 32;

  if constexpr (RPX0) {
    for (int i = tid; i < 32 * 16; i += 256) {
      const int r = i >> 4, q = i & 15;
      const long gb = (row0 + r) * 128 + q * 8;
      const int lb = r * 264 + q * 8;
      *(bf16x8*)&xh[lb] = *(const bf16x8*)&x0h[gb];
      *(bf16x8*)&xm[lb] = *(const bf16x8*)&x0m[gb];
      *(bf16x8*)&xl[lb] = *(const bf16x8*)&x0l[gb];
    }
  } else {
    for (int i = tid; i < 32 * 32; i += 256) {
      const int r = i >> 5, q = i & 31;
      float4 v = *(const float4*)&x0[(row0 + r) * 128 + q * 4];
      const int base = r * 264 + q * 4;
      split3(v.x, xh, xm, xl, base + 0);
      split3(v.y, xh, xm, xl, base + 1);
      split3(v.z, xh, xm, xl, base + 2);
      split3(v.w, xh, xm, xl, base + 3);
    }
  }
  if constexpr (KTOT == 256) {
    for (int i = tid; i < 32 * 32; i += 256) {
      const int r = i >> 5, q = i & 31;
      float4 v = *(const float4*)&x1[(row0 + r) * 128 + q * 4];
      if constexpr (SUM2) {
        float4 w = *(const float4*)&x1b[(row0 + r) * 128 + q * 4];
        v.x += w.x; v.y += w.y; v.z += w.z; v.w += w.w;
      }
      const int base = r * 264 + 128 + q * 4;
      split3(v.x, xh, xm, xl, base + 0);
      split3(v.y, xh, xm, xl, base + 1);
      split3(v.z, xh, xm, xl, base + 2);
      split3(v.w, xh, xm, xl, base + 3);
    }
  }
  if constexpr (DEG) { if (tid < 32) degs[tid] = deg[row0 + tid]; }
  __syncthreads();

  const int lane = tid & 63, wid = tid >> 6;
  const int lr = lane & 15;
  const int lk = (lane >> 4) * 8;
  const int rsub = (lane >> 4) * 4;

  // ---- layer 1: 32 x 256, wave cols [wid*64, wid*64+64) ----
  f32x4 acc[2][4];
#pragma unroll
  for (int fc = 0; fc < 4; ++fc) {
    const int col = wid * 64 + fc * 16 + lr;
    const float bv = b1[col];
#pragma unroll
    for (int fr = 0; fr < 2; ++fr) acc[fr][fc] = {bv, bv, bv, bv};
    if constexpr (DEG) {
      const float vb = vbias[col];
#pragma unroll
      for (int fr = 0; fr < 2; ++fr)
#pragma unroll
        for (int r = 0; r < 4; ++r)
          acc[fr][fc][r] += (float)degs[fr * 16 + rsub + r] * vb;
    }
  }

  for (int ks = 0; ks < KTOT / 32; ++ks) {
    const int k0 = ks * 32 + lk;
    bf16x8 ah[2], am[2], al[2];
#pragma unroll
    for (int fr = 0; fr < 2; ++fr) {
      const int ab = (fr * 16 + lr) * 264 + k0;
      ah[fr] = *(const bf16x8*)&xh[ab];
      am[fr] = *(const bf16x8*)&xm[ab];
      al[fr] = *(const bf16x8*)&xl[ab];
    }
#pragma unroll
    for (int fc = 0; fc < 4; ++fc) {
      const long wrow = (long)(wid * 64 + fc * 16 + lr) * 256 + k0;
      const bf16x8 bh = *(const bf16x8*)&W1h[wrow];
      const bf16x8 bm = *(const bf16x8*)&W1m[wrow];
      const bf16x8 bl = *(const bf16x8*)&W1l[wrow];
#pragma unroll
      for (int fr = 0; fr < 2; ++fr) {
        acc[fr][fc] = __builtin_amdgcn_mfma_f32_16x16x32_bf16(ah[fr], bh, acc[fr][fc], 0, 0, 0);
        acc[fr][fc] = __builtin_amdgcn_mfma_f32_16x16x32_bf16(ah[fr], bm, acc[fr][fc], 0, 0, 0);
        acc[fr][fc] = __builtin_amdgcn_mfma_f32_16x16x32_bf16(am[fr], bh, acc[fr][fc], 0, 0, 0);
        acc[fr][fc] = __builtin_amdgcn_mfma_f32_16x16x32_bf16(ah[fr], bl, acc[fr][fc], 0, 0, 0);
        acc[fr][fc] = __builtin_amdgcn_mfma_f32_16x16x32_bf16(am[fr], bm, acc[fr][fc], 0, 0, 0);
        acc[fr][fc] = __builtin_amdgcn_mfma_f32_16x16x32_bf16(al[fr], bh, acc[fr][fc], 0, 0, 0);
      }
    }
  }
  __syncthreads();

  // relu + split3 + store hidden to LDS [row][hcol]
#pragma unroll
  for (int fr = 0; fr < 2; ++fr)
#pragma unroll
    for (int fc = 0; fc < 4; ++fc) {
      const int col = wid * 64 + fc * 16 + lr;
#pragma unroll
      for (int r = 0; r < 4; ++r) {
        const int row = fr * 16 + rsub + r;
        float v = fmaxf(acc[fr][fc][r], 0.f);
        split3(v, xh, xm, xl, row * 264 + col);
      }
    }
  __syncthreads();

  // ---- layer 2: 32 x 128, wave cols [wid*32, wid*32+32) ----
  f32x4 acc2[2][2];
#pragma unroll
  for (int fc = 0; fc < 2; ++fc) {
    const float bv = b2[wid * 32 + fc * 16 + lr];
#pragma unroll
    for (int fr = 0; fr < 2; ++fr) acc2[fr][fc] = {bv, bv, bv, bv};
  }
  for (int ks = 0; ks < 8; ++ks) {
    const int k0 = ks * 32 + lk;
    bf16x8 ah[2], am[2], al[2];
#pragma unroll
    for (int fr = 0; fr < 2; ++fr) {
      const int ab = (fr * 16 + lr) * 264 + k0;
      ah[fr] = *(const bf16x8*)&xh[ab];
      am[fr] = *(const bf16x8*)&xm[ab];
      al[fr] = *(const bf16x8*)&xl[ab];
    }
#pragma unroll
    for (int fc = 0; fc < 2; ++fc) {
      const long wrow = (long)(wid * 32 + fc * 16 + lr) * 256 + k0;
      const bf16x8 bh = *(const bf16x8*)&W2h[wrow];
      const bf16x8 bm = *(const bf16x8*)&W2m[wrow];
      const bf16x8 bl = *(const bf16x8*)&W2l[wrow];
#pragma unroll
      for (int fr = 0; fr < 2; ++fr) {
        acc2[fr][fc] = __builtin_amdgcn_mfma_f32_16x16x32_bf16(ah[fr], bh, acc2[fr][fc], 0, 0, 0);
        acc2[fr][fc] = __builtin_amdgcn_mfma_f32_16x16x32_bf16(ah[fr], bm, acc2[fr][fc], 0, 0, 0);
        acc2[fr][fc] = __builtin_amdgcn_mfma_f32_16x16x32_bf16(am[fr], bh, acc2[fr][fc], 0, 0, 0);
        acc2[fr][fc] = __builtin_amdgcn_mfma_f32_16x16x32_bf16(ah[fr], bl, acc2[fr][fc], 0, 0, 0);
        acc2[fr][fc] = __builtin_amdgcn_mfma_f32_16x16x32_bf16(am[fr], bm, acc2[fr][fc], 0, 0, 0);
        acc2[fr][fc] = __builtin_amdgcn_mfma_f32_16x16x32_bf16(al[fr], bh, acc2[fr][fc], 0, 0, 0);
      }
    }
  }
#pragma unroll
  for (int fr = 0; fr < 2; ++fr)
#pragma unroll
    for (int fc = 0; fc < 2; ++fc) {
      const int col = wid * 32 + fc * 16 + lr;
#pragma unroll
      for (int r = 0; r < 4; ++r) {
        const long gi = (row0 + fr * 16 + rsub + r) * 128 + col;
        if constexpr (WPOUT) {
          split3(acc2[fr][fc][r], outh, outm, outl, gi);
        } else {
          out[gi] = acc2[fr][fc][r];
        }
      }
    }
}

// ---------------------------------------------------------------------------
// Fused per-group edge pipeline, MFMA GEMMs + fp32 CSR edge phase. grid (512,2).
// Spill-free schedule: cbi loop does {MFMA cA/cB -> LDS; edge segsum -> ag2[cbi]};
// then ONE deferred mw2 phase: split3 ag2[cbi] -> planes (aliased over cAB),
// aM += planes @ mw2t, with aM live only in this short tail.
__global__ __launch_bounds__(256, 2)
void k_edgem(const short* __restrict__ chp, const short* __restrict__ cmp,
             const short* __restrict__ clp,
             const float* __restrict__ efp,
             const short* __restrict__ m1h, const short* __restrict__ m1m,
             const short* __restrict__ m1l,
             const short* __restrict__ m2h, const short* __restrict__ m2m,
             const short* __restrict__ m2l,
             const float* __restrict__ Wfold, const float* __restrict__ bfold,
             const int* __restrict__ csr_f, const int* __restrict__ rp_g,
             float* __restrict__ aggM) {
  __shared__ __align__(16) float cAB[2 * 64 * 68];   // cA | cB ; later agp planes
  __shared__ __align__(16) float ag2[2][64 * 68];    // ag for cbi=0,1
  __shared__ int fl[EPG];
  __shared__ int rp[65];
  float* cA = cAB;
  float* cB = cAB + 64 * 68;
  short* agp = (short*)cAB;                 // 3 planes of [64][72] shorts (27.6KB)

  const int tid = threadIdx.x;
  const int g = blockIdx.x, half = blockIdx.y;
  const int be = g * EPG, bn = g * 64;

  for (int i = tid; i < EPG; i += 256) fl[i] = csr_f[be + i];
  if (tid < 65) rp[tid] = rp_g[g * 65 + tid];

  const int lane = tid & 63, wid = tid >> 6;
  const int lr = lane & 15;
  const int lk = (lane >> 4) * 8;
  const int rsub = (lane >> 4) * 4;
  const int ng = tid >> 4, cg = tid & 15;
  const int n0 = ng * 4, cq = cg * 4;

  for (int cbi = 0; cbi < 2; ++cbi) {
    const int col0 = (half * 2 + cbi) * 64;
    __syncthreads();   // fl/rp ready; prev iter's cA/cB reads done

    // phase a: MFMA cA/cB. waves 0,1 -> cA (mw1 k 0..127); waves 2,3 -> cB (k 128..255)
    {
      const int isB = wid >> 1;
      const int cw = (wid & 1) * 32;
      const int wkof = isB * 128;
      f32x4 c[4][2];
#pragma unroll
      for (int fr = 0; fr < 4; ++fr)
#pragma unroll
        for (int fc = 0; fc < 2; ++fc) c[fr][fc] = {0.f, 0.f, 0.f, 0.f};
      for (int ks = 0; ks < 4; ++ks) {
        const int k0 = ks * 32 + lk;
        bf16x8 ah[4], am[4], al[4];
#pragma unroll
        for (int fr = 0; fr < 4; ++fr) {
          const long ga = (long)(bn + fr * 16 + lr) * 128 + k0;
          ah[fr] = *(const bf16x8*)&chp[ga];
          am[fr] = *(const bf16x8*)&cmp[ga];
          al[fr] = *(const bf16x8*)&clp[ga];
        }
#pragma unroll
        for (int fc = 0; fc < 2; ++fc) {
          const long wrow = (long)(col0 + cw + fc * 16 + lr) * 256 + wkof + k0;
          const bf16x8 bh = *(const bf16x8*)&m1h[wrow];
          const bf16x8 bm = *(const bf16x8*)&m1m[wrow];
          const bf16x8 bl = *(const bf16x8*)&m1l[wrow];
#pragma unroll
          for (int fr = 0; fr < 4; ++fr) {
            c[fr][fc] = __builtin_amdgcn_mfma_f32_16x16x32_bf16(ah[fr], bh, c[fr][fc], 0, 0, 0);
            c[fr][fc] = __builtin_amdgcn_mfma_f32_16x16x32_bf16(ah[fr], bm, c[fr][fc], 0, 0, 0);
            c[fr][fc] = __builtin_amdgcn_mfma_f32_16x16x32_bf16(am[fr], bh, c[fr][fc], 0, 0, 0);
            c[fr][fc] = __builtin_amdgcn_mfma_f32_16x16x32_bf16(ah[fr], bl, c[fr][fc], 0, 0, 0);
            c[fr][fc] = __builtin_amdgcn_mfma_f32_16x16x32_bf16(am[fr], bm, c[fr][fc], 0, 0, 0);
            c[fr][fc] = __builtin_amdgcn_mfma_f32_16x16x32_bf16(al[fr], bh, c[fr][fc], 0, 0, 0);
          }
        }
      }
      float* dstC = isB ? cB : cA;
#pragma unroll
      for (int fr = 0; fr < 4; ++fr)
#pragma unroll
        for (int fc = 0; fc < 2; ++fc) {
          const int col = cw + fc * 16 + lr;
#pragma unroll
          for (int r = 0; r < 4; ++r)
            dstC[(fr * 16 + rsub + r) * 68 + col] = c[fr][fc][r];
        }
    }
    float4 Wf[16];
#pragma unroll
    for (int k = 0; k < 16; ++k) Wf[k] = *(const float4*)&Wfold[k * 256 + col0 + cq];
    const float4 bf = *(const float4*)&bfold[col0 + cq];
    __syncthreads();   // cA/cB visible

    // phase b: edge phase (fp32 CSR, atomic-free) -> ag2[cbi]
#pragma unroll
    for (int i = 0; i < 4; ++i) {
      const int n = n0 + i;
      float4 acc = make_float4(0.f, 0.f, 0.f, 0.f);
      const float4 cBn = *(const float4*)&cB[n * 68 + cq];
      const int e1 = rp[n + 1];
      for (int e = rp[n]; e < e1; ++e) {
        const int f = fl[e];
        const float* er = efp + (long)(be + e) * 16;
        float4 h = bf;
#pragma unroll
        for (int kq = 0; kq < 4; ++kq) {
          const float4 e4 = *(const float4*)(er + kq * 4);
          const float ev[4] = {e4.x, e4.y, e4.z, e4.w};
#pragma unroll
          for (int s = 0; s < 4; ++s) {
            const float4 w = Wf[kq * 4 + s];
            h.x = fmaf(ev[s], w.x, h.x); h.y = fmaf(ev[s], w.y, h.y);
            h.z = fmaf(ev[s], w.z, h.z); h.w = fmaf(ev[s], w.w, h.w);
          }
        }
        const float4 va = *(const float4*)&cA[f * 68 + cq];
        acc.x += fmaxf(h.x + va.x + cBn.x, 0.f);
        acc.y += fmaxf(h.y + va.y + cBn.y, 0.f);
        acc.z += fmaxf(h.z + va.z + cBn.z, 0.f);
        acc.w += fmaxf(h.w + va.w + cBn.w, 0.f);
      }
      *(float4*)&ag2[cbi][n * 68 + cq] = acc;
    }
  }
  __syncthreads();   // both ag2 complete; cAB dead

  // deferred mw2 phase: aM lives only here (no spill across phases a/b)
  f32x4 aM[4][2];
#pragma unroll
  for (int fr = 0; fr < 4; ++fr)
#pragma unroll
    for (int fc = 0; fc < 2; ++fc) aM[fr][fc] = {0.f, 0.f, 0.f, 0.f};

  for (int cbi = 0; cbi < 2; ++cbi) {
    const int col0 = (half * 2 + cbi) * 64;
    // split3 ag2[cbi] -> agp planes [64][72] (aliased over cAB)
    for (int i = tid; i < 1024; i += 256) {
      const int n = i >> 4, kq = (i & 15) * 4;
      const float4 v = *(const float4*)&ag2[cbi][n * 68 + kq];
      const int b0 = n * 72 + kq;
      split3(v.x, agp, agp + 4608, agp + 9216, b0 + 0);
      split3(v.y, agp, agp + 4608, agp + 9216, b0 + 1);
      split3(v.z, agp, agp + 4608, agp + 9216, b0 + 2);
      split3(v.w, agp, agp + 4608, agp + 9216, b0 + 3);
    }
    __syncthreads();

    // aM += agp @ mw2t[col0 slice]  (K=64)
    for (int ks = 0; ks < 2; ++ks) {
      const int k0 = ks * 32 + lk;
      bf16x8 ah[4], am[4], al[4];
#pragma unroll
      for (int fr = 0; fr < 4; ++fr) {
        const int ab = (fr * 16 + lr) * 72 + k0;
        ah[fr] = *(const bf16x8*)&agp[ab];
        am[fr] = *(const bf16x8*)&agp[4608 + ab];
        al[fr] = *(const bf16x8*)&agp[9216 + ab];
      }
#pragma unroll
      for (int fc = 0; fc < 2; ++fc) {
        const long wrow = (long)(wid * 32 + fc * 16 + lr) * 256 + col0 + k0;
        const bf16x8 bh = *(const bf16x8*)&m2h[wrow];
        const bf16x8 bm = *(const bf16x8*)&m2m[wrow];
        const bf16x8 bl = *(const bf16x8*)&m2l[wrow];
#pragma unroll
        for (int fr = 0; fr < 4; ++fr) {
          aM[fr][fc] = __builtin_amdgcn_mfma_f32_16x16x32_bf16(ah[fr], bh, aM[fr][fc], 0, 0, 0);
          aM[fr][fc] = __builtin_amdgcn_mfma_f32_16x16x32_bf16(ah[fr], bm, aM[fr][fc], 0, 0, 0);
          aM[fr][fc] = __builtin_amdgcn_mfma_f32_16x16x32_bf16(am[fr], bh, aM[fr][fc], 0, 0, 0);
          aM[fr][fc] = __builtin_amdgcn_mfma_f32_16x16x32_bf16(ah[fr], bl, aM[fr][fc], 0, 0, 0);
          aM[fr][fc] = __builtin_amdgcn_mfma_f32_16x16x32_bf16(am[fr], bm, aM[fr][fc], 0, 0, 0);
          aM[fr][fc] = __builtin_amdgcn_mfma_f32_16x16x32_bf16(al[fr], bh, aM[fr][fc], 0, 0, 0);
        }
      }
    }
    __syncthreads();   // agp consumed before next overwrite
  }

  float* aggMh = aggM + (long)half * ND;
#pragma unroll
  for (int fr = 0; fr < 4; ++fr)
#pragma unroll
    for (int fc = 0; fc < 2; ++fc) {
      const int col = wid * 32 + fc * 16 + lr;
#pragma unroll
      for (int r = 0; r < 4; ++r)
        aggMh[(long)(bn + fr * 16 + rsub + r) * 128 + col] = aM[fr][fc][r];
    }
}

// ---------------------------------------------------------------------------
__global__ void k_tfeat(const float* __restrict__ x,
                        const float* __restrict__ t1w, const float* __restrict__ t1b,
                        const float* __restrict__ t2w, const float* __restrict__ t2b,
                        float* __restrict__ tf) {
  __shared__ float xs[4][128];
  __shared__ float ys[4][64];
  const int tid = threadIdx.x;
  const long row0 = (long)blockIdx.x * 4;
  for (int i = tid; i < 512; i += 256)
    xs[i >> 7][i & 127] = x[(row0 + (i >> 7)) * 128 + (i & 127)];
  __syncthreads();
  const int r = tid >> 6, c = tid & 63;
  float acc = t1b[c];
#pragma unroll 4
  for (int k = 0; k < 128; ++k) acc = fmaf(xs[r][k], t1w[k * 64 + c], acc);
  ys[r][c] = fmaxf(acc, 0.f);
  __syncthreads();
  float a2 = t2b[c];
#pragma unroll 4
  for (int k = 0; k < 64; ++k) a2 = fmaf(ys[r][k], t2w[k * 64 + c], a2);
  tf[(row0 + r) * 64 + c] = a2;
}

// ---------------------------------------------------------------------------
__global__ void k_sim(const float* __restrict__ tf, float* __restrict__ sim) {
  const int b = blockIdx.x, tid = threadIdx.x;
  __shared__ float tq[64][65];
  __shared__ float tcs[64][65];
  for (int i = tid; i < 4096; i += 256) {
    tq[i >> 6][i & 63]  = tf[(long)b * 8192 + i];
    tcs[i >> 6][i & 63] = tf[(long)b * 8192 + 4096 + i];
  }
  __syncthreads();
  const int m = tid >> 2, j0 = (tid & 3) * 16;
#pragma unroll
  for (int j = 0; j < 16; ++j) {
    float a = 0.f;
#pragma unroll 4
    for (int k = 0; k < 64; ++k) a = fmaf(tq[m][k], tcs[j0 + j][k], a);
    sim[(long)b * 4096 + m * 64 + j0 + j] = a;
  }
}

// ---------------------------------------------------------------------------
__global__ void k_sink(float* __restrict__ sim, float* __restrict__ outp) {
  const int b = blockIdx.x, tid = threadIdx.x;
  __shared__ float la[64][65];
  const float C = 14.426950408889634f;   // 10 / ln(2)
  for (int i = tid; i < 4096; i += 256)
    la[i >> 6][i & 63] = sim[(long)b * 4096 + i] * C;
  __syncthreads();
  const int r4 = tid >> 2, l4 = tid & 3;
  for (int it = 0; it < 20; ++it) {
    {
      float m = -3.4e38f;
#pragma unroll
      for (int i = 0; i < 16; ++i) m = fmaxf(m, la[r4][l4 + 4 * i]);
      m = fmaxf(m, __shfl_xor(m, 1)); m = fmaxf(m, __shfl_xor(m, 2));
      float s = 0.f;
#pragma unroll
      for (int i = 0; i < 16; ++i) s += exp2f(la[r4][l4 + 4 * i] - m);
      s += __shfl_xor(s, 1); s += __shfl_xor(s, 2);
      const float lse = m + log2f(s);
#pragma unroll
      for (int i = 0; i < 16; ++i) la[r4][l4 + 4 * i] -= lse;
    }
    __syncthreads();
    {
      float m = -3.4e38f;
#pragma unroll
      for (int i = 0; i < 16; ++i) m = fmaxf(m, la[l4 + 4 * i][r4]);
      m = fmaxf(m, __shfl_xor(m, 1)); m = fmaxf(m, __shfl_xor(m, 2));
      float s = 0.f;
#pragma unroll
      for (int i = 0; i < 16; ++i) s += exp2f(la[l4 + 4 * i][r4] - m);
      s += __shfl_xor(s, 1); s += __shfl_xor(s, 2);
      const float lse = m + log2f(s);
#pragma unroll
      for (int i = 0; i < 16; ++i) la[l4 + 4 * i][r4] -= lse;
    }
    __syncthreads();
  }
  for (int i = tid; i < 4096; i += 256) {
    const float v = exp2f(la[i >> 6][i & 63]);
    outp[(long)b * 4096 + i] = v;
    sim[(long)b * 4096 + i] = v;
  }
}

// ---------------------------------------------------------------------------
__global__ void k_mix(const float* __restrict__ plan, const float* __restrict__ src,
                      float* __restrict__ dst) {
  const int b = blockIdx.x, tid = threadIdx.x;
  __shared__ float pl[64][65];
  __shared__ float qs[64][128];
  __shared__ float cs[64][128];
  const long qbase = (long)(2 * b) * 64, cbase = qbase + 64;
  for (int i = tid; i < 4096; i += 256) pl[i >> 6][i & 63] = plan[(long)b * 4096 + i];
  for (int i = tid; i < 8192; i += 256) {
    qs[i >> 7][i & 127] = src[qbase * 128 + i];
    cs[i >> 7][i & 127] = src[cbase * 128 + i];
  }
  __syncthreads();
  const int d = tid & 127, m0 = (tid >> 7) * 32;
  for (int m = m0; m < m0 + 32; ++m) {
    float a = 0.f;
#pragma unroll 4
    for (int j = 0; j < 64; ++j) a = fmaf(pl[m][j], cs[j][d], a);
    dst[(qbase + m) * 128 + d] = a;
  }
  for (int j = m0; j < m0 + 32; ++j) {
    float a = 0.f;
#pragma unroll 4
    for (int m = 0; m < 64; ++m) a = fmaf(pl[m][j], qs[m][d], a);
    dst[(cbase + j) * 128 + d] = a;
  }
}

// ---------------------------------------------------------------------------
extern "C" void kernel_launch(void* const* d_in, const int* in_sizes, int n_in,
                              void* d_out, int out_size, void* d_ws, size_t ws_size,
                              hipStream_t stream) {
  const float* nf  = (const float*)d_in[0];
  const float* ef  = (const float*)d_in[1];
  const int* from_idx = (const int*)d_in[2];
  const int* to_idx   = (const int*)d_in[3];
  const float* new_w = (const float*)d_in[4];
  const float* new_b = (const float*)d_in[5];
  const float* eew = (const float*)d_in[6];
  const float* eeb = (const float*)d_in[7];
  const float* mw1 = (const float*)d_in[8];
  const float* mb1 = (const float*)d_in[9];
  const float* mw2 = (const float*)d_in[10];
  const float* mb2 = (const float*)d_in[11];
  const float* nw1 = (const float*)d_in[12];
  const float* nb1 = (const float*)d_in[13];
  const float* nw2 = (const float*)d_in[14];
  const float* nb2 = (const float*)d_in[15];
  const float* cw1 = (const float*)d_in[16];
  const float* cb1 = (const float*)d_in[17];
  const float* cw2 = (const float*)d_in[18];
  const float* cb2 = (const float*)d_in[19];
  const float* t1w = (const float*)d_in[20];
  const float* t1b = (const float*)d_in[21];
  const float* t2w = (const float*)d_in[22];
  const float* t2b = (const float*)d_in[23];

  float* W = (float*)d_ws;
  float* h0     = W;                       // ND
  float* aggM0  = h0 + ND;                 // ND (tf/sim alias here)
  float* aggM1  = aggM0 + ND;              // ND
  float* parts  = aggM1 + ND;              // 5*ND
  float* efp    = parts + 5 * ND;          // 262144*16
  float* Wfold  = efp + 262144l * 16;      // 4096
  float* bfold  = Wfold + 4096;            // 256
  float* vbias  = bfold + 256;             // 256
  int*   deg    = (int*)(vbias + 256);     // 32768
  int*   csr_f  = deg + 32768;             // 262144
  int*   rp_g   = csr_f + 262144;          // 512*65 = 33280
  short* cw1t_h = (short*)(rp_g + 33280);  // 65536 shorts per plane
  short* cw1t_m = cw1t_h + 65536;
  short* cw1t_l = cw1t_m + 65536;
  short* nw1t_h = cw1t_l + 65536;
  short* nw1t_m = nw1t_h + 65536;
  short* nw1t_l = nw1t_m + 65536;
  short* cw2t_h = nw1t_l + 65536;          // 32768 each
  short* cw2t_m = cw2t_h + 32768;
  short* cw2t_l = cw2t_m + 32768;
  short* nw2t_h = cw2t_l + 32768;
  short* nw2t_m = nw2t_h + 32768;
  short* nw2t_l = nw2t_m + 32768;
  short* m1t_h  = nw2t_l + 32768;          // mw1[0:256] -> 65536 each
  short* m1t_m  = m1t_h + 65536;
  short* m1t_l  = m1t_m + 65536;
  short* m2t_h  = m1t_l + 65536;           // mw2 -> 32768 each
  short* m2t_m  = m2t_h + 32768;
  short* m2t_l  = m2t_m + 32768;
  short* chp    = m2t_l + 32768;           // comb planes: 32768*128 shorts each
  short* cmp    = chp + 32768l * 128;
  short* clp    = cmp + 32768l * 128;
  float* tf     = aggM0;                   // 32768*64
  float* sim    = aggM0 + 2097152;         // 256*4096
  float* outp   = (float*)d_out;

  k_prep<<<18, 256, 0, stream>>>(eew, eeb, mw1, mb1, mb2, nw1, Wfold, bfold, vbias);
  k_csr<<<512, 256, 0, stream>>>(from_idx, to_idx, ef, csr_f, rp_g, efp, deg);
  k_wsplit3<<<256, 256, 0, stream>>>(cw1, 256, 256, cw1t_h, cw1t_m, cw1t_l);
  k_wsplit3<<<256, 256, 0, stream>>>(nw1, 256, 256, nw1t_h, nw1t_m, nw1t_l);
  k_wsplit3<<<128, 256, 0, stream>>>(cw2, 128, 256, cw2t_h, cw2t_m, cw2t_l);
  k_wsplit3<<<128, 256, 0, stream>>>(nw2, 128, 256, nw2t_h, nw2t_m, nw2t_l);
  k_wsplit3<<<256, 256, 0, stream>>>(mw1, 256, 256, m1t_h, m1t_m, m1t_l);
  k_wsplit3<<<128, 256, 0, stream>>>(mw2, 128, 256, m2t_h, m2t_m, m2t_l);
  k_node_enc<<<16384, 256, 0, stream>>>(nf, new_w, new_b, h0);

  for (int t = 0; t < 3; ++t) {
    const float* hprev = h0;
    for (int p = 1; p <= 5; ++p) {
      if (t > 0 && p > 1)
        k_mlp2m<256, false, false, false, true><<<1024, 256, 0, stream>>>(
            hprev, nullptr, nullptr, nullptr,
            parts + (long)(p - 1) * ND, nullptr,
            cw1t_h, cw1t_m, cw1t_l, cb1, nullptr, nullptr,
            cw2t_h, cw2t_m, cw2t_l, cb2, nullptr, chp, cmp, clp);
      else
        k_mlp2m<128, false, false, false, true><<<1024, 256, 0, stream>>>(
            hprev, nullptr, nullptr, nullptr, nullptr, nullptr,
            cw1t_h, cw1t_m, cw1t_l, cb1, nullptr, nullptr,
            cw2t_h, cw2t_m, cw2t_l, cb2, nullptr, chp, cmp, clp);
      k_edgem<<<dim3(512, 2), 256, 0, stream>>>(chp, cmp, clp, efp,
                                                m1t_h, m1t_m, m1t_l,
                                                m2t_h, m2t_m, m2t_l,
                                                Wfold, bfold, csr_f, rp_g, aggM0);
      float* hnew = parts + (long)(p - 1) * ND;
      k_mlp2m<256, true, true, true, false><<<1024, 256, 0, stream>>>(
          nullptr, chp, cmp, clp, aggM0, aggM1,
          nw1t_h, nw1t_m, nw1t_l, nb1, deg, vbias,
          nw2t_h, nw2t_m, nw2t_l, nb2, hnew, nullptr, nullptr, nullptr);
      hprev = hnew;
    }
    k_tfeat<<<8192, 256, 0, stream>>>(parts + 4 * ND, t1w, t1b, t2w, t2b, tf);
    k_sim<<<256, 256, 0, stream>>>(tf, sim);
    k_sink<<<256, 256, 0, stream>>>(sim, outp);
    if (t < 2) {
      for (int pi = 3; pi >= 0; --pi)
        k_mix<<<256, 256, 0, stream>>>(sim, parts + (long)pi * ND, parts + (long)(pi + 1) * ND);
    }
  }
}

// Round 9
// 5985.490 us; speedup vs baseline: 3.8179x; 1.0144x over previous
//
#include <hip/hip_runtime.h>
#include <hip/hip_bf16.h>

#define NNODES   32768
#define NGROUPS  512
#define EPG      512
#define ND       (32768l*128)

typedef __attribute__((ext_vector_type(4))) float f32x4;
typedef __attribute__((ext_vector_type(8))) short bf16x8;

__device__ __forceinline__ short f2bf(float x) {
  unsigned u = __float_as_uint(x);
  unsigned r = (u + 0x7FFF + ((u >> 16) & 1)) >> 16;   // RNE
  return (short)r;
}
__device__ __forceinline__ float bf2f(short h) {
  return __uint_as_float(((unsigned)(unsigned short)h) << 16);
}
// 3-term bf16 split: x ~= h + m + l  (covers ~24 mantissa bits)
__device__ __forceinline__ void split3(float x, short* ph, short* pm, short* pl, long idx) {
  short h = f2bf(x); float r1 = x - bf2f(h);
  short m = f2bf(r1); float r2 = r1 - bf2f(m);
  ph[idx] = h; pm[idx] = m; pl[idx] = f2bf(r2);
}

// ---------------------------------------------------------------------------
// h0 = node_features(32768x32) @ W(32x128) + b
__global__ void k_node_enc(const float* __restrict__ nf, const float* __restrict__ w,
                           const float* __restrict__ b, float* __restrict__ h0) {
  int idx = blockIdx.x * 256 + threadIdx.x;
  int row = idx >> 7, col = idx & 127;
  const float* x = nf + row * 32;
  float acc = b[col];
#pragma unroll
  for (int k = 0; k < 32; ++k) acc = fmaf(x[k], w[k * 128 + col], acc);
  h0[idx] = acc;
}

// ---------------------------------------------------------------------------
// Folded weights (fp32):
//  blocks 0..15 : Wfold[16][256] = eew(16x64) @ mw1[256:320,:]
//  block  16    : bfold[256]     = eeb @ mw1[256:320,:] + mb1
//  block  17    : vbias[256]     = mb2 @ nw1[128:256,:]
__global__ void k_prep(const float* __restrict__ eew, const float* __restrict__ eeb,
                       const float* __restrict__ mw1, const float* __restrict__ mb1,
                       const float* __restrict__ mb2, const float* __restrict__ nw1,
                       float* __restrict__ Wfold, float* __restrict__ bfold,
                       float* __restrict__ vbias) {
  const int c = threadIdx.x, b = blockIdx.x;
  if (b < 16) {
    float a = 0.f;
    for (int j = 0; j < 64; ++j) a = fmaf(eew[b * 64 + j], mw1[(256 + j) * 256 + c], a);
    Wfold[b * 256 + c] = a;
  } else if (b == 16) {
    float a = mb1[c];
    for (int j = 0; j < 64; ++j) a = fmaf(eeb[j], mw1[(256 + j) * 256 + c], a);
    bfold[c] = a;
  } else {
    float a = 0.f;
    for (int j = 0; j < 128; ++j) a = fmaf(mb2[j], nw1[(128 + j) * 256 + c], a);
    vbias[c] = a;
  }
}

// ---------------------------------------------------------------------------
// Weight transpose + bf16x3 split: W (>=Kd x C row-major) -> Wt[c][k], k-stride 256
__global__ void k_wsplit3(const float* __restrict__ W, int C, int Kd,
                          short* __restrict__ th, short* __restrict__ tm,
                          short* __restrict__ tl) {
  const int c = blockIdx.x;
  for (int k = threadIdx.x; k < Kd; k += 256) {
    float w = W[(long)k * C + c];
    split3(w, th, tm, tl, c * 256 + k);
  }
}

// ---------------------------------------------------------------------------
// Deterministic CSR per group: edges stably sorted by to-node.
__global__ void k_csr(const int* __restrict__ from_idx, const int* __restrict__ to_idx,
                      const float* __restrict__ ef,
                      int* __restrict__ csr_f, int* __restrict__ rp_g,
                      float* __restrict__ efp, int* __restrict__ deg) {
  __shared__ int cnt[64], rps[65];
  __shared__ int tls[EPG], fls[EPG];
  __shared__ short ord[EPG];
  const int g = blockIdx.x, tid = threadIdx.x;
  const int be = g * EPG, bn = g * 64;
  if (tid < 64) cnt[tid] = 0;
  __syncthreads();
  for (int e = tid; e < EPG; e += 256) {
    int t = to_idx[be + e] - bn;
    tls[e] = t;
    fls[e] = from_idx[be + e] - bn;
    atomicAdd(&cnt[t], 1);
  }
  __syncthreads();
  if (tid == 0) {
    int s = 0;
    for (int i = 0; i < 64; ++i) { rps[i] = s; s += cnt[i]; }
    rps[64] = s;
  }
  __syncthreads();
  if (tid < 64) {
    int pos = rps[tid];
    for (int e = 0; e < EPG; ++e)
      if (tls[e] == tid) ord[pos++] = (short)e;
  }
  __syncthreads();
  for (int ec = tid; ec < EPG; ec += 256) {
    const int eo = ord[ec];
    csr_f[be + ec] = fls[eo];
    const float4* src = (const float4*)&ef[(long)(be + eo) * 16];
    float4* dst = (float4*)&efp[(long)(be + ec) * 16];
    dst[0] = src[0]; dst[1] = src[1]; dst[2] = src[2]; dst[3] = src[3];
  }
  if (tid < 65) rp_g[g * 65 + tid] = rps[tid];
  if (tid < 64) deg[bn + tid] = cnt[tid];
}

// ---------------------------------------------------------------------------
// MFMA bf16x3 2-layer MLP. X = [x0 | x1(+x1b)].
// RPX0: x0 read from pre-split planes. WPOUT: output written as bf16x3 planes.
template<int KTOT, bool DEG, bool SUM2, bool RPX0, bool WPOUT>
__global__ __launch_bounds__(256, 3)
void k_mlp2m(const float* __restrict__ x0,
             const short* __restrict__ x0h, const short* __restrict__ x0m,
             const short* __restrict__ x0l,
             const float* __restrict__ x1, const float* __restrict__ x1b,
             const short* __restrict__ W1h, const short* __restrict__ W1m,
             const short* __restrict__ W1l,
             const float* __restrict__ b1, const int* __restrict__ deg,
             const float* __restrict__ vbias,
             const short* __restrict__ W2h, const short* __restrict__ W2m,
             const short* __restrict__ W2l,
             const float* __restrict__ b2,
             float* __restrict__ out,
             short* __restrict__ outh, short* __restrict__ outm,
             short* __restrict__ outl) {
  __shared__ short xh[32 * 264];
  __shared__ short xm[32 * 264];
  __shared__ short xl[32 * 264];
  __shared__ int degs[32];
  const int tid = threadIdx.x;
  const long row0 = (long)blockIdx.x * 32;

  if constexpr (RPX0) {
    for (int i = tid; i < 32 * 16; i += 256) {
      const int r = i >> 4, q = i & 15;
      const long gb = (row0 + r) * 128 + q * 8;
      const int lb = r * 264 + q * 8;
      *(bf16x8*)&xh[lb] = *(const bf16x8*)&x0h[gb];
      *(bf16x8*)&xm[lb] = *(const bf16x8*)&x0m[gb];
      *(bf16x8*)&xl[lb] = *(const bf16x8*)&x0l[gb];
    }
  } else {
    for (int i = tid; i < 32 * 32; i += 256) {
      const int r = i >> 5, q = i & 31;
      float4 v = *(const float4*)&x0[(row0 + r) * 128 + q * 4];
      const int base = r * 264 + q * 4;
      split3(v.x, xh, xm, xl, base + 0);
      split3(v.y, xh, xm, xl, base + 1);
      split3(v.z, xh, xm, xl, base + 2);
      split3(v.w, xh, xm, xl, base + 3);
    }
  }
  if constexpr (KTOT == 256) {
    for (int i = tid; i < 32 * 32; i += 256) {
      const int r = i >> 5, q = i & 31;
      float4 v = *(const float4*)&x1[(row0 + r) * 128 + q * 4];
      if constexpr (SUM2) {
        float4 w = *(const float4*)&x1b[(row0 + r) * 128 + q * 4];
        v.x += w.x; v.y += w.y; v.z += w.z; v.w += w.w;
      }
      const int base = r * 264 + 128 + q * 4;
      split3(v.x, xh, xm, xl, base + 0);
      split3(v.y, xh, xm, xl, base + 1);
      split3(v.z, xh, xm, xl, base + 2);
      split3(v.w, xh, xm, xl, base + 3);
    }
  }
  if constexpr (DEG) { if (tid < 32) degs[tid] = deg[row0 + tid]; }
  __syncthreads();

  const int lane = tid & 63, wid = tid >> 6;
  const int lr = lane & 15;
  const int lk = (lane >> 4) * 8;
  const int rsub = (lane >> 4) * 4;

  // ---- layer 1: 32 x 256, wave cols [wid*64, wid*64+64) ----
  f32x4 acc[2][4];
#pragma unroll
  for (int fc = 0; fc < 4; ++fc) {
    const int col = wid * 64 + fc * 16 + lr;
    const float bv = b1[col];
#pragma unroll
    for (int fr = 0; fr < 2; ++fr) acc[fr][fc] = {bv, bv, bv, bv};
    if constexpr (DEG) {
      const float vb = vbias[col];
#pragma unroll
      for (int fr = 0; fr < 2; ++fr)
#pragma unroll
        for (int r = 0; r < 4; ++r)
          acc[fr][fc][r] += (float)degs[fr * 16 + rsub + r] * vb;
    }
  }

  for (int ks = 0; ks < KTOT / 32; ++ks) {
    const int k0 = ks * 32 + lk;
    bf16x8 ah[2], am[2], al[2];
#pragma unroll
    for (int fr = 0; fr < 2; ++fr) {
      const int ab = (fr * 16 + lr) * 264 + k0;
      ah[fr] = *(const bf16x8*)&xh[ab];
      am[fr] = *(const bf16x8*)&xm[ab];
      al[fr] = *(const bf16x8*)&xl[ab];
    }
#pragma unroll
    for (int fc = 0; fc < 4; ++fc) {
      const long wrow = (long)(wid * 64 + fc * 16 + lr) * 256 + k0;
      const bf16x8 bh = *(const bf16x8*)&W1h[wrow];
      const bf16x8 bm = *(const bf16x8*)&W1m[wrow];
      const bf16x8 bl = *(const bf16x8*)&W1l[wrow];
#pragma unroll
      for (int fr = 0; fr < 2; ++fr) {
        acc[fr][fc] = __builtin_amdgcn_mfma_f32_16x16x32_bf16(ah[fr], bh, acc[fr][fc], 0, 0, 0);
        acc[fr][fc] = __builtin_amdgcn_mfma_f32_16x16x32_bf16(ah[fr], bm, acc[fr][fc], 0, 0, 0);
        acc[fr][fc] = __builtin_amdgcn_mfma_f32_16x16x32_bf16(am[fr], bh, acc[fr][fc], 0, 0, 0);
        acc[fr][fc] = __builtin_amdgcn_mfma_f32_16x16x32_bf16(ah[fr], bl, acc[fr][fc], 0, 0, 0);
        acc[fr][fc] = __builtin_amdgcn_mfma_f32_16x16x32_bf16(am[fr], bm, acc[fr][fc], 0, 0, 0);
        acc[fr][fc] = __builtin_amdgcn_mfma_f32_16x16x32_bf16(al[fr], bh, acc[fr][fc], 0, 0, 0);
      }
    }
  }
  __syncthreads();

  // relu + split3 + store hidden to LDS [row][hcol]
#pragma unroll
  for (int fr = 0; fr < 2; ++fr)
#pragma unroll
    for (int fc = 0; fc < 4; ++fc) {
      const int col = wid * 64 + fc * 16 + lr;
#pragma unroll
      for (int r = 0; r < 4; ++r) {
        const int row = fr * 16 + rsub + r;
        float v = fmaxf(acc[fr][fc][r], 0.f);
        split3(v, xh, xm, xl, row * 264 + col);
      }
    }
  __syncthreads();

  // ---- layer 2: 32 x 128, wave cols [wid*32, wid*32+32) ----
  f32x4 acc2[2][2];
#pragma unroll
  for (int fc = 0; fc < 2; ++fc) {
    const float bv = b2[wid * 32 + fc * 16 + lr];
#pragma unroll
    for (int fr = 0; fr < 2; ++fr) acc2[fr][fc] = {bv, bv, bv, bv};
  }
  for (int ks = 0; ks < 8; ++ks) {
    const int k0 = ks * 32 + lk;
    bf16x8 ah[2], am[2], al[2];
#pragma unroll
    for (int fr = 0; fr < 2; ++fr) {
      const int ab = (fr * 16 + lr) * 264 + k0;
      ah[fr] = *(const bf16x8*)&xh[ab];
      am[fr] = *(const bf16x8*)&xm[ab];
      al[fr] = *(const bf16x8*)&xl[ab];
    }
#pragma unroll
    for (int fc = 0; fc < 2; ++fc) {
      const long wrow = (long)(wid * 32 + fc * 16 + lr) * 256 + k0;
      const bf16x8 bh = *(const bf16x8*)&W2h[wrow];
      const bf16x8 bm = *(const bf16x8*)&W2m[wrow];
      const bf16x8 bl = *(const bf16x8*)&W2l[wrow];
#pragma unroll
      for (int fr = 0; fr < 2; ++fr) {
        acc2[fr][fc] = __builtin_amdgcn_mfma_f32_16x16x32_bf16(ah[fr], bh, acc2[fr][fc], 0, 0, 0);
        acc2[fr][fc] = __builtin_amdgcn_mfma_f32_16x16x32_bf16(ah[fr], bm, acc2[fr][fc], 0, 0, 0);
        acc2[fr][fc] = __builtin_amdgcn_mfma_f32_16x16x32_bf16(am[fr], bh, acc2[fr][fc], 0, 0, 0);
        acc2[fr][fc] = __builtin_amdgcn_mfma_f32_16x16x32_bf16(ah[fr], bl, acc2[fr][fc], 0, 0, 0);
        acc2[fr][fc] = __builtin_amdgcn_mfma_f32_16x16x32_bf16(am[fr], bm, acc2[fr][fc], 0, 0, 0);
        acc2[fr][fc] = __builtin_amdgcn_mfma_f32_16x16x32_bf16(al[fr], bh, acc2[fr][fc], 0, 0, 0);
      }
    }
  }
#pragma unroll
  for (int fr = 0; fr < 2; ++fr)
#pragma unroll
    for (int fc = 0; fc < 2; ++fc) {
      const int col = wid * 32 + fc * 16 + lr;
#pragma unroll
      for (int r = 0; r < 4; ++r) {
        const long gi = (row0 + fr * 16 + rsub + r) * 128 + col;
        if constexpr (WPOUT) {
          split3(acc2[fr][fc][r], outh, outm, outl, gi);
        } else {
          out[gi] = acc2[fr][fc][r];
        }
      }
    }
}

// ---------------------------------------------------------------------------
// Fused per-group edge pipeline, MFMA GEMMs + fp32 CSR edge phase. grid (512,2).
// waves_per_eu(2,2): LDS (72KB) caps at 2 blocks/CU anyway -> 256-VGPR budget,
// eliminating the 128-cap scratch spills. Phase a split into two fr-passes
// (unroll 1) so register demand stays ~80 regardless.
__global__ __attribute__((amdgpu_waves_per_eu(2, 2))) __launch_bounds__(256)
void k_edgem(const short* __restrict__ chp, const short* __restrict__ cmp,
             const short* __restrict__ clp,
             const float* __restrict__ efp,
             const short* __restrict__ m1h, const short* __restrict__ m1m,
             const short* __restrict__ m1l,
             const short* __restrict__ m2h, const short* __restrict__ m2m,
             const short* __restrict__ m2l,
             const float* __restrict__ Wfold, const float* __restrict__ bfold,
             const int* __restrict__ csr_f, const int* __restrict__ rp_g,
             float* __restrict__ aggM) {
  __shared__ __align__(16) float cAB[2 * 64 * 68];   // cA | cB ; later agp planes
  __shared__ __align__(16) float ag2[2][64 * 68];    // ag for cbi=0,1
  __shared__ int fl[EPG];
  __shared__ int rp[65];
  float* cA = cAB;
  float* cB = cAB + 64 * 68;
  short* agp = (short*)cAB;                 // 3 planes of [64][72] shorts (27.6KB)

  const int tid = threadIdx.x;
  const int g = blockIdx.x, half = blockIdx.y;
  const int be = g * EPG, bn = g * 64;

  for (int i = tid; i < EPG; i += 256) fl[i] = csr_f[be + i];
  if (tid < 65) rp[tid] = rp_g[g * 65 + tid];

  const int lane = tid & 63, wid = tid >> 6;
  const int lr = lane & 15;
  const int lk = (lane >> 4) * 8;
  const int rsub = (lane >> 4) * 4;
  const int ng = tid >> 4, cg = tid & 15;
  const int n0 = ng * 4, cq = cg * 4;

  for (int cbi = 0; cbi < 2; ++cbi) {
    const int col0 = (half * 2 + cbi) * 64;
    __syncthreads();   // fl/rp ready; prev iter's cA/cB reads done

    // phase a: MFMA cA/cB. waves 0,1 -> cA (mw1 k 0..127); waves 2,3 -> cB (k 128..255)
    // Two fr-passes (rows 0..31, then 32..63) to cap register pressure.
    {
      const int isB = wid >> 1;
      const int cw = (wid & 1) * 32;
      const int wkof = isB * 128;
      float* dstC = isB ? cB : cA;
#pragma unroll 1
      for (int hf = 0; hf < 2; ++hf) {
        f32x4 c[2][2];
#pragma unroll
        for (int fr = 0; fr < 2; ++fr)
#pragma unroll
          for (int fc = 0; fc < 2; ++fc) c[fr][fc] = {0.f, 0.f, 0.f, 0.f};
        for (int ks = 0; ks < 4; ++ks) {
          const int k0 = ks * 32 + lk;
          bf16x8 ah[2], am[2], al[2];
#pragma unroll
          for (int fr = 0; fr < 2; ++fr) {
            const long ga = (long)(bn + (hf * 2 + fr) * 16 + lr) * 128 + k0;
            ah[fr] = *(const bf16x8*)&chp[ga];
            am[fr] = *(const bf16x8*)&cmp[ga];
            al[fr] = *(const bf16x8*)&clp[ga];
          }
#pragma unroll
          for (int fc = 0; fc < 2; ++fc) {
            const long wrow = (long)(col0 + cw + fc * 16 + lr) * 256 + wkof + k0;
            const bf16x8 bh = *(const bf16x8*)&m1h[wrow];
            const bf16x8 bm = *(const bf16x8*)&m1m[wrow];
            const bf16x8 bl = *(const bf16x8*)&m1l[wrow];
#pragma unroll
            for (int fr = 0; fr < 2; ++fr) {
              c[fr][fc] = __builtin_amdgcn_mfma_f32_16x16x32_bf16(ah[fr], bh, c[fr][fc], 0, 0, 0);
              c[fr][fc] = __builtin_amdgcn_mfma_f32_16x16x32_bf16(ah[fr], bm, c[fr][fc], 0, 0, 0);
              c[fr][fc] = __builtin_amdgcn_mfma_f32_16x16x32_bf16(am[fr], bh, c[fr][fc], 0, 0, 0);
              c[fr][fc] = __builtin_amdgcn_mfma_f32_16x16x32_bf16(ah[fr], bl, c[fr][fc], 0, 0, 0);
              c[fr][fc] = __builtin_amdgcn_mfma_f32_16x16x32_bf16(am[fr], bm, c[fr][fc], 0, 0, 0);
              c[fr][fc] = __builtin_amdgcn_mfma_f32_16x16x32_bf16(al[fr], bh, c[fr][fc], 0, 0, 0);
            }
          }
        }
#pragma unroll
        for (int fr = 0; fr < 2; ++fr)
#pragma unroll
          for (int fc = 0; fc < 2; ++fc) {
            const int col = cw + fc * 16 + lr;
#pragma unroll
            for (int r = 0; r < 4; ++r)
              dstC[((hf * 2 + fr) * 16 + rsub + r) * 68 + col] = c[fr][fc][r];
          }
      }
    }
    float4 Wf[16];
#pragma unroll
    for (int k = 0; k < 16; ++k) Wf[k] = *(const float4*)&Wfold[k * 256 + col0 + cq];
    const float4 bf = *(const float4*)&bfold[col0 + cq];
    __syncthreads();   // cA/cB visible

    // phase b: edge phase (fp32 CSR, atomic-free) -> ag2[cbi]
#pragma unroll
    for (int i = 0; i < 4; ++i) {
      const int n = n0 + i;
      float4 acc = make_float4(0.f, 0.f, 0.f, 0.f);
      const float4 cBn = *(const float4*)&cB[n * 68 + cq];
      const int e1 = rp[n + 1];
      for (int e = rp[n]; e < e1; ++e) {
        const int f = fl[e];
        const float* er = efp + (long)(be + e) * 16;
        float4 h = bf;
#pragma unroll
        for (int kq = 0; kq < 4; ++kq) {
          const float4 e4 = *(const float4*)(er + kq * 4);
          const float ev[4] = {e4.x, e4.y, e4.z, e4.w};
#pragma unroll
          for (int s = 0; s < 4; ++s) {
            const float4 w = Wf[kq * 4 + s];
            h.x = fmaf(ev[s], w.x, h.x); h.y = fmaf(ev[s], w.y, h.y);
            h.z = fmaf(ev[s], w.z, h.z); h.w = fmaf(ev[s], w.w, h.w);
          }
        }
        const float4 va = *(const float4*)&cA[f * 68 + cq];
        acc.x += fmaxf(h.x + va.x + cBn.x, 0.f);
        acc.y += fmaxf(h.y + va.y + cBn.y, 0.f);
        acc.z += fmaxf(h.z + va.z + cBn.z, 0.f);
        acc.w += fmaxf(h.w + va.w + cBn.w, 0.f);
      }
      *(float4*)&ag2[cbi][n * 68 + cq] = acc;
    }
  }
  __syncthreads();   // both ag2 complete; cAB dead

  // deferred mw2 phase: aM lives only here
  f32x4 aM[4][2];
#pragma unroll
  for (int fr = 0; fr < 4; ++fr)
#pragma unroll
    for (int fc = 0; fc < 2; ++fc) aM[fr][fc] = {0.f, 0.f, 0.f, 0.f};

  for (int cbi = 0; cbi < 2; ++cbi) {
    const int col0 = (half * 2 + cbi) * 64;
    // split3 ag2[cbi] -> agp planes [64][72] (aliased over cAB)
    for (int i = tid; i < 1024; i += 256) {
      const int n = i >> 4, kq = (i & 15) * 4;
      const float4 v = *(const float4*)&ag2[cbi][n * 68 + kq];
      const int b0 = n * 72 + kq;
      split3(v.x, agp, agp + 4608, agp + 9216, b0 + 0);
      split3(v.y, agp, agp + 4608, agp + 9216, b0 + 1);
      split3(v.z, agp, agp + 4608, agp + 9216, b0 + 2);
      split3(v.w, agp, agp + 4608, agp + 9216, b0 + 3);
    }
    __syncthreads();

    // aM += agp @ mw2t[col0 slice]  (K=64)
    for (int ks = 0; ks < 2; ++ks) {
      const int k0 = ks * 32 + lk;
      bf16x8 ah[4], am[4], al[4];
#pragma unroll
      for (int fr = 0; fr < 4; ++fr) {
        const int ab = (fr * 16 + lr) * 72 + k0;
        ah[fr] = *(const bf16x8*)&agp[ab];
        am[fr] = *(const bf16x8*)&agp[4608 + ab];
        al[fr] = *(const bf16x8*)&agp[9216 + ab];
      }
#pragma unroll
      for (int fc = 0; fc < 2; ++fc) {
        const long wrow = (long)(wid * 32 + fc * 16 + lr) * 256 + col0 + k0;
        const bf16x8 bh = *(const bf16x8*)&m2h[wrow];
        const bf16x8 bm = *(const bf16x8*)&m2m[wrow];
        const bf16x8 bl = *(const bf16x8*)&m2l[wrow];
#pragma unroll
        for (int fr = 0; fr < 4; ++fr) {
          aM[fr][fc] = __builtin_amdgcn_mfma_f32_16x16x32_bf16(ah[fr], bh, aM[fr][fc], 0, 0, 0);
          aM[fr][fc] = __builtin_amdgcn_mfma_f32_16x16x32_bf16(ah[fr], bm, aM[fr][fc], 0, 0, 0);
          aM[fr][fc] = __builtin_amdgcn_mfma_f32_16x16x32_bf16(am[fr], bh, aM[fr][fc], 0, 0, 0);
          aM[fr][fc] = __builtin_amdgcn_mfma_f32_16x16x32_bf16(ah[fr], bl, aM[fr][fc], 0, 0, 0);
          aM[fr][fc] = __builtin_amdgcn_mfma_f32_16x16x32_bf16(am[fr], bm, aM[fr][fc], 0, 0, 0);
          aM[fr][fc] = __builtin_amdgcn_mfma_f32_16x16x32_bf16(al[fr], bh, aM[fr][fc], 0, 0, 0);
        }
      }
    }
    __syncthreads();   // agp consumed before next overwrite
  }

  float* aggMh = aggM + (long)half * ND;
#pragma unroll
  for (int fr = 0; fr < 4; ++fr)
#pragma unroll
    for (int fc = 0; fc < 2; ++fc) {
      const int col = wid * 32 + fc * 16 + lr;
#pragma unroll
      for (int r = 0; r < 4; ++r)
        aggMh[(long)(bn + fr * 16 + rsub + r) * 128 + col] = aM[fr][fc][r];
    }
}

// ---------------------------------------------------------------------------
__global__ void k_tfeat(const float* __restrict__ x,
                        const float* __restrict__ t1w, const float* __restrict__ t1b,
                        const float* __restrict__ t2w, const float* __restrict__ t2b,
                        float* __restrict__ tf) {
  __shared__ float xs[4][128];
  __shared__ float ys[4][64];
  const int tid = threadIdx.x;
  const long row0 = (long)blockIdx.x * 4;
  for (int i = tid; i < 512; i += 256)
    xs[i >> 7][i & 127] = x[(row0 + (i >> 7)) * 128 + (i & 127)];
  __syncthreads();
  const int r = tid >> 6, c = tid & 63;
  float acc = t1b[c];
#pragma unroll 4
  for (int k = 0; k < 128; ++k) acc = fmaf(xs[r][k], t1w[k * 64 + c], acc);
  ys[r][c] = fmaxf(acc, 0.f);
  __syncthreads();
  float a2 = t2b[c];
#pragma unroll 4
  for (int k = 0; k < 64; ++k) a2 = fmaf(ys[r][k], t2w[k * 64 + c], a2);
  tf[(row0 + r) * 64 + c] = a2;
}

// ---------------------------------------------------------------------------
__global__ void k_sim(const float* __restrict__ tf, float* __restrict__ sim) {
  const int b = blockIdx.x, tid = threadIdx.x;
  __shared__ float tq[64][65];
  __shared__ float tcs[64][65];
  for (int i = tid; i < 4096; i += 256) {
    tq[i >> 6][i & 63]  = tf[(long)b * 8192 + i];
    tcs[i >> 6][i & 63] = tf[(long)b * 8192 + 4096 + i];
  }
  __syncthreads();
  const int m = tid >> 2, j0 = (tid & 3) * 16;
#pragma unroll
  for (int j = 0; j < 16; ++j) {
    float a = 0.f;
#pragma unroll 4
    for (int k = 0; k < 64; ++k) a = fmaf(tq[m][k], tcs[j0 + j][k], a);
    sim[(long)b * 4096 + m * 64 + j0 + j] = a;
  }
}

// ---------------------------------------------------------------------------
__global__ void k_sink(float* __restrict__ sim, float* __restrict__ outp) {
  const int b = blockIdx.x, tid = threadIdx.x;
  __shared__ float la[64][65];
  const float C = 14.426950408889634f;   // 10 / ln(2)
  for (int i = tid; i < 4096; i += 256)
    la[i >> 6][i & 63] = sim[(long)b * 4096 + i] * C;
  __syncthreads();
  const int r4 = tid >> 2, l4 = tid & 3;
  for (int it = 0; it < 20; ++it) {
    {
      float m = -3.4e38f;
#pragma unroll
      for (int i = 0; i < 16; ++i) m = fmaxf(m, la[r4][l4 + 4 * i]);
      m = fmaxf(m, __shfl_xor(m, 1)); m = fmaxf(m, __shfl_xor(m, 2));
      float s = 0.f;
#pragma unroll
      for (int i = 0; i < 16; ++i) s += exp2f(la[r4][l4 + 4 * i] - m);
      s += __shfl_xor(s, 1); s += __shfl_xor(s, 2);
      const float lse = m + log2f(s);
#pragma unroll
      for (int i = 0; i < 16; ++i) la[r4][l4 + 4 * i] -= lse;
    }
    __syncthreads();
    {
      float m = -3.4e38f;
#pragma unroll
      for (int i = 0; i < 16; ++i) m = fmaxf(m, la[l4 + 4 * i][r4]);
      m = fmaxf(m, __shfl_xor(m, 1)); m = fmaxf(m, __shfl_xor(m, 2));
      float s = 0.f;
#pragma unroll
      for (int i = 0; i < 16; ++i) s += exp2f(la[l4 + 4 * i][r4] - m);
      s += __shfl_xor(s, 1); s += __shfl_xor(s, 2);
      const float lse = m + log2f(s);
#pragma unroll
      for (int i = 0; i < 16; ++i) la[l4 + 4 * i][r4] -= lse;
    }
    __syncthreads();
  }
  for (int i = tid; i < 4096; i += 256) {
    const float v = exp2f(la[i >> 6][i & 63]);
    outp[(long)b * 4096 + i] = v;
    sim[(long)b * 4096 + i] = v;
  }
}

// ---------------------------------------------------------------------------
__global__ void k_mix(const float* __restrict__ plan, const float* __restrict__ src,
                      float* __restrict__ dst) {
  const int b = blockIdx.x, tid = threadIdx.x;
  __shared__ float pl[64][65];
  __shared__ float qs[64][128];
  __shared__ float cs[64][128];
  const long qbase = (long)(2 * b) * 64, cbase = qbase + 64;
  for (int i = tid; i < 4096; i += 256) pl[i >> 6][i & 63] = plan[(long)b * 4096 + i];
  for (int i = tid; i < 8192; i += 256) {
    qs[i >> 7][i & 127] = src[qbase * 128 + i];
    cs[i >> 7][i & 127] = src[cbase * 128 + i];
  }
  __syncthreads();
  const int d = tid & 127, m0 = (tid >> 7) * 32;
  for (int m = m0; m < m0 + 32; ++m) {
    float a = 0.f;
#pragma unroll 4
    for (int j = 0; j < 64; ++j) a = fmaf(pl[m][j], cs[j][d], a);
    dst[(qbase + m) * 128 + d] = a;
  }
  for (int j = m0; j < m0 + 32; ++j) {
    float a = 0.f;
#pragma unroll 4
    for (int m = 0; m < 64; ++m) a = fmaf(pl[m][j], qs[m][d], a);
    dst[(cbase + j) * 128 + d] = a;
  }
}

// ---------------------------------------------------------------------------
extern "C" void kernel_launch(void* const* d_in, const int* in_sizes, int n_in,
                              void* d_out, int out_size, void* d_ws, size_t ws_size,
                              hipStream_t stream) {
  const float* nf  = (const float*)d_in[0];
  const float* ef  = (const float*)d_in[1];
  const int* from_idx = (const int*)d_in[2];
  const int* to_idx   = (const int*)d_in[3];
  const float* new_w = (const float*)d_in[4];
  const float* new_b = (const float*)d_in[5];
  const float* eew = (const float*)d_in[6];
  const float* eeb = (const float*)d_in[7];
  const float* mw1 = (const float*)d_in[8];
  const float* mb1 = (const float*)d_in[9];
  const float* mw2 = (const float*)d_in[10];
  const float* mb2 = (const float*)d_in[11];
  const float* nw1 = (const float*)d_in[12];
  const float* nb1 = (const float*)d_in[13];
  const float* nw2 = (const float*)d_in[14];
  const float* nb2 = (const float*)d_in[15];
  const float* cw1 = (const float*)d_in[16];
  const float* cb1 = (const float*)d_in[17];
  const float* cw2 = (const float*)d_in[18];
  const float* cb2 = (const float*)d_in[19];
  const float* t1w = (const float*)d_in[20];
  const float* t1b = (const float*)d_in[21];
  const float* t2w = (const float*)d_in[22];
  const float* t2b = (const float*)d_in[23];

  float* W = (float*)d_ws;
  float* h0     = W;                       // ND
  float* aggM0  = h0 + ND;                 // ND (tf/sim alias here)
  float* aggM1  = aggM0 + ND;              // ND
  float* parts  = aggM1 + ND;              // 5*ND
  float* efp    = parts + 5 * ND;          // 262144*16
  float* Wfold  = efp + 262144l * 16;      // 4096
  float* bfold  = Wfold + 4096;            // 256
  float* vbias  = bfold + 256;             // 256
  int*   deg    = (int*)(vbias + 256);     // 32768
  int*   csr_f  = deg + 32768;             // 262144
  int*   rp_g   = csr_f + 262144;          // 512*65 = 33280
  short* cw1t_h = (short*)(rp_g + 33280);  // 65536 shorts per plane
  short* cw1t_m = cw1t_h + 65536;
  short* cw1t_l = cw1t_m + 65536;
  short* nw1t_h = cw1t_l + 65536;
  short* nw1t_m = nw1t_h + 65536;
  short* nw1t_l = nw1t_m + 65536;
  short* cw2t_h = nw1t_l + 65536;          // 32768 each
  short* cw2t_m = cw2t_h + 32768;
  short* cw2t_l = cw2t_m + 32768;
  short* nw2t_h = cw2t_l + 32768;
  short* nw2t_m = nw2t_h + 32768;
  short* nw2t_l = nw2t_m + 32768;
  short* m1t_h  = nw2t_l + 32768;          // mw1[0:256] -> 65536 each
  short* m1t_m  = m1t_h + 65536;
  short* m1t_l  = m1t_m + 65536;
  short* m2t_h  = m1t_l + 65536;           // mw2 -> 32768 each
  short* m2t_m  = m2t_h + 32768;
  short* m2t_l  = m2t_m + 32768;
  short* chp    = m2t_l + 32768;           // comb planes: 32768*128 shorts each
  short* cmp    = chp + 32768l * 128;
  short* clp    = cmp + 32768l * 128;
  float* tf     = aggM0;                   // 32768*64
  float* sim    = aggM0 + 2097152;         // 256*4096
  float* outp   = (float*)d_out;

  k_prep<<<18, 256, 0, stream>>>(eew, eeb, mw1, mb1, mb2, nw1, Wfold, bfold, vbias);
  k_csr<<<512, 256, 0, stream>>>(from_idx, to_idx, ef, csr_f, rp_g, efp, deg);
  k_wsplit3<<<256, 256, 0, stream>>>(cw1, 256, 256, cw1t_h, cw1t_m, cw1t_l);
  k_wsplit3<<<256, 256, 0, stream>>>(nw1, 256, 256, nw1t_h, nw1t_m, nw1t_l);
  k_wsplit3<<<128, 256, 0, stream>>>(cw2, 128, 256, cw2t_h, cw2t_m, cw2t_l);
  k_wsplit3<<<128, 256, 0, stream>>>(nw2, 128, 256, nw2t_h, nw2t_m, nw2t_l);
  k_wsplit3<<<256, 256, 0, stream>>>(mw1, 256, 256, m1t_h, m1t_m, m1t_l);
  k_wsplit3<<<128, 256, 0, stream>>>(mw2, 128, 256, m2t_h, m2t_m, m2t_l);
  k_node_enc<<<16384, 256, 0, stream>>>(nf, new_w, new_b, h0);

  for (int t = 0; t < 3; ++t) {
    const float* hprev = h0;
    for (int p = 1; p <= 5; ++p) {
      if (t > 0 && p > 1)
        k_mlp2m<256, false, false, false, true><<<1024, 256, 0, stream>>>(
            hprev, nullptr, nullptr, nullptr,
            parts + (long)(p - 1) * ND, nullptr,
            cw1t_h, cw1t_m, cw1t_l, cb1, nullptr, nullptr,
            cw2t_h, cw2t_m, cw2t_l, cb2, nullptr, chp, cmp, clp);
      else
        k_mlp2m<128, false, false, false, true><<<1024, 256, 0, stream>>>(
            hprev, nullptr, nullptr, nullptr, nullptr, nullptr,
            cw1t_h, cw1t_m, cw1t_l, cb1, nullptr, nullptr,
            cw2t_h, cw2t_m, cw2t_l, cb2, nullptr, chp, cmp, clp);
      k_edgem<<<dim3(512, 2), 256, 0, stream>>>(chp, cmp, clp, efp,
                                                m1t_h, m1t_m, m1t_l,
                                                m2t_h, m2t_m, m2t_l,
                                                Wfold, bfold, csr_f, rp_g, aggM0);
      float* hnew = parts + (long)(p - 1) * ND;
      k_mlp2m<256, true, true, true, false><<<1024, 256, 0, stream>>>(
          nullptr, chp, cmp, clp, aggM0, aggM1,
          nw1t_h, nw1t_m, nw1t_l, nb1, deg, vbias,
          nw2t_h, nw2t_m, nw2t_l, nb2, hnew, nullptr, nullptr, nullptr);
      hprev = hnew;
    }
    k_tfeat<<<8192, 256, 0, stream>>>(parts + 4 * ND, t1w, t1b, t2w, t2b, tf);
    k_sim<<<256, 256, 0, stream>>>(tf, sim);
    k_sink<<<256, 256, 0, stream>>>(sim, outp);
    if (t < 2) {
      for (int pi = 3; pi >= 0; --pi)
        k_mix<<<256, 256, 0, stream>>>(sim, parts + (long)pi * ND, parts + (long)(pi + 1) * ND);
    }
  }
}